// Round 17
// baseline (348.407 us; speedup 1.0000x reference)
//
#include <hip/hip_runtime.h>

#define NA 15
#define NB 32
#define DD 256
#define PL 65536  // shorts per weight plane (8 slices x 256 cols x 32 k)
#define ASTR 264  // act LDS row stride (shorts)

using bf16x8 = __attribute__((ext_vector_type(8))) short;
using f32x4  = __attribute__((ext_vector_type(4))) float;

__device__ __forceinline__ unsigned short f2bf(float f){
  unsigned int u = __float_as_uint(f);
  u = u + 0x7fffu + ((u >> 16) & 1u);
  return (unsigned short)(u >> 16);
}
__device__ __forceinline__ float bf2f(unsigned short h){
  return __uint_as_float(((unsigned int)h) << 16);
}
__device__ __forceinline__ unsigned int cvtpk_bf16(float lo, float hi){
    unsigned int r;
    asm("v_cvt_pk_bf16_f32 %0, %1, %2" : "=v"(r) : "v"(lo), "v"(hi));
    return r;
}
__device__ __forceinline__ void split2_write(const float v[4], short* pH, short* pL){
    unsigned int h01 = cvtpk_bf16(v[0], v[1]);
    unsigned int h23 = cvtpk_bf16(v[2], v[3]);
    float r0 = v[0] - __uint_as_float(h01 << 16);
    float r1 = v[1] - __uint_as_float(h01 & 0xffff0000u);
    float r2 = v[2] - __uint_as_float(h23 << 16);
    float r3 = v[3] - __uint_as_float(h23 & 0xffff0000u);
    unsigned int l01 = cvtpk_bf16(r0, r1);
    unsigned int l23 = cvtpk_bf16(r2, r3);
    *(uint2*)pH = make_uint2(h01, h23);
    *(uint2*)pL = make_uint2(l01, l23);
}
__device__ __forceinline__ void split3_write(const float v[4], short* pH, short* pM, short* pL){
    unsigned int h01 = cvtpk_bf16(v[0], v[1]);
    unsigned int h23 = cvtpk_bf16(v[2], v[3]);
    float r0 = v[0] - __uint_as_float(h01 << 16);
    float r1 = v[1] - __uint_as_float(h01 & 0xffff0000u);
    float r2 = v[2] - __uint_as_float(h23 << 16);
    float r3 = v[3] - __uint_as_float(h23 & 0xffff0000u);
    unsigned int m01 = cvtpk_bf16(r0, r1);
    unsigned int m23 = cvtpk_bf16(r2, r3);
    float s0 = r0 - __uint_as_float(m01 << 16);
    float s1 = r1 - __uint_as_float(m01 & 0xffff0000u);
    float s2 = r2 - __uint_as_float(m23 << 16);
    float s3 = r3 - __uint_as_float(m23 & 0xffff0000u);
    unsigned int l01 = cvtpk_bf16(s0, s1);
    unsigned int l23 = cvtpk_bf16(s2, s3);
    *(uint2*)pH = make_uint2(h01, h23);
    *(uint2*)pM = make_uint2(m01, m23);
    *(uint2*)pL = make_uint2(l01, l23);
}

// ---------------------------------------------------------------------------
// fp32 VALU primitives (value_x branch of front kernel)
// ---------------------------------------------------------------------------
template<int TM, bool RELU>
__device__ __forceinline__ void layer256(
    const float* __restrict__ W, const float* __restrict__ bias,
    const float* act, int K, int lda, float* out, int ldo)
{
    constexpr int RPG = TM / 4;
    const int tid = threadIdx.x;
    const int tr = tid >> 6;
    const int tc = tid & 63;
    float acc[RPG][4];
#pragma unroll
    for (int i = 0; i < RPG; ++i) { acc[i][0]=0.f; acc[i][1]=0.f; acc[i][2]=0.f; acc[i][3]=0.f; }
    const float* wp = W + 4 * tc;
    int k = 0;
    for (; k + 4 <= K; k += 4) {
        float4 w0 = *reinterpret_cast<const float4*>(wp + (k + 0) * DD);
        float4 w1 = *reinterpret_cast<const float4*>(wp + (k + 1) * DD);
        float4 w2 = *reinterpret_cast<const float4*>(wp + (k + 2) * DD);
        float4 w3 = *reinterpret_cast<const float4*>(wp + (k + 3) * DD);
#pragma unroll
        for (int i = 0; i < RPG; ++i) {
            float4 a = *reinterpret_cast<const float4*>(act + (RPG * tr + i) * lda + k);
            acc[i][0] += a.x * w0.x + a.y * w1.x + a.z * w2.x + a.w * w3.x;
            acc[i][1] += a.x * w0.y + a.y * w1.y + a.z * w2.y + a.w * w3.y;
            acc[i][2] += a.x * w0.z + a.y * w1.z + a.z * w2.z + a.w * w3.z;
            acc[i][3] += a.x * w0.w + a.y * w1.w + a.z * w2.w + a.w * w3.w;
        }
    }
    for (; k < K; ++k) {
        float4 w0 = *reinterpret_cast<const float4*>(wp + k * DD);
#pragma unroll
        for (int i = 0; i < RPG; ++i) {
            float a = act[(RPG * tr + i) * lda + k];
            acc[i][0] += a * w0.x; acc[i][1] += a * w0.y;
            acc[i][2] += a * w0.z; acc[i][3] += a * w0.w;
        }
    }
    float4 bb = *reinterpret_cast<const float4*>(bias + 4 * tc);
#pragma unroll
    for (int i = 0; i < RPG; ++i) {
        float4 o;
        o.x = acc[i][0] + bb.x; o.y = acc[i][1] + bb.y;
        o.z = acc[i][2] + bb.z; o.w = acc[i][3] + bb.w;
        if (RELU) {
            o.x = fmaxf(o.x, 0.f); o.y = fmaxf(o.y, 0.f);
            o.z = fmaxf(o.z, 0.f); o.w = fmaxf(o.w, 0.f);
        }
        *reinterpret_cast<float4*>(out + (RPG * tr + i) * ldo + 4 * tc) = o;
    }
}

template<int TM>
__device__ __forceinline__ void head1c(
    const float* h, int ldh, const float* __restrict__ W, int wstr, int col, float bias,
    float* __restrict__ gout, int gbase)
{
    const int wv = threadIdx.x >> 6;
    const int lane = threadIdx.x & 63;
    for (int rr = wv; rr < TM; rr += 4) {
        float p = 0.f;
#pragma unroll
        for (int t = 0; t < 4; ++t) {
            int k = lane + 64 * t;
            p += h[rr * ldh + k] * W[k * wstr + col];
        }
#pragma unroll
        for (int m = 1; m < 64; m <<= 1) p += __shfl_xor(p, m);
        if (lane == 0) gout[gbase + rr] = p + bias;
    }
}

// ---------------------------------------------------------------------------
// front_kernel (unchanged from R15/R16)
// ---------------------------------------------------------------------------
__global__ __launch_bounds__(256) void front_kernel(
    const float* __restrict__ x,
    const float* __restrict__ emW0, const float* __restrict__ emB0,
    const float* __restrict__ emW1, const float* __restrict__ emB1,
    const float* __restrict__ emW2, const float* __restrict__ emB2,
    const float* __restrict__ vW, const float* __restrict__ vb,
    const float* __restrict__ crW0, const float* __restrict__ crW1,
    const float* __restrict__ tmW0, const float* __restrict__ tmW1,
    const float* __restrict__ tmW2, const float* __restrict__ tmB2,
    short* __restrict__ planes, float* __restrict__ w5, float* __restrict__ b5,
    float* __restrict__ c2cr, float* __restrict__ c2tm, float* __restrict__ b45,
    float* __restrict__ vout, float* __restrict__ U1cr, float* __restrict__ U1tm)
{
    __shared__ __align__(16) float smem[32 * DD];
    const int blk = blockIdx.x;
    const int tid = threadIdx.x;

    if (blk < 24) {
        const int mat = blk >> 3;
        const int kk  = blk & 7;
        const float* W = (mat == 0) ? crW1 : (mat == 1) ? tmW1 : emW1;
        const int col = tid;
        short bh[32], bm[32], bl[32];
#pragma unroll
        for (int j = 0; j < 32; ++j) {
            float w = W[(kk * 32 + j) * 256 + col];
            unsigned short h = f2bf(w); float fh = bf2f(h);
            float r1 = w - fh;
            unsigned short m = f2bf(r1); float fm = bf2f(m);
            bh[j] = (short)h; bm[j] = (short)m; bl[j] = (short)f2bf(r1 - fm);
        }
        short* pH = planes + (size_t)(mat * 3 + 0) * PL + kk * 8192 + col * 32;
        short* pM = planes + (size_t)(mat * 3 + 1) * PL + kk * 8192 + col * 32;
        short* pLp = planes + (size_t)(mat * 3 + 2) * PL + kk * 8192 + col * 32;
#pragma unroll
        for (int j = 0; j < 32; j += 4) {
            *(short4*)(pH + j) = make_short4(bh[j], bh[j+1], bh[j+2], bh[j+3]);
            *(short4*)(pM + j) = make_short4(bm[j], bm[j+1], bm[j+2], bm[j+3]);
            *(short4*)(pLp + j) = make_short4(bl[j], bl[j+1], bl[j+2], bl[j+3]);
        }
    } else if (blk == 24) {
        float acc = 0.f;
        for (int j = 0; j < 256; j += 4) {
            float4 wrow = *(const float4*)(emW2 + tid * 256 + j);
            float4 vv   = *(const float4*)(vW + j);
            acc += wrow.x * vv.x + wrow.y * vv.y + wrow.z * vv.z + wrow.w * vv.w;
        }
        w5[tid] = acc;
        if (tid == 0) {
            float b = 0.f;
            for (int j = 0; j < 256; ++j) b += emB2[j] * vW[j];
            b5[0] = b + vb[0];
        }
    } else if (blk < 33) {
        constexpr int TM = 4;
        float* bufA = smem;
        float* bufB = bufA + TM * DD;
        float* bufC = bufB + TM * DD;
        const int row0 = (blk - 25) * TM;
        for (int i = 0; i < TM; ++i) bufA[i * DD + tid] = x[(row0 + i) * DD + tid];
        __syncthreads();
        layer256<TM, true >(emW0, emB0, bufA, 256, DD, bufB, DD); __syncthreads();
        layer256<TM, true >(emW1, emB1, bufB, 256, DD, bufC, DD); __syncthreads();
        layer256<TM, false>(emW2, emB2, bufC, 256, DD, bufB, DD); __syncthreads();
        head1c<TM>(bufB, DD, vW, 1, 0, vb[0], vout, row0);
    } else if (blk < 41) {
        const int row0 = (blk - 33) * 4;
        float* xs = smem;   // [4][256]
        for (int i = 0; i < 4; ++i) xs[i * 256 + tid] = x[(row0 + i) * 256 + tid];
        __syncthreads();
        float acr[4] = {0.f,0.f,0.f,0.f}, atm[4] = {0.f,0.f,0.f,0.f};
        for (int k = 0; k < 256; ++k) {
            float wc = crW0[k * 256 + tid];
            float wt = tmW0[k * 256 + tid];
#pragma unroll
            for (int i = 0; i < 4; ++i) {
                acr[i] += xs[i * 256 + k] * wc;
                atm[i] += xs[i * 256 + k] * wt;
            }
        }
        for (int i = 0; i < 4; ++i) {
            U1cr[(row0 + i) * 256 + tid] = acr[i];
            U1tm[(row0 + i) * 256 + tid] = atm[i];
        }
    } else if (blk < 65) {
        const int pb = blk - 41;
        const int prod = pb >> 3;           // 0=W45, 1=W2cr, 2=W2tm
        const int r0 = (pb & 7) * 32;
        const float* B = (prod == 0) ? emW0 : (prod == 1) ? crW0 : tmW0;
        const int pbase = 9 + prod * 3;
        float* As = smem;   // [32][256]
        for (int i = tid; i < 32 * 256; i += 256)
            As[i] = tmW2[(r0 + (i >> 8)) * 256 + (i & 255)];
        __syncthreads();
        float acc[32];
#pragma unroll
        for (int j = 0; j < 32; ++j) acc[j] = 0.f;
        for (int m = 0; m < 256; ++m) {
            float b = B[m * 256 + tid];
#pragma unroll
            for (int j = 0; j < 32; ++j) acc[j] += As[j * 256 + m] * b;
        }
        short bh[32], bm[32], bl[32];
#pragma unroll
        for (int j = 0; j < 32; ++j) {
            float w = acc[j];
            unsigned short h = f2bf(w); float fh = bf2f(h);
            float r1 = w - fh;
            unsigned short mm = f2bf(r1); float fm = bf2f(mm);
            bh[j] = (short)h; bm[j] = (short)mm; bl[j] = (short)f2bf(r1 - fm);
        }
        const int kk = r0 >> 5;
        short* pH = planes + (size_t)(pbase + 0) * PL + kk * 8192 + tid * 32;
        short* pM = planes + (size_t)(pbase + 1) * PL + kk * 8192 + tid * 32;
        short* pLp = planes + (size_t)(pbase + 2) * PL + kk * 8192 + tid * 32;
#pragma unroll
        for (int j = 0; j < 32; j += 4) {
            *(short4*)(pH + j) = make_short4(bh[j], bh[j+1], bh[j+2], bh[j+3]);
            *(short4*)(pM + j) = make_short4(bm[j], bm[j+1], bm[j+2], bm[j+3]);
            *(short4*)(pLp + j) = make_short4(bl[j], bl[j+1], bl[j+2], bl[j+3]);
        }
    } else {
        const int j = tid;
        float a0 = 0.f, a1 = 0.f, a2 = 0.f;
        for (int k = 0; k < 256; ++k) {
            float t = tmB2[k];
            a0 += t * crW0[k * 256 + j];
            a1 += t * tmW0[k * 256 + j];
            a2 += t * emW0[k * 256 + j];
        }
        c2cr[j] = a0;
        c2tm[j] = a1;
        b45[j] = a2 + emB0[j];
    }
}

__global__ __launch_bounds__(256) void finalize_kernel(
    const float* __restrict__ Vns3, const float* __restrict__ cont2,
    const float* __restrict__ rews0, const float* __restrict__ rews1,
    const float* __restrict__ cont1, float* __restrict__ out)
{
    const int b = blockIdx.x;
    const int tid = threadIdx.x;
    __shared__ float vs2[NA][NA];
    __shared__ float vs3[NA];
    if (tid < NA * NA) {
        const int x = tid / NA, y = tid % NA;
        float vals[NA];
        float m = -INFINITY;
#pragma unroll
        for (int z = 0; z < NA; ++z) {
            int vidx = ((b * NA + y) * NA + z) * NA + x;
            int cidx = ((b * NA + x) * NA + y) * NA + z;
            float c1 = rews0[b * NA + z] * 0.99f;
            float c2 = (c1 + rews1[(b * NA + x) * NA + z]) * 0.99f;
            float v = Vns3[vidx] * 0.970299f + c2;
            if (cont2[cidx] > 0.f) v = 0.f;
            vals[z] = v;
            m = fmaxf(m, v);
        }
        float se = 0.f, sw = 0.f;
#pragma unroll
        for (int z = 0; z < NA; ++z) { float e = expf(vals[z] - m); se += e; sw += e * vals[z]; }
        vs2[x][y] = sw / se;
    }
    __syncthreads();
    if (tid < NA) {
        const int x = tid;
        float vals[NA];
        float m = -INFINITY;
#pragma unroll
        for (int y = 0; y < NA; ++y) {
            float v = vs2[x][y];
            if (cont1[(b * NA + x) * NA + y] > 0.f) v = 0.f;
            vals[y] = v;
            m = fmaxf(m, v);
        }
        float se = 0.f, sw = 0.f;
#pragma unroll
        for (int y = 0; y < NA; ++y) { float e = expf(vals[y] - m); se += e; sw += e * vals[y]; }
        vs3[x] = sw / se;
    }
    __syncthreads();
    if (tid == 0) {
        float m = -INFINITY;
#pragma unroll
        for (int x = 0; x < NA; ++x) m = fmaxf(m, vs3[x]);
        float se = 0.f;
#pragma unroll
        for (int x = 0; x < NA; ++x) se += expf(vs3[x] - m);
        float l = logf(se);
#pragma unroll
        for (int x = 0; x < NA; ++x) out[b * NA + x] = vs3[x] - m - l;
    }
}

// ---------------------------------------------------------------------------
// mm3: accumulate RT row-tiles x 4 col-tiles over K=256 with NP passes.
// ---------------------------------------------------------------------------
template<int RT, int NP>
__device__ __forceinline__ void mm3(
    const short* __restrict__ plH, const short* __restrict__ plM, const short* __restrict__ plL,
    const short* actH, const short* actM, const short* actL,
    f32x4 (&acc)[4][RT])
{
    const int tid = threadIdx.x;
    const int ln15 = tid & 15, lng = (tid >> 4) & 3, wv = tid >> 6;
    const int wo = (wv * 64 + ln15) * 32 + lng * 8;
#pragma unroll
    for (int kk = 0; kk < 8; ++kk) {
        bf16x8 wH[4], wM[4], wL[4], xH[RT], xM[RT], xL[RT];
#pragma unroll
        for (int ct = 0; ct < 4; ++ct) {
            wH[ct] = *(const bf16x8*)(plH + wo + kk * 8192 + ct * 512);
            wM[ct] = *(const bf16x8*)(plM + wo + kk * 8192 + ct * 512);
            if (NP == 6) wL[ct] = *(const bf16x8*)(plL + wo + kk * 8192 + ct * 512);
        }
#pragma unroll
        for (int rt = 0; rt < RT; ++rt) {
            int off = (rt * 16 + ln15) * ASTR + kk * 32 + lng * 8;
            xH[rt] = *(const bf16x8*)(actH + off);
            xM[rt] = *(const bf16x8*)(actM + off);
            if (NP == 6) xL[rt] = *(const bf16x8*)(actL + off);
        }
        __builtin_amdgcn_s_setprio(1);
#pragma unroll
        for (int ct = 0; ct < 4; ++ct)
#pragma unroll
            for (int rt = 0; rt < RT; ++rt) {
                acc[ct][rt] = __builtin_amdgcn_mfma_f32_16x16x32_bf16(wH[ct], xH[rt], acc[ct][rt], 0, 0, 0);
                acc[ct][rt] = __builtin_amdgcn_mfma_f32_16x16x32_bf16(wH[ct], xM[rt], acc[ct][rt], 0, 0, 0);
                acc[ct][rt] = __builtin_amdgcn_mfma_f32_16x16x32_bf16(wM[ct], xH[rt], acc[ct][rt], 0, 0, 0);
                if (NP == 6) {
                    acc[ct][rt] = __builtin_amdgcn_mfma_f32_16x16x32_bf16(wM[ct], xM[rt], acc[ct][rt], 0, 0, 0);
                    acc[ct][rt] = __builtin_amdgcn_mfma_f32_16x16x32_bf16(wH[ct], xL[rt], acc[ct][rt], 0, 0, 0);
                    acc[ct][rt] = __builtin_amdgcn_mfma_f32_16x16x32_bf16(wL[ct], xH[rt], acc[ct][rt], 0, 0, 0);
                }
            }
        __builtin_amdgcn_s_setprio(0);
    }
}

// stage a 3-way-split activation row block from U + a*wrow + bias (relu)
template<int ROWS, bool CLAMP>
__device__ __forceinline__ void stage3w(
    const float* __restrict__ U, const float* __restrict__ wrow256,
    const float* __restrict__ bias, int row0,
    short* actH, short* actM, short* actL)
{
    const int tid = threadIdx.x;
    const int wv = tid >> 6, ln = tid & 63;
    constexpr int RPW = ROWS / 4;
    const float4 wr = *(const float4*)(wrow256 + ln * 4);
    const float4 bb = *(const float4*)(bias + ln * 4);
    for (int i = wv * RPW; i < wv * RPW + RPW; ++i) {
        int r = row0 + i;
        int srow = r / 15;
        if (CLAMP && srow > 7199) srow = 7199;
        float a = (float)(r % 15);
        float4 u = *(const float4*)(U + srow * 256 + ln * 4);
        float sv[4];
        sv[0] = fmaxf(u.x + a * wr.x + bb.x, 0.f);
        sv[1] = fmaxf(u.y + a * wr.y + bb.y, 0.f);
        sv[2] = fmaxf(u.z + a * wr.z + bb.z, 0.f);
        sv[3] = fmaxf(u.w + a * wr.w + bb.w, 0.f);
        split3_write(sv, actH + i * ASTR + ln * 4, actM + i * ASTR + ln * 4, actL + i * ASTR + ln * 4);
    }
}

// ---------------------------------------------------------------------------
// stage1m: 480 rows (b,a1), 30 blocks x 16 rows. rews0 + U2cr/U2tm.
// ---------------------------------------------------------------------------
__global__ __launch_bounds__(256, 2) void stage1m_kernel(
    const float* __restrict__ U1cr, const float* __restrict__ U1tm,
    const short* __restrict__ planes,
    const float* __restrict__ crW0, const float* __restrict__ crB0,
    const float* __restrict__ crB1, const float* __restrict__ crW2, const float* __restrict__ crB2,
    const float* __restrict__ tmW0, const float* __restrict__ tmB0,
    const float* __restrict__ tmB1,
    const float* __restrict__ c2cr, const float* __restrict__ c2tm,
    float* __restrict__ rews0, float* __restrict__ U2cr, float* __restrict__ U2tm)
{
    __shared__ short actH[16 * ASTR];
    __shared__ short actM[16 * ASTR];
    __shared__ short actL[16 * ASTR];
    __shared__ float hred[64];
    const int tid = threadIdx.x;
    const int row0 = blockIdx.x * 16;
    const int ln15 = tid & 15, lng = (tid >> 4) & 3, wv = tid >> 6;

    stage3w<16, false>(U1cr, crW0 + 65536, crB0, row0, actH, actM, actL);
    __syncthreads();
    {
        f32x4 acc[4][1];
#pragma unroll
        for (int a = 0; a < 4; ++a) acc[a][0] = f32x4{0.f,0.f,0.f,0.f};
        mm3<1, 6>(planes + 0*PL, planes + 1*PL, planes + 2*PL, actH, actM, actL, acc);
        float hp = 0.f;
#pragma unroll
        for (int ct = 0; ct < 4; ++ct) {
            const int colb = wv * 64 + ct * 16 + lng * 4;
            const float4 b1 = *(const float4*)(crB1 + colb);
            f32x4 v = acc[ct][0];
            v[0] += b1.x; v[1] += b1.y; v[2] += b1.z; v[3] += b1.w;
#pragma unroll
            for (int j = 0; j < 4; ++j) v[j] = fmaxf(v[j], 0.f);
#pragma unroll
            for (int j = 0; j < 4; ++j) hp += v[j] * crW2[(colb + j) * 2 + 1];
        }
        hp += __shfl_xor(hp, 16);
        hp += __shfl_xor(hp, 32);
        if (lng == 0) hred[wv * 16 + ln15] = hp;
        __syncthreads();
        if (tid < 16) rews0[row0 + tid] = hred[tid] + hred[16 + tid] + hred[32 + tid] + hred[48 + tid] + crB2[1];
        __syncthreads();
    }

    stage3w<16, false>(U1tm, tmW0 + 65536, tmB0, row0, actH, actM, actL);
    __syncthreads();
    {
        f32x4 acc[4][1];
#pragma unroll
        for (int a = 0; a < 4; ++a) acc[a][0] = f32x4{0.f,0.f,0.f,0.f};
        mm3<1, 6>(planes + 3*PL, planes + 4*PL, planes + 5*PL, actH, actM, actL, acc);
        __syncthreads();
#pragma unroll
        for (int ct = 0; ct < 4; ++ct) {
            const int colb = wv * 64 + ct * 16 + lng * 4;
            const float4 bb = *(const float4*)(tmB1 + colb);
            f32x4 v = acc[ct][0];
            v[0] += bb.x; v[1] += bb.y; v[2] += bb.z; v[3] += bb.w;
#pragma unroll
            for (int j = 0; j < 4; ++j) v[j] = fmaxf(v[j], 0.f);
            float sv[4] = {v[0], v[1], v[2], v[3]};
            const int ao = ln15 * ASTR + colb;
            split3_write(sv, actH + ao, actM + ao, actL + ao);
        }
        __syncthreads();
    }
    {
        f32x4 acc[4][1];
#pragma unroll
        for (int a = 0; a < 4; ++a) acc[a][0] = f32x4{0.f,0.f,0.f,0.f};
        mm3<1, 6>(planes + 12*PL, planes + 13*PL, planes + 14*PL, actH, actM, actL, acc);
#pragma unroll
        for (int ct = 0; ct < 4; ++ct) {
            const int colb = wv * 64 + ct * 16 + lng * 4;
            const float4 cc = *(const float4*)(c2cr + colb);
            float4 o; o.x = acc[ct][0][0] + cc.x; o.y = acc[ct][0][1] + cc.y;
            o.z = acc[ct][0][2] + cc.z; o.w = acc[ct][0][3] + cc.w;
            *(float4*)(U2cr + (row0 + ln15) * 256 + colb) = o;
        }
    }
    {
        f32x4 acc[4][1];
#pragma unroll
        for (int a = 0; a < 4; ++a) acc[a][0] = f32x4{0.f,0.f,0.f,0.f};
        mm3<1, 6>(planes + 15*PL, planes + 16*PL, planes + 17*PL, actH, actM, actL, acc);
#pragma unroll
        for (int ct = 0; ct < 4; ++ct) {
            const int colb = wv * 64 + ct * 16 + lng * 4;
            const float4 cc = *(const float4*)(c2tm + colb);
            float4 o; o.x = acc[ct][0][0] + cc.x; o.y = acc[ct][0][1] + cc.y;
            o.z = acc[ct][0][2] + cc.z; o.w = acc[ct][0][3] + cc.w;
            *(float4*)(U2tm + (row0 + ln15) * 256 + colb) = o;
        }
    }
}

// ---------------------------------------------------------------------------
// stage2m: 7200 rows, 450 blocks x 16 rows. cont1/rews1 + Ucr/Utm (permuted).
// ---------------------------------------------------------------------------
__global__ __launch_bounds__(256, 2) void stage2m_kernel(
    const float* __restrict__ U2cr, const float* __restrict__ U2tm,
    const short* __restrict__ planes,
    const float* __restrict__ crW0, const float* __restrict__ crB0,
    const float* __restrict__ crB1, const float* __restrict__ crW2, const float* __restrict__ crB2,
    const float* __restrict__ tmW0, const float* __restrict__ tmB0,
    const float* __restrict__ tmB1,
    const float* __restrict__ c2cr, const float* __restrict__ c2tm,
    float* __restrict__ cont1, float* __restrict__ rews1,
    float* __restrict__ Ucr, float* __restrict__ Utm)
{
    __shared__ short actH[16 * ASTR];
    __shared__ short actM[16 * ASTR];
    __shared__ short actL[16 * ASTR];
    __shared__ float hred[2][64];
    const int tid = threadIdx.x;
    const int row0 = blockIdx.x * 16;
    const int ln15 = tid & 15, lng = (tid >> 4) & 3, wv = tid >> 6;

    stage3w<16, false>(U2cr, crW0 + 65536, crB0, row0, actH, actM, actL);
    __syncthreads();
    {
        f32x4 acc[4][1];
#pragma unroll
        for (int a = 0; a < 4; ++a) acc[a][0] = f32x4{0.f,0.f,0.f,0.f};
        mm3<1, 6>(planes + 0*PL, planes + 1*PL, planes + 2*PL, actH, actM, actL, acc);
        float hp0 = 0.f, hp1 = 0.f;
#pragma unroll
        for (int ct = 0; ct < 4; ++ct) {
            const int colb = wv * 64 + ct * 16 + lng * 4;
            const float4 b1 = *(const float4*)(crB1 + colb);
            f32x4 v = acc[ct][0];
            v[0] += b1.x; v[1] += b1.y; v[2] += b1.z; v[3] += b1.w;
#pragma unroll
            for (int j = 0; j < 4; ++j) v[j] = fmaxf(v[j], 0.f);
#pragma unroll
            for (int j = 0; j < 4; ++j) {
                hp0 += v[j] * crW2[(colb + j) * 2 + 0];
                hp1 += v[j] * crW2[(colb + j) * 2 + 1];
            }
        }
        hp0 += __shfl_xor(hp0, 16); hp0 += __shfl_xor(hp0, 32);
        hp1 += __shfl_xor(hp1, 16); hp1 += __shfl_xor(hp1, 32);
        if (lng == 0) {
            hred[0][wv * 16 + ln15] = hp0;
            hred[1][wv * 16 + ln15] = hp1;
        }
        __syncthreads();
        if (tid < 16)
            cont1[row0 + tid] = hred[0][tid] + hred[0][16 + tid] + hred[0][32 + tid] + hred[0][48 + tid] + crB2[0];
        else if (tid >= 64 && tid < 80)
            rews1[row0 + tid - 64] = hred[1][tid - 64] + hred[1][16 + tid - 64] + hred[1][32 + tid - 64] + hred[1][48 + tid - 64] + crB2[1];
        __syncthreads();
    }

    stage3w<16, false>(U2tm, tmW0 + 65536, tmB0, row0, actH, actM, actL);
    __syncthreads();
    {
        f32x4 acc[4][1];
#pragma unroll
        for (int a = 0; a < 4; ++a) acc[a][0] = f32x4{0.f,0.f,0.f,0.f};
        mm3<1, 6>(planes + 3*PL, planes + 4*PL, planes + 5*PL, actH, actM, actL, acc);
        __syncthreads();
#pragma unroll
        for (int ct = 0; ct < 4; ++ct) {
            const int colb = wv * 64 + ct * 16 + lng * 4;
            const float4 bb = *(const float4*)(tmB1 + colb);
            f32x4 v = acc[ct][0];
            v[0] += bb.x; v[1] += bb.y; v[2] += bb.z; v[3] += bb.w;
#pragma unroll
            for (int j = 0; j < 4; ++j) v[j] = fmaxf(v[j], 0.f);
            float sv[4] = {v[0], v[1], v[2], v[3]};
            const int ao = ln15 * ASTR + colb;
            split3_write(sv, actH + ao, actM + ao, actL + ao);
        }
        __syncthreads();
    }
    int pr;
    {
        int r = row0 + ln15;
        int b = r / 225, a1 = (r / 15) % 15, a2 = r % 15;
        pr = (b * 15 + a2) * 15 + a1;
    }
    {
        f32x4 acc[4][1];
#pragma unroll
        for (int a = 0; a < 4; ++a) acc[a][0] = f32x4{0.f,0.f,0.f,0.f};
        mm3<1, 6>(planes + 12*PL, planes + 13*PL, planes + 14*PL, actH, actM, actL, acc);
#pragma unroll
        for (int ct = 0; ct < 4; ++ct) {
            const int colb = wv * 64 + ct * 16 + lng * 4;
            const float4 cc = *(const float4*)(c2cr + colb);
            float4 o; o.x = acc[ct][0][0] + cc.x; o.y = acc[ct][0][1] + cc.y;
            o.z = acc[ct][0][2] + cc.z; o.w = acc[ct][0][3] + cc.w;
            *(float4*)(Ucr + pr * 256 + colb) = o;
        }
    }
    {
        f32x4 acc[4][1];
#pragma unroll
        for (int a = 0; a < 4; ++a) acc[a][0] = f32x4{0.f,0.f,0.f,0.f};
        mm3<1, 3>(planes + 15*PL, planes + 16*PL, planes + 17*PL, actH, actM, actL, acc);
#pragma unroll
        for (int ct = 0; ct < 4; ++ct) {
            const int colb = wv * 64 + ct * 16 + lng * 4;
            const float4 cc = *(const float4*)(c2tm + colb);
            float4 o; o.x = acc[ct][0][0] + cc.x; o.y = acc[ct][0][1] + cc.y;
            o.z = acc[ct][0][2] + cc.z; o.w = acc[ct][0][3] + cc.w;
            *(float4*)(Utm + pr * 256 + colb) = o;
        }
    }
}

// ---------------------------------------------------------------------------
// layer_g2: 2-way (H,M) 3-pass 16x16x32 layer over RT*16-row act tile.
// ---------------------------------------------------------------------------
template<int RT, bool RELU, bool HEAD, bool WRITEACT>
__device__ __forceinline__ void layer_g2(
    const short* __restrict__ plH, const short* __restrict__ plL,
    const float* __restrict__ bias,
    const float* __restrict__ headW, const float* __restrict__ headB,
    float* __restrict__ headOut, int row0,
    short* actH, short* actL, float* hred)
{
    const int tid = threadIdx.x;
    const int ln15 = tid & 15, lng = (tid >> 4) & 3, wv = tid >> 6;
    const int wo = (wv * 64 + ln15) * 32 + lng * 8;
    f32x4 acc[4][RT];
#pragma unroll
    for (int a = 0; a < 4; ++a)
#pragma unroll
        for (int b = 0; b < RT; ++b) acc[a][b] = f32x4{0.f, 0.f, 0.f, 0.f};

#pragma unroll
    for (int kk = 0; kk < 8; ++kk) {
        bf16x8 aH[4], aL[4], bH[RT], bL[RT];
#pragma unroll
        for (int ct = 0; ct < 4; ++ct) {
            aH[ct] = *(const bf16x8*)(plH + wo + kk * 8192 + ct * 512);
            aL[ct] = *(const bf16x8*)(plL + wo + kk * 8192 + ct * 512);
        }
#pragma unroll
        for (int rt = 0; rt < RT; ++rt) {
            int off = (rt * 16 + ln15) * ASTR + kk * 32 + lng * 8;
            bH[rt] = *(const bf16x8*)(actH + off);
            bL[rt] = *(const bf16x8*)(actL + off);
        }
        __builtin_amdgcn_s_setprio(1);
#pragma unroll
        for (int ct = 0; ct < 4; ++ct)
#pragma unroll
            for (int rt = 0; rt < RT; ++rt) {
                acc[ct][rt] = __builtin_amdgcn_mfma_f32_16x16x32_bf16(aH[ct], bH[rt], acc[ct][rt], 0, 0, 0);
                acc[ct][rt] = __builtin_amdgcn_mfma_f32_16x16x32_bf16(aH[ct], bL[rt], acc[ct][rt], 0, 0, 0);
                acc[ct][rt] = __builtin_amdgcn_mfma_f32_16x16x32_bf16(aL[ct], bH[rt], acc[ct][rt], 0, 0, 0);
            }
        __builtin_amdgcn_s_setprio(0);
    }
    __syncthreads();

    float hp[RT];
#pragma unroll
    for (int rt = 0; rt < RT; ++rt) hp[rt] = 0.f;
#pragma unroll
    for (int ct = 0; ct < 4; ++ct) {
        const int colb = wv * 64 + ct * 16 + lng * 4;
        const float4 bb = *(const float4*)(bias + colb);
#pragma unroll
        for (int rt = 0; rt < RT; ++rt) {
            f32x4 v = acc[ct][rt];
            v[0] += bb.x; v[1] += bb.y; v[2] += bb.z; v[3] += bb.w;
            if (RELU) {
#pragma unroll
                for (int j = 0; j < 4; ++j) v[j] = fmaxf(v[j], 0.f);
            }
            if (HEAD) {
                const float4 hw = *(const float4*)(headW + colb);
                hp[rt] += v[0] * hw.x + v[1] * hw.y + v[2] * hw.z + v[3] * hw.w;
            }
            if (WRITEACT) {
                float sv[4] = {v[0], v[1], v[2], v[3]};
                const int ao = (rt * 16 + ln15) * ASTR + colb;
                split2_write(sv, actH + ao, actL + ao);
            }
        }
    }
    if constexpr (HEAD) {
        constexpr int NR = RT * 16;
#pragma unroll
        for (int rt = 0; rt < RT; ++rt) {
            hp[rt] += __shfl_xor(hp[rt], 16);
            hp[rt] += __shfl_xor(hp[rt], 32);
        }
        if (lng == 0) {
#pragma unroll
            for (int rt = 0; rt < RT; ++rt) hred[wv * NR + rt * 16 + ln15] = hp[rt];
        }
        __syncthreads();
        if (tid < NR && row0 + tid < 108000) {
            float s = hred[tid] + hred[NR + tid] + hred[2 * NR + tid] + hred[3 * NR + tid] + headB[0];
            headOut[row0 + tid] = s;
        }
    }
    if constexpr (WRITEACT) __syncthreads();
}

// ---------------------------------------------------------------------------
// k3ab: fused stage-3, 1 block/CU, maximal tiles for weight amortization.
// k3b: 844 x 128-row tiles (RT=8, last guarded). k3a: 1125 x 96-row (RT=6).
// Interleave 3:4 in groups of 7 (281 groups) + 2 remainder = 1969 blocks.
// LDS: max(2*128, 3*96)*ASTR*2 = 152064 B + hred 2KB <= 160K -> 1 block/CU.
// ---------------------------------------------------------------------------
__global__ __launch_bounds__(256, 1) void k3ab_kernel(
    const float* __restrict__ Ucr, const float* __restrict__ Utm,
    const short* __restrict__ planes,
    const float* __restrict__ crW0, const float* __restrict__ crB0,
    const float* __restrict__ crB1, const float* __restrict__ crW2,
    const float* __restrict__ crB2,
    const float* __restrict__ tmW0, const float* __restrict__ tmB0,
    const float* __restrict__ tmB1,
    const float* __restrict__ b45, const float* __restrict__ emB1,
    const float* __restrict__ w5, const float* __restrict__ b5,
    float* __restrict__ cont2, float* __restrict__ Vns3)
{
    __shared__ short lds[3 * 96 * ASTR];   // 152064 B (>= 2*128*ASTR = 135168)
    __shared__ float hred[512];
    const int tid = threadIdx.x;
    const int g = blockIdx.x / 7, rm = blockIdx.x % 7;
    bool isB; int idx;
    if (g < 281) {
        isB = rm < 3;
        idx = isB ? (g * 3 + rm) : (g * 4 + (rm - 3));
    } else {
        isB = rm < 1;
        idx = isB ? 843 : 1124;
    }
    const int ln15 = tid & 15, lng = (tid >> 4) & 3, wv = tid >> 6;
    const short* P = planes;

    if (isB) {
        const int row0 = idx * 128;
        short* actH = lds;
        short* actL = lds + 128 * ASTR;
        const int ln = tid & 63;
        const float4 wr = *(const float4*)(tmW0 + 65536 + ln * 4);
        const float4 bb = *(const float4*)(tmB0 + ln * 4);
        for (int i = wv * 32; i < wv * 32 + 32; ++i) {
            int r = row0 + i;
            int srow = r / 15;
            if (srow > 7199) srow = 7199;
            float a = (float)(r % 15);
            float4 u = *(const float4*)(Utm + srow * 256 + ln * 4);
            float sv[4];
            sv[0] = fmaxf(u.x + a * wr.x + bb.x, 0.f);
            sv[1] = fmaxf(u.y + a * wr.y + bb.y, 0.f);
            sv[2] = fmaxf(u.z + a * wr.z + bb.z, 0.f);
            sv[3] = fmaxf(u.w + a * wr.w + bb.w, 0.f);
            split2_write(sv, actH + i * ASTR + ln * 4, actL + i * ASTR + ln * 4);
        }
        __syncthreads();
        layer_g2<8, true,  false, true >(P + 3 * PL,  P + 4 * PL,  tmB1, nullptr, nullptr, nullptr, row0, actH, actL, hred);
        layer_g2<8, true,  false, true >(P + 9 * PL,  P + 10 * PL, b45,  nullptr, nullptr, nullptr, row0, actH, actL, hred);
        layer_g2<8, true,  true,  false>(P + 6 * PL,  P + 7 * PL,  emB1, w5, b5, Vns3, row0, actH, actL, hred);
    } else {
        const int row0 = idx * 96;
        short* actH = lds;
        short* actM = lds + 96 * ASTR;
        short* actL = lds + 2 * 96 * ASTR;
        stage3w<96, false>(Ucr, crW0 + 65536, crB0, row0, actH, actM, actL);
        __syncthreads();
        f32x4 acc[4][6];
#pragma unroll
        for (int a = 0; a < 4; ++a)
#pragma unroll
            for (int b = 0; b < 6; ++b) acc[a][b] = f32x4{0.f,0.f,0.f,0.f};
        mm3<6, 6>(P + 0*PL, P + 1*PL, P + 2*PL, actH, actM, actL, acc);
        float hp[6] = {0.f, 0.f, 0.f, 0.f, 0.f, 0.f};
#pragma unroll
        for (int ct = 0; ct < 4; ++ct) {
            const int colb = wv * 64 + ct * 16 + lng * 4;
            const float4 b1 = *(const float4*)(crB1 + colb);
#pragma unroll
            for (int rt = 0; rt < 6; ++rt) {
                f32x4 v = acc[ct][rt];
                v[0] += b1.x; v[1] += b1.y; v[2] += b1.z; v[3] += b1.w;
#pragma unroll
                for (int j = 0; j < 4; ++j) v[j] = fmaxf(v[j], 0.f);
#pragma unroll
                for (int j = 0; j < 4; ++j) hp[rt] += v[j] * crW2[(colb + j) * 2];
            }
        }
#pragma unroll
        for (int rt = 0; rt < 6; ++rt) {
            hp[rt] += __shfl_xor(hp[rt], 16);
            hp[rt] += __shfl_xor(hp[rt], 32);
        }
        if (lng == 0) {
#pragma unroll
            for (int rt = 0; rt < 6; ++rt) hred[wv * 96 + rt * 16 + ln15] = hp[rt];
        }
        __syncthreads();
        if (tid < 96)
            cont2[row0 + tid] = hred[tid] + hred[96 + tid] + hred[192 + tid] + hred[288 + tid] + crB2[0];
    }
}

extern "C" void kernel_launch(void* const* d_in, const int* in_sizes, int n_in,
                              void* d_out, int out_size, void* d_ws, size_t ws_size,
                              hipStream_t stream)
{
    (void)in_sizes; (void)n_in; (void)out_size; (void)ws_size;
    const float* x    = (const float*)d_in[0];
    const float* emW0 = (const float*)d_in[1];
    const float* emB0 = (const float*)d_in[2];
    const float* emW1 = (const float*)d_in[3];
    const float* emB1 = (const float*)d_in[4];
    const float* emW2 = (const float*)d_in[5];
    const float* emB2 = (const float*)d_in[6];
    const float* vW   = (const float*)d_in[7];
    const float* vb   = (const float*)d_in[8];
    const float* crW0 = (const float*)d_in[9];
    const float* crB0 = (const float*)d_in[10];
    const float* crW1 = (const float*)d_in[11];
    const float* crB1 = (const float*)d_in[12];
    const float* crW2 = (const float*)d_in[13];
    const float* crB2 = (const float*)d_in[14];
    const float* tmW0 = (const float*)d_in[15];
    const float* tmB0 = (const float*)d_in[16];
    const float* tmW1 = (const float*)d_in[17];
    const float* tmB1 = (const float*)d_in[18];
    const float* tmW2 = (const float*)d_in[19];
    const float* tmB2 = (const float*)d_in[20];
    float* out = (float*)d_out;

    float* w     = (float*)d_ws;
    float* rews0 = w;                     // 480
    float* cont1 = rews0 + 480;           // 7200
    float* rews1 = cont1 + 7200;          // 7200
    float* cont2 = rews1 + 7200;          // 108000
    float* Vns3  = cont2 + 108000;        // 108000
    float* U1cr  = Vns3 + 108000;         // 32*256
    float* U1tm  = U1cr + 32 * 256;       // 32*256
    short* planes = (short*)(U1tm + 32 * 256);  // 18 * PL shorts = 2.25 MB
    float* U2cr  = (float*)(planes + 18 * PL);  // 480*256
    float* U2tm  = U2cr + 480 * 256;            // 480*256
    float* Ucr   = U2tm + 480 * 256;            // 7200*256
    float* Utm   = Ucr + 7200 * 256;            // 7200*256
    float* w5    = Utm + 7200 * 256;            // 256
    float* b5    = w5 + 256;                    // 1 (pad to 4)
    float* c2cr  = b5 + 4;                      // 256
    float* c2tm  = c2cr + 256;                  // 256
    float* b45   = c2tm + 256;                  // 256

    front_kernel<<<66, 256, 0, stream>>>(x,
        emW0, emB0, emW1, emB1, emW2, emB2, vW, vb,
        crW0, crW1, tmW0, tmW1, tmW2, tmB2,
        planes, w5, b5, c2cr, c2tm, b45,
        out + NB * NA, U1cr, U1tm);
    stage1m_kernel<<<30, 256, 0, stream>>>(U1cr, U1tm, planes,
        crW0, crB0, crB1, crW2, crB2, tmW0, tmB0, tmB1,
        c2cr, c2tm, rews0, U2cr, U2tm);
    stage2m_kernel<<<450, 256, 0, stream>>>(U2cr, U2tm, planes,
        crW0, crB0, crB1, crW2, crB2, tmW0, tmB0, tmB1,
        c2cr, c2tm, cont1, rews1, Ucr, Utm);
    k3ab_kernel<<<1969, 256, 0, stream>>>(Ucr, Utm, planes,
        crW0, crB0, crB1, crW2, crB2,
        tmW0, tmB0, tmB1, b45, emB1, w5, b5, cont2, Vns3);
    finalize_kernel<<<NB, 256, 0, stream>>>(Vns3, cont2, rews0, rews1, cont1, out);
}

// Round 18
// 307.706 us; speedup vs baseline: 1.1323x; 1.1323x over previous
//
#include <hip/hip_runtime.h>

#define NA 15
#define NB 32
#define DD 256
#define PL 65536  // shorts per weight plane (8 slices x 256 cols x 32 k)
#define ASTR 264  // act LDS row stride (shorts)

using bf16x8 = __attribute__((ext_vector_type(8))) short;
using f32x4  = __attribute__((ext_vector_type(4))) float;

__device__ __forceinline__ unsigned short f2bf(float f){
  unsigned int u = __float_as_uint(f);
  u = u + 0x7fffu + ((u >> 16) & 1u);
  return (unsigned short)(u >> 16);
}
__device__ __forceinline__ float bf2f(unsigned short h){
  return __uint_as_float(((unsigned int)h) << 16);
}
__device__ __forceinline__ unsigned int cvtpk_bf16(float lo, float hi){
    unsigned int r;
    asm("v_cvt_pk_bf16_f32 %0, %1, %2" : "=v"(r) : "v"(lo), "v"(hi));
    return r;
}
__device__ __forceinline__ void split2_write(const float v[4], short* pH, short* pL){
    unsigned int h01 = cvtpk_bf16(v[0], v[1]);
    unsigned int h23 = cvtpk_bf16(v[2], v[3]);
    float r0 = v[0] - __uint_as_float(h01 << 16);
    float r1 = v[1] - __uint_as_float(h01 & 0xffff0000u);
    float r2 = v[2] - __uint_as_float(h23 << 16);
    float r3 = v[3] - __uint_as_float(h23 & 0xffff0000u);
    unsigned int l01 = cvtpk_bf16(r0, r1);
    unsigned int l23 = cvtpk_bf16(r2, r3);
    *(uint2*)pH = make_uint2(h01, h23);
    *(uint2*)pL = make_uint2(l01, l23);
}
__device__ __forceinline__ void split3_write(const float v[4], short* pH, short* pM, short* pL){
    unsigned int h01 = cvtpk_bf16(v[0], v[1]);
    unsigned int h23 = cvtpk_bf16(v[2], v[3]);
    float r0 = v[0] - __uint_as_float(h01 << 16);
    float r1 = v[1] - __uint_as_float(h01 & 0xffff0000u);
    float r2 = v[2] - __uint_as_float(h23 << 16);
    float r3 = v[3] - __uint_as_float(h23 & 0xffff0000u);
    unsigned int m01 = cvtpk_bf16(r0, r1);
    unsigned int m23 = cvtpk_bf16(r2, r3);
    float s0 = r0 - __uint_as_float(m01 << 16);
    float s1 = r1 - __uint_as_float(m01 & 0xffff0000u);
    float s2 = r2 - __uint_as_float(m23 << 16);
    float s3 = r3 - __uint_as_float(m23 & 0xffff0000u);
    unsigned int l01 = cvtpk_bf16(s0, s1);
    unsigned int l23 = cvtpk_bf16(s2, s3);
    *(uint2*)pH = make_uint2(h01, h23);
    *(uint2*)pM = make_uint2(m01, m23);
    *(uint2*)pL = make_uint2(l01, l23);
}

// ---------------------------------------------------------------------------
// fp32 VALU primitives (value_x branch of front kernel)
// ---------------------------------------------------------------------------
template<int TM, bool RELU>
__device__ __forceinline__ void layer256(
    const float* __restrict__ W, const float* __restrict__ bias,
    const float* act, int K, int lda, float* out, int ldo)
{
    constexpr int RPG = TM / 4;
    const int tid = threadIdx.x;
    const int tr = tid >> 6;
    const int tc = tid & 63;
    float acc[RPG][4];
#pragma unroll
    for (int i = 0; i < RPG; ++i) { acc[i][0]=0.f; acc[i][1]=0.f; acc[i][2]=0.f; acc[i][3]=0.f; }
    const float* wp = W + 4 * tc;
    int k = 0;
    for (; k + 4 <= K; k += 4) {
        float4 w0 = *reinterpret_cast<const float4*>(wp + (k + 0) * DD);
        float4 w1 = *reinterpret_cast<const float4*>(wp + (k + 1) * DD);
        float4 w2 = *reinterpret_cast<const float4*>(wp + (k + 2) * DD);
        float4 w3 = *reinterpret_cast<const float4*>(wp + (k + 3) * DD);
#pragma unroll
        for (int i = 0; i < RPG; ++i) {
            float4 a = *reinterpret_cast<const float4*>(act + (RPG * tr + i) * lda + k);
            acc[i][0] += a.x * w0.x + a.y * w1.x + a.z * w2.x + a.w * w3.x;
            acc[i][1] += a.x * w0.y + a.y * w1.y + a.z * w2.y + a.w * w3.y;
            acc[i][2] += a.x * w0.z + a.y * w1.z + a.z * w2.z + a.w * w3.z;
            acc[i][3] += a.x * w0.w + a.y * w1.w + a.z * w2.w + a.w * w3.w;
        }
    }
    for (; k < K; ++k) {
        float4 w0 = *reinterpret_cast<const float4*>(wp + k * DD);
#pragma unroll
        for (int i = 0; i < RPG; ++i) {
            float a = act[(RPG * tr + i) * lda + k];
            acc[i][0] += a * w0.x; acc[i][1] += a * w0.y;
            acc[i][2] += a * w0.z; acc[i][3] += a * w0.w;
        }
    }
    float4 bb = *reinterpret_cast<const float4*>(bias + 4 * tc);
#pragma unroll
    for (int i = 0; i < RPG; ++i) {
        float4 o;
        o.x = acc[i][0] + bb.x; o.y = acc[i][1] + bb.y;
        o.z = acc[i][2] + bb.z; o.w = acc[i][3] + bb.w;
        if (RELU) {
            o.x = fmaxf(o.x, 0.f); o.y = fmaxf(o.y, 0.f);
            o.z = fmaxf(o.z, 0.f); o.w = fmaxf(o.w, 0.f);
        }
        *reinterpret_cast<float4*>(out + (RPG * tr + i) * ldo + 4 * tc) = o;
    }
}

template<int TM>
__device__ __forceinline__ void head1c(
    const float* h, int ldh, const float* __restrict__ W, int wstr, int col, float bias,
    float* __restrict__ gout, int gbase)
{
    const int wv = threadIdx.x >> 6;
    const int lane = threadIdx.x & 63;
    for (int rr = wv; rr < TM; rr += 4) {
        float p = 0.f;
#pragma unroll
        for (int t = 0; t < 4; ++t) {
            int k = lane + 64 * t;
            p += h[rr * ldh + k] * W[k * wstr + col];
        }
#pragma unroll
        for (int m = 1; m < 64; m <<= 1) p += __shfl_xor(p, m);
        if (lane == 0) gout[gbase + rr] = p + bias;
    }
}

// ---------------------------------------------------------------------------
// front_kernel (unchanged from R15/R16)
// ---------------------------------------------------------------------------
__global__ __launch_bounds__(256) void front_kernel(
    const float* __restrict__ x,
    const float* __restrict__ emW0, const float* __restrict__ emB0,
    const float* __restrict__ emW1, const float* __restrict__ emB1,
    const float* __restrict__ emW2, const float* __restrict__ emB2,
    const float* __restrict__ vW, const float* __restrict__ vb,
    const float* __restrict__ crW0, const float* __restrict__ crW1,
    const float* __restrict__ tmW0, const float* __restrict__ tmW1,
    const float* __restrict__ tmW2, const float* __restrict__ tmB2,
    short* __restrict__ planes, float* __restrict__ w5, float* __restrict__ b5,
    float* __restrict__ c2cr, float* __restrict__ c2tm, float* __restrict__ b45,
    float* __restrict__ vout, float* __restrict__ U1cr, float* __restrict__ U1tm)
{
    __shared__ __align__(16) float smem[32 * DD];
    const int blk = blockIdx.x;
    const int tid = threadIdx.x;

    if (blk < 24) {
        const int mat = blk >> 3;
        const int kk  = blk & 7;
        const float* W = (mat == 0) ? crW1 : (mat == 1) ? tmW1 : emW1;
        const int col = tid;
        short bh[32], bm[32], bl[32];
#pragma unroll
        for (int j = 0; j < 32; ++j) {
            float w = W[(kk * 32 + j) * 256 + col];
            unsigned short h = f2bf(w); float fh = bf2f(h);
            float r1 = w - fh;
            unsigned short m = f2bf(r1); float fm = bf2f(m);
            bh[j] = (short)h; bm[j] = (short)m; bl[j] = (short)f2bf(r1 - fm);
        }
        short* pH = planes + (size_t)(mat * 3 + 0) * PL + kk * 8192 + col * 32;
        short* pM = planes + (size_t)(mat * 3 + 1) * PL + kk * 8192 + col * 32;
        short* pLp = planes + (size_t)(mat * 3 + 2) * PL + kk * 8192 + col * 32;
#pragma unroll
        for (int j = 0; j < 32; j += 4) {
            *(short4*)(pH + j) = make_short4(bh[j], bh[j+1], bh[j+2], bh[j+3]);
            *(short4*)(pM + j) = make_short4(bm[j], bm[j+1], bm[j+2], bm[j+3]);
            *(short4*)(pLp + j) = make_short4(bl[j], bl[j+1], bl[j+2], bl[j+3]);
        }
    } else if (blk == 24) {
        float acc = 0.f;
        for (int j = 0; j < 256; j += 4) {
            float4 wrow = *(const float4*)(emW2 + tid * 256 + j);
            float4 vv   = *(const float4*)(vW + j);
            acc += wrow.x * vv.x + wrow.y * vv.y + wrow.z * vv.z + wrow.w * vv.w;
        }
        w5[tid] = acc;
        if (tid == 0) {
            float b = 0.f;
            for (int j = 0; j < 256; ++j) b += emB2[j] * vW[j];
            b5[0] = b + vb[0];
        }
    } else if (blk < 33) {
        constexpr int TM = 4;
        float* bufA = smem;
        float* bufB = bufA + TM * DD;
        float* bufC = bufB + TM * DD;
        const int row0 = (blk - 25) * TM;
        for (int i = 0; i < TM; ++i) bufA[i * DD + tid] = x[(row0 + i) * DD + tid];
        __syncthreads();
        layer256<TM, true >(emW0, emB0, bufA, 256, DD, bufB, DD); __syncthreads();
        layer256<TM, true >(emW1, emB1, bufB, 256, DD, bufC, DD); __syncthreads();
        layer256<TM, false>(emW2, emB2, bufC, 256, DD, bufB, DD); __syncthreads();
        head1c<TM>(bufB, DD, vW, 1, 0, vb[0], vout, row0);
    } else if (blk < 41) {
        const int row0 = (blk - 33) * 4;
        float* xs = smem;   // [4][256]
        for (int i = 0; i < 4; ++i) xs[i * 256 + tid] = x[(row0 + i) * 256 + tid];
        __syncthreads();
        float acr[4] = {0.f,0.f,0.f,0.f}, atm[4] = {0.f,0.f,0.f,0.f};
        for (int k = 0; k < 256; ++k) {
            float wc = crW0[k * 256 + tid];
            float wt = tmW0[k * 256 + tid];
#pragma unroll
            for (int i = 0; i < 4; ++i) {
                acr[i] += xs[i * 256 + k] * wc;
                atm[i] += xs[i * 256 + k] * wt;
            }
        }
        for (int i = 0; i < 4; ++i) {
            U1cr[(row0 + i) * 256 + tid] = acr[i];
            U1tm[(row0 + i) * 256 + tid] = atm[i];
        }
    } else if (blk < 65) {
        const int pb = blk - 41;
        const int prod = pb >> 3;           // 0=W45, 1=W2cr, 2=W2tm
        const int r0 = (pb & 7) * 32;
        const float* B = (prod == 0) ? emW0 : (prod == 1) ? crW0 : tmW0;
        const int pbase = 9 + prod * 3;
        float* As = smem;   // [32][256]
        for (int i = tid; i < 32 * 256; i += 256)
            As[i] = tmW2[(r0 + (i >> 8)) * 256 + (i & 255)];
        __syncthreads();
        float acc[32];
#pragma unroll
        for (int j = 0; j < 32; ++j) acc[j] = 0.f;
        for (int m = 0; m < 256; ++m) {
            float b = B[m * 256 + tid];
#pragma unroll
            for (int j = 0; j < 32; ++j) acc[j] += As[j * 256 + m] * b;
        }
        short bh[32], bm[32], bl[32];
#pragma unroll
        for (int j = 0; j < 32; ++j) {
            float w = acc[j];
            unsigned short h = f2bf(w); float fh = bf2f(h);
            float r1 = w - fh;
            unsigned short mm = f2bf(r1); float fm = bf2f(mm);
            bh[j] = (short)h; bm[j] = (short)mm; bl[j] = (short)f2bf(r1 - fm);
        }
        const int kk = r0 >> 5;
        short* pH = planes + (size_t)(pbase + 0) * PL + kk * 8192 + tid * 32;
        short* pM = planes + (size_t)(pbase + 1) * PL + kk * 8192 + tid * 32;
        short* pLp = planes + (size_t)(pbase + 2) * PL + kk * 8192 + tid * 32;
#pragma unroll
        for (int j = 0; j < 32; j += 4) {
            *(short4*)(pH + j) = make_short4(bh[j], bh[j+1], bh[j+2], bh[j+3]);
            *(short4*)(pM + j) = make_short4(bm[j], bm[j+1], bm[j+2], bm[j+3]);
            *(short4*)(pLp + j) = make_short4(bl[j], bl[j+1], bl[j+2], bl[j+3]);
        }
    } else {
        const int j = tid;
        float a0 = 0.f, a1 = 0.f, a2 = 0.f;
        for (int k = 0; k < 256; ++k) {
            float t = tmB2[k];
            a0 += t * crW0[k * 256 + j];
            a1 += t * tmW0[k * 256 + j];
            a2 += t * emW0[k * 256 + j];
        }
        c2cr[j] = a0;
        c2tm[j] = a1;
        b45[j] = a2 + emB0[j];
    }
}

__global__ __launch_bounds__(256) void finalize_kernel(
    const float* __restrict__ Vns3, const float* __restrict__ cont2,
    const float* __restrict__ rews0, const float* __restrict__ rews1,
    const float* __restrict__ cont1, float* __restrict__ out)
{
    const int b = blockIdx.x;
    const int tid = threadIdx.x;
    __shared__ float vs2[NA][NA];
    __shared__ float vs3[NA];
    if (tid < NA * NA) {
        const int x = tid / NA, y = tid % NA;
        float vals[NA];
        float m = -INFINITY;
#pragma unroll
        for (int z = 0; z < NA; ++z) {
            int vidx = ((b * NA + y) * NA + z) * NA + x;
            int cidx = ((b * NA + x) * NA + y) * NA + z;
            float c1 = rews0[b * NA + z] * 0.99f;
            float c2 = (c1 + rews1[(b * NA + x) * NA + z]) * 0.99f;
            float v = Vns3[vidx] * 0.970299f + c2;
            if (cont2[cidx] > 0.f) v = 0.f;
            vals[z] = v;
            m = fmaxf(m, v);
        }
        float se = 0.f, sw = 0.f;
#pragma unroll
        for (int z = 0; z < NA; ++z) { float e = expf(vals[z] - m); se += e; sw += e * vals[z]; }
        vs2[x][y] = sw / se;
    }
    __syncthreads();
    if (tid < NA) {
        const int x = tid;
        float vals[NA];
        float m = -INFINITY;
#pragma unroll
        for (int y = 0; y < NA; ++y) {
            float v = vs2[x][y];
            if (cont1[(b * NA + x) * NA + y] > 0.f) v = 0.f;
            vals[y] = v;
            m = fmaxf(m, v);
        }
        float se = 0.f, sw = 0.f;
#pragma unroll
        for (int y = 0; y < NA; ++y) { float e = expf(vals[y] - m); se += e; sw += e * vals[y]; }
        vs3[x] = sw / se;
    }
    __syncthreads();
    if (tid == 0) {
        float m = -INFINITY;
#pragma unroll
        for (int x = 0; x < NA; ++x) m = fmaxf(m, vs3[x]);
        float se = 0.f;
#pragma unroll
        for (int x = 0; x < NA; ++x) se += expf(vs3[x] - m);
        float l = logf(se);
#pragma unroll
        for (int x = 0; x < NA; ++x) out[b * NA + x] = vs3[x] - m - l;
    }
}

// ---------------------------------------------------------------------------
// mm3: accumulate RT row-tiles x 4 col-tiles over K=256 with NP passes.
// ---------------------------------------------------------------------------
template<int RT, int NP>
__device__ __forceinline__ void mm3(
    const short* __restrict__ plH, const short* __restrict__ plM, const short* __restrict__ plL,
    const short* actH, const short* actM, const short* actL,
    f32x4 (&acc)[4][RT])
{
    const int tid = threadIdx.x;
    const int ln15 = tid & 15, lng = (tid >> 4) & 3, wv = tid >> 6;
    const int wo = (wv * 64 + ln15) * 32 + lng * 8;
#pragma unroll
    for (int kk = 0; kk < 8; ++kk) {
        bf16x8 wH[4], wM[4], wL[4], xH[RT], xM[RT], xL[RT];
#pragma unroll
        for (int ct = 0; ct < 4; ++ct) {
            wH[ct] = *(const bf16x8*)(plH + wo + kk * 8192 + ct * 512);
            wM[ct] = *(const bf16x8*)(plM + wo + kk * 8192 + ct * 512);
            if (NP == 6) wL[ct] = *(const bf16x8*)(plL + wo + kk * 8192 + ct * 512);
        }
#pragma unroll
        for (int rt = 0; rt < RT; ++rt) {
            int off = (rt * 16 + ln15) * ASTR + kk * 32 + lng * 8;
            xH[rt] = *(const bf16x8*)(actH + off);
            xM[rt] = *(const bf16x8*)(actM + off);
            if (NP == 6) xL[rt] = *(const bf16x8*)(actL + off);
        }
        __builtin_amdgcn_s_setprio(1);
#pragma unroll
        for (int ct = 0; ct < 4; ++ct)
#pragma unroll
            for (int rt = 0; rt < RT; ++rt) {
                acc[ct][rt] = __builtin_amdgcn_mfma_f32_16x16x32_bf16(wH[ct], xH[rt], acc[ct][rt], 0, 0, 0);
                acc[ct][rt] = __builtin_amdgcn_mfma_f32_16x16x32_bf16(wH[ct], xM[rt], acc[ct][rt], 0, 0, 0);
                acc[ct][rt] = __builtin_amdgcn_mfma_f32_16x16x32_bf16(wM[ct], xH[rt], acc[ct][rt], 0, 0, 0);
                if (NP == 6) {
                    acc[ct][rt] = __builtin_amdgcn_mfma_f32_16x16x32_bf16(wM[ct], xM[rt], acc[ct][rt], 0, 0, 0);
                    acc[ct][rt] = __builtin_amdgcn_mfma_f32_16x16x32_bf16(wH[ct], xL[rt], acc[ct][rt], 0, 0, 0);
                    acc[ct][rt] = __builtin_amdgcn_mfma_f32_16x16x32_bf16(wL[ct], xH[rt], acc[ct][rt], 0, 0, 0);
                }
            }
        __builtin_amdgcn_s_setprio(0);
    }
}

// stage a 3-way-split activation row block from U + a*wrow + bias (relu)
template<int ROWS, bool CLAMP>
__device__ __forceinline__ void stage3w(
    const float* __restrict__ U, const float* __restrict__ wrow256,
    const float* __restrict__ bias, int row0,
    short* actH, short* actM, short* actL)
{
    const int tid = threadIdx.x;
    const int wv = tid >> 6, ln = tid & 63;
    constexpr int RPW = ROWS / 4;
    const float4 wr = *(const float4*)(wrow256 + ln * 4);
    const float4 bb = *(const float4*)(bias + ln * 4);
    for (int i = wv * RPW; i < wv * RPW + RPW; ++i) {
        int r = row0 + i;
        int srow = r / 15;
        if (CLAMP && srow > 7199) srow = 7199;
        float a = (float)(r % 15);
        float4 u = *(const float4*)(U + srow * 256 + ln * 4);
        float sv[4];
        sv[0] = fmaxf(u.x + a * wr.x + bb.x, 0.f);
        sv[1] = fmaxf(u.y + a * wr.y + bb.y, 0.f);
        sv[2] = fmaxf(u.z + a * wr.z + bb.z, 0.f);
        sv[3] = fmaxf(u.w + a * wr.w + bb.w, 0.f);
        split3_write(sv, actH + i * ASTR + ln * 4, actM + i * ASTR + ln * 4, actL + i * ASTR + ln * 4);
    }
}

// ---------------------------------------------------------------------------
// stage1m: 480 rows (b,a1), 30 blocks x 16 rows. rews0 + U2cr/U2tm.
// ---------------------------------------------------------------------------
__global__ __launch_bounds__(256, 2) void stage1m_kernel(
    const float* __restrict__ U1cr, const float* __restrict__ U1tm,
    const short* __restrict__ planes,
    const float* __restrict__ crW0, const float* __restrict__ crB0,
    const float* __restrict__ crB1, const float* __restrict__ crW2, const float* __restrict__ crB2,
    const float* __restrict__ tmW0, const float* __restrict__ tmB0,
    const float* __restrict__ tmB1,
    const float* __restrict__ c2cr, const float* __restrict__ c2tm,
    float* __restrict__ rews0, float* __restrict__ U2cr, float* __restrict__ U2tm)
{
    __shared__ short actH[16 * ASTR];
    __shared__ short actM[16 * ASTR];
    __shared__ short actL[16 * ASTR];
    __shared__ float hred[64];
    const int tid = threadIdx.x;
    const int row0 = blockIdx.x * 16;
    const int ln15 = tid & 15, lng = (tid >> 4) & 3, wv = tid >> 6;

    stage3w<16, false>(U1cr, crW0 + 65536, crB0, row0, actH, actM, actL);
    __syncthreads();
    {
        f32x4 acc[4][1];
#pragma unroll
        for (int a = 0; a < 4; ++a) acc[a][0] = f32x4{0.f,0.f,0.f,0.f};
        mm3<1, 6>(planes + 0*PL, planes + 1*PL, planes + 2*PL, actH, actM, actL, acc);
        float hp = 0.f;
#pragma unroll
        for (int ct = 0; ct < 4; ++ct) {
            const int colb = wv * 64 + ct * 16 + lng * 4;
            const float4 b1 = *(const float4*)(crB1 + colb);
            f32x4 v = acc[ct][0];
            v[0] += b1.x; v[1] += b1.y; v[2] += b1.z; v[3] += b1.w;
#pragma unroll
            for (int j = 0; j < 4; ++j) v[j] = fmaxf(v[j], 0.f);
#pragma unroll
            for (int j = 0; j < 4; ++j) hp += v[j] * crW2[(colb + j) * 2 + 1];
        }
        hp += __shfl_xor(hp, 16);
        hp += __shfl_xor(hp, 32);
        if (lng == 0) hred[wv * 16 + ln15] = hp;
        __syncthreads();
        if (tid < 16) rews0[row0 + tid] = hred[tid] + hred[16 + tid] + hred[32 + tid] + hred[48 + tid] + crB2[1];
        __syncthreads();
    }

    stage3w<16, false>(U1tm, tmW0 + 65536, tmB0, row0, actH, actM, actL);
    __syncthreads();
    {
        f32x4 acc[4][1];
#pragma unroll
        for (int a = 0; a < 4; ++a) acc[a][0] = f32x4{0.f,0.f,0.f,0.f};
        mm3<1, 6>(planes + 3*PL, planes + 4*PL, planes + 5*PL, actH, actM, actL, acc);
        __syncthreads();
#pragma unroll
        for (int ct = 0; ct < 4; ++ct) {
            const int colb = wv * 64 + ct * 16 + lng * 4;
            const float4 bb = *(const float4*)(tmB1 + colb);
            f32x4 v = acc[ct][0];
            v[0] += bb.x; v[1] += bb.y; v[2] += bb.z; v[3] += bb.w;
#pragma unroll
            for (int j = 0; j < 4; ++j) v[j] = fmaxf(v[j], 0.f);
            float sv[4] = {v[0], v[1], v[2], v[3]};
            const int ao = ln15 * ASTR + colb;
            split3_write(sv, actH + ao, actM + ao, actL + ao);
        }
        __syncthreads();
    }
    {
        f32x4 acc[4][1];
#pragma unroll
        for (int a = 0; a < 4; ++a) acc[a][0] = f32x4{0.f,0.f,0.f,0.f};
        mm3<1, 6>(planes + 12*PL, planes + 13*PL, planes + 14*PL, actH, actM, actL, acc);
#pragma unroll
        for (int ct = 0; ct < 4; ++ct) {
            const int colb = wv * 64 + ct * 16 + lng * 4;
            const float4 cc = *(const float4*)(c2cr + colb);
            float4 o; o.x = acc[ct][0][0] + cc.x; o.y = acc[ct][0][1] + cc.y;
            o.z = acc[ct][0][2] + cc.z; o.w = acc[ct][0][3] + cc.w;
            *(float4*)(U2cr + (row0 + ln15) * 256 + colb) = o;
        }
    }
    {
        f32x4 acc[4][1];
#pragma unroll
        for (int a = 0; a < 4; ++a) acc[a][0] = f32x4{0.f,0.f,0.f,0.f};
        mm3<1, 6>(planes + 15*PL, planes + 16*PL, planes + 17*PL, actH, actM, actL, acc);
#pragma unroll
        for (int ct = 0; ct < 4; ++ct) {
            const int colb = wv * 64 + ct * 16 + lng * 4;
            const float4 cc = *(const float4*)(c2tm + colb);
            float4 o; o.x = acc[ct][0][0] + cc.x; o.y = acc[ct][0][1] + cc.y;
            o.z = acc[ct][0][2] + cc.z; o.w = acc[ct][0][3] + cc.w;
            *(float4*)(U2tm + (row0 + ln15) * 256 + colb) = o;
        }
    }
}

// ---------------------------------------------------------------------------
// stage2m: 7200 rows, 450 blocks x 16 rows. cont1/rews1 + Ucr/Utm (permuted).
// ---------------------------------------------------------------------------
__global__ __launch_bounds__(256, 2) void stage2m_kernel(
    const float* __restrict__ U2cr, const float* __restrict__ U2tm,
    const short* __restrict__ planes,
    const float* __restrict__ crW0, const float* __restrict__ crB0,
    const float* __restrict__ crB1, const float* __restrict__ crW2, const float* __restrict__ crB2,
    const float* __restrict__ tmW0, const float* __restrict__ tmB0,
    const float* __restrict__ tmB1,
    const float* __restrict__ c2cr, const float* __restrict__ c2tm,
    float* __restrict__ cont1, float* __restrict__ rews1,
    float* __restrict__ Ucr, float* __restrict__ Utm)
{
    __shared__ short actH[16 * ASTR];
    __shared__ short actM[16 * ASTR];
    __shared__ short actL[16 * ASTR];
    __shared__ float hred[2][64];
    const int tid = threadIdx.x;
    const int row0 = blockIdx.x * 16;
    const int ln15 = tid & 15, lng = (tid >> 4) & 3, wv = tid >> 6;

    stage3w<16, false>(U2cr, crW0 + 65536, crB0, row0, actH, actM, actL);
    __syncthreads();
    {
        f32x4 acc[4][1];
#pragma unroll
        for (int a = 0; a < 4; ++a) acc[a][0] = f32x4{0.f,0.f,0.f,0.f};
        mm3<1, 6>(planes + 0*PL, planes + 1*PL, planes + 2*PL, actH, actM, actL, acc);
        float hp0 = 0.f, hp1 = 0.f;
#pragma unroll
        for (int ct = 0; ct < 4; ++ct) {
            const int colb = wv * 64 + ct * 16 + lng * 4;
            const float4 b1 = *(const float4*)(crB1 + colb);
            f32x4 v = acc[ct][0];
            v[0] += b1.x; v[1] += b1.y; v[2] += b1.z; v[3] += b1.w;
#pragma unroll
            for (int j = 0; j < 4; ++j) v[j] = fmaxf(v[j], 0.f);
#pragma unroll
            for (int j = 0; j < 4; ++j) {
                hp0 += v[j] * crW2[(colb + j) * 2 + 0];
                hp1 += v[j] * crW2[(colb + j) * 2 + 1];
            }
        }
        hp0 += __shfl_xor(hp0, 16); hp0 += __shfl_xor(hp0, 32);
        hp1 += __shfl_xor(hp1, 16); hp1 += __shfl_xor(hp1, 32);
        if (lng == 0) {
            hred[0][wv * 16 + ln15] = hp0;
            hred[1][wv * 16 + ln15] = hp1;
        }
        __syncthreads();
        if (tid < 16)
            cont1[row0 + tid] = hred[0][tid] + hred[0][16 + tid] + hred[0][32 + tid] + hred[0][48 + tid] + crB2[0];
        else if (tid >= 64 && tid < 80)
            rews1[row0 + tid - 64] = hred[1][tid - 64] + hred[1][16 + tid - 64] + hred[1][32 + tid - 64] + hred[1][48 + tid - 64] + crB2[1];
        __syncthreads();
    }

    stage3w<16, false>(U2tm, tmW0 + 65536, tmB0, row0, actH, actM, actL);
    __syncthreads();
    {
        f32x4 acc[4][1];
#pragma unroll
        for (int a = 0; a < 4; ++a) acc[a][0] = f32x4{0.f,0.f,0.f,0.f};
        mm3<1, 6>(planes + 3*PL, planes + 4*PL, planes + 5*PL, actH, actM, actL, acc);
        __syncthreads();
#pragma unroll
        for (int ct = 0; ct < 4; ++ct) {
            const int colb = wv * 64 + ct * 16 + lng * 4;
            const float4 bb = *(const float4*)(tmB1 + colb);
            f32x4 v = acc[ct][0];
            v[0] += bb.x; v[1] += bb.y; v[2] += bb.z; v[3] += bb.w;
#pragma unroll
            for (int j = 0; j < 4; ++j) v[j] = fmaxf(v[j], 0.f);
            float sv[4] = {v[0], v[1], v[2], v[3]};
            const int ao = ln15 * ASTR + colb;
            split3_write(sv, actH + ao, actM + ao, actL + ao);
        }
        __syncthreads();
    }
    int pr;
    {
        int r = row0 + ln15;
        int b = r / 225, a1 = (r / 15) % 15, a2 = r % 15;
        pr = (b * 15 + a2) * 15 + a1;
    }
    {
        f32x4 acc[4][1];
#pragma unroll
        for (int a = 0; a < 4; ++a) acc[a][0] = f32x4{0.f,0.f,0.f,0.f};
        mm3<1, 6>(planes + 12*PL, planes + 13*PL, planes + 14*PL, actH, actM, actL, acc);
#pragma unroll
        for (int ct = 0; ct < 4; ++ct) {
            const int colb = wv * 64 + ct * 16 + lng * 4;
            const float4 cc = *(const float4*)(c2cr + colb);
            float4 o; o.x = acc[ct][0][0] + cc.x; o.y = acc[ct][0][1] + cc.y;
            o.z = acc[ct][0][2] + cc.z; o.w = acc[ct][0][3] + cc.w;
            *(float4*)(Ucr + pr * 256 + colb) = o;
        }
    }
    {
        f32x4 acc[4][1];
#pragma unroll
        for (int a = 0; a < 4; ++a) acc[a][0] = f32x4{0.f,0.f,0.f,0.f};
        mm3<1, 3>(planes + 15*PL, planes + 16*PL, planes + 17*PL, actH, actM, actL, acc);
#pragma unroll
        for (int ct = 0; ct < 4; ++ct) {
            const int colb = wv * 64 + ct * 16 + lng * 4;
            const float4 cc = *(const float4*)(c2tm + colb);
            float4 o; o.x = acc[ct][0][0] + cc.x; o.y = acc[ct][0][1] + cc.y;
            o.z = acc[ct][0][2] + cc.z; o.w = acc[ct][0][3] + cc.w;
            *(float4*)(Utm + pr * 256 + colb) = o;
        }
    }
}

// ---------------------------------------------------------------------------
// layer_g2: 2-way (H,M) 3-pass 16x16x32 layer over RT*16-row act tile.
// ---------------------------------------------------------------------------
template<int RT, bool RELU, bool HEAD, bool WRITEACT>
__device__ __forceinline__ void layer_g2(
    const short* __restrict__ plH, const short* __restrict__ plL,
    const float* __restrict__ bias,
    const float* __restrict__ headW, const float* __restrict__ headB,
    float* __restrict__ headOut, int row0,
    short* actH, short* actL, float* hred)
{
    const int tid = threadIdx.x;
    const int ln15 = tid & 15, lng = (tid >> 4) & 3, wv = tid >> 6;
    const int wo = (wv * 64 + ln15) * 32 + lng * 8;
    f32x4 acc[4][RT];
#pragma unroll
    for (int a = 0; a < 4; ++a)
#pragma unroll
        for (int b = 0; b < RT; ++b) acc[a][b] = f32x4{0.f, 0.f, 0.f, 0.f};

#pragma unroll
    for (int kk = 0; kk < 8; ++kk) {
        bf16x8 aH[4], aL[4], bH[RT], bL[RT];
#pragma unroll
        for (int ct = 0; ct < 4; ++ct) {
            aH[ct] = *(const bf16x8*)(plH + wo + kk * 8192 + ct * 512);
            aL[ct] = *(const bf16x8*)(plL + wo + kk * 8192 + ct * 512);
        }
#pragma unroll
        for (int rt = 0; rt < RT; ++rt) {
            int off = (rt * 16 + ln15) * ASTR + kk * 32 + lng * 8;
            bH[rt] = *(const bf16x8*)(actH + off);
            bL[rt] = *(const bf16x8*)(actL + off);
        }
        __builtin_amdgcn_s_setprio(1);
#pragma unroll
        for (int ct = 0; ct < 4; ++ct)
#pragma unroll
            for (int rt = 0; rt < RT; ++rt) {
                acc[ct][rt] = __builtin_amdgcn_mfma_f32_16x16x32_bf16(aH[ct], bH[rt], acc[ct][rt], 0, 0, 0);
                acc[ct][rt] = __builtin_amdgcn_mfma_f32_16x16x32_bf16(aH[ct], bL[rt], acc[ct][rt], 0, 0, 0);
                acc[ct][rt] = __builtin_amdgcn_mfma_f32_16x16x32_bf16(aL[ct], bH[rt], acc[ct][rt], 0, 0, 0);
            }
        __builtin_amdgcn_s_setprio(0);
    }
    __syncthreads();

    float hp[RT];
#pragma unroll
    for (int rt = 0; rt < RT; ++rt) hp[rt] = 0.f;
#pragma unroll
    for (int ct = 0; ct < 4; ++ct) {
        const int colb = wv * 64 + ct * 16 + lng * 4;
        const float4 bb = *(const float4*)(bias + colb);
#pragma unroll
        for (int rt = 0; rt < RT; ++rt) {
            f32x4 v = acc[ct][rt];
            v[0] += bb.x; v[1] += bb.y; v[2] += bb.z; v[3] += bb.w;
            if (RELU) {
#pragma unroll
                for (int j = 0; j < 4; ++j) v[j] = fmaxf(v[j], 0.f);
            }
            if (HEAD) {
                const float4 hw = *(const float4*)(headW + colb);
                hp[rt] += v[0] * hw.x + v[1] * hw.y + v[2] * hw.z + v[3] * hw.w;
            }
            if (WRITEACT) {
                float sv[4] = {v[0], v[1], v[2], v[3]};
                const int ao = (rt * 16 + ln15) * ASTR + colb;
                split2_write(sv, actH + ao, actL + ao);
            }
        }
    }
    if constexpr (HEAD) {
        constexpr int NR = RT * 16;
#pragma unroll
        for (int rt = 0; rt < RT; ++rt) {
            hp[rt] += __shfl_xor(hp[rt], 16);
            hp[rt] += __shfl_xor(hp[rt], 32);
        }
        if (lng == 0) {
#pragma unroll
            for (int rt = 0; rt < RT; ++rt) hred[wv * NR + rt * 16 + ln15] = hp[rt];
        }
        __syncthreads();
        if (tid < NR && row0 + tid < 108000) {
            float s = hred[tid] + hred[NR + tid] + hred[2 * NR + tid] + hred[3 * NR + tid] + headB[0];
            headOut[row0 + tid] = s;
        }
    }
    if constexpr (WRITEACT) __syncthreads();
}

// ---------------------------------------------------------------------------
// k3ab: fused stage-3, 2 blocks/CU (measured optimum of the tile/occupancy
// tradeoff: 3blk/48r=278us, 2blk/64r=200us, 1blk/128r=248us).
// k3b: 1688 x 64-row tiles (RT=4, last guarded). k3a: 2250 x 48-row.
// Interleave 3:4 in groups of 7 (3938 blocks total).
// ---------------------------------------------------------------------------
__global__ __launch_bounds__(256, 2) void k3ab_kernel(
    const float* __restrict__ Ucr, const float* __restrict__ Utm,
    const short* __restrict__ planes,
    const float* __restrict__ crW0, const float* __restrict__ crB0,
    const float* __restrict__ crB1, const float* __restrict__ crW2,
    const float* __restrict__ crB2,
    const float* __restrict__ tmW0, const float* __restrict__ tmB0,
    const float* __restrict__ tmB1,
    const float* __restrict__ b45, const float* __restrict__ emB1,
    const float* __restrict__ w5, const float* __restrict__ b5,
    float* __restrict__ cont2, float* __restrict__ Vns3)
{
    __shared__ short lds[3 * 48 * ASTR];   // 76032 B >= 2*64*ASTR (67584 B)
    __shared__ float hred[256];
    const int tid = threadIdx.x;
    const int g = blockIdx.x / 7, rm = blockIdx.x % 7;
    bool isB; int idx;
    if (g < 562) {
        isB = rm < 3;
        idx = isB ? (g * 3 + rm) : (g * 4 + (rm - 3));
    } else {
        isB = rm < 2;
        idx = isB ? (1686 + rm) : (2248 + (rm - 2));
    }
    const int ln15 = tid & 15, lng = (tid >> 4) & 3, wv = tid >> 6;
    const short* P = planes;

    if (isB) {
        const int row0 = idx * 64;
        short* actH = lds;
        short* actL = lds + 64 * ASTR;
        const int ln = tid & 63;
        const float4 wr = *(const float4*)(tmW0 + 65536 + ln * 4);
        const float4 bb = *(const float4*)(tmB0 + ln * 4);
        for (int i = wv * 16; i < wv * 16 + 16; ++i) {
            int r = row0 + i;
            int srow = r / 15;
            if (srow > 7199) srow = 7199;
            float a = (float)(r % 15);
            float4 u = *(const float4*)(Utm + srow * 256 + ln * 4);
            float sv[4];
            sv[0] = fmaxf(u.x + a * wr.x + bb.x, 0.f);
            sv[1] = fmaxf(u.y + a * wr.y + bb.y, 0.f);
            sv[2] = fmaxf(u.z + a * wr.z + bb.z, 0.f);
            sv[3] = fmaxf(u.w + a * wr.w + bb.w, 0.f);
            split2_write(sv, actH + i * ASTR + ln * 4, actL + i * ASTR + ln * 4);
        }
        __syncthreads();
        layer_g2<4, true,  false, true >(P + 3 * PL,  P + 4 * PL,  tmB1, nullptr, nullptr, nullptr, row0, actH, actL, hred);
        layer_g2<4, true,  false, true >(P + 9 * PL,  P + 10 * PL, b45,  nullptr, nullptr, nullptr, row0, actH, actL, hred);
        layer_g2<4, true,  true,  false>(P + 6 * PL,  P + 7 * PL,  emB1, w5, b5, Vns3, row0, actH, actL, hred);
    } else {
        const int row0 = idx * 48;
        short* actH = lds;
        short* actM = lds + 48 * ASTR;
        short* actL = lds + 2 * 48 * ASTR;
        stage3w<48, false>(Ucr, crW0 + 65536, crB0, row0, actH, actM, actL);
        __syncthreads();
        f32x4 acc[4][3];
#pragma unroll
        for (int a = 0; a < 4; ++a)
#pragma unroll
            for (int b = 0; b < 3; ++b) acc[a][b] = f32x4{0.f,0.f,0.f,0.f};
        mm3<3, 6>(P + 0*PL, P + 1*PL, P + 2*PL, actH, actM, actL, acc);
        float hp[3] = {0.f, 0.f, 0.f};
#pragma unroll
        for (int ct = 0; ct < 4; ++ct) {
            const int colb = wv * 64 + ct * 16 + lng * 4;
            const float4 b1 = *(const float4*)(crB1 + colb);
#pragma unroll
            for (int rt = 0; rt < 3; ++rt) {
                f32x4 v = acc[ct][rt];
                v[0] += b1.x; v[1] += b1.y; v[2] += b1.z; v[3] += b1.w;
#pragma unroll
                for (int j = 0; j < 4; ++j) v[j] = fmaxf(v[j], 0.f);
#pragma unroll
                for (int j = 0; j < 4; ++j) hp[rt] += v[j] * crW2[(colb + j) * 2];
            }
        }
#pragma unroll
        for (int rt = 0; rt < 3; ++rt) {
            hp[rt] += __shfl_xor(hp[rt], 16);
            hp[rt] += __shfl_xor(hp[rt], 32);
        }
        if (lng == 0) {
#pragma unroll
            for (int rt = 0; rt < 3; ++rt) hred[wv * 48 + rt * 16 + ln15] = hp[rt];
        }
        __syncthreads();
        if (tid < 48)
            cont2[row0 + tid] = hred[tid] + hred[48 + tid] + hred[96 + tid] + hred[144 + tid] + crB2[0];
    }
}

extern "C" void kernel_launch(void* const* d_in, const int* in_sizes, int n_in,
                              void* d_out, int out_size, void* d_ws, size_t ws_size,
                              hipStream_t stream)
{
    (void)in_sizes; (void)n_in; (void)out_size; (void)ws_size;
    const float* x    = (const float*)d_in[0];
    const float* emW0 = (const float*)d_in[1];
    const float* emB0 = (const float*)d_in[2];
    const float* emW1 = (const float*)d_in[3];
    const float* emB1 = (const float*)d_in[4];
    const float* emW2 = (const float*)d_in[5];
    const float* emB2 = (const float*)d_in[6];
    const float* vW   = (const float*)d_in[7];
    const float* vb   = (const float*)d_in[8];
    const float* crW0 = (const float*)d_in[9];
    const float* crB0 = (const float*)d_in[10];
    const float* crW1 = (const float*)d_in[11];
    const float* crB1 = (const float*)d_in[12];
    const float* crW2 = (const float*)d_in[13];
    const float* crB2 = (const float*)d_in[14];
    const float* tmW0 = (const float*)d_in[15];
    const float* tmB0 = (const float*)d_in[16];
    const float* tmW1 = (const float*)d_in[17];
    const float* tmB1 = (const float*)d_in[18];
    const float* tmW2 = (const float*)d_in[19];
    const float* tmB2 = (const float*)d_in[20];
    float* out = (float*)d_out;

    float* w     = (float*)d_ws;
    float* rews0 = w;                     // 480
    float* cont1 = rews0 + 480;           // 7200
    float* rews1 = cont1 + 7200;          // 7200
    float* cont2 = rews1 + 7200;          // 108000
    float* Vns3  = cont2 + 108000;        // 108000
    float* U1cr  = Vns3 + 108000;         // 32*256
    float* U1tm  = U1cr + 32 * 256;       // 32*256
    short* planes = (short*)(U1tm + 32 * 256);  // 18 * PL shorts = 2.25 MB
    float* U2cr  = (float*)(planes + 18 * PL);  // 480*256
    float* U2tm  = U2cr + 480 * 256;            // 480*256
    float* Ucr   = U2tm + 480 * 256;            // 7200*256
    float* Utm   = Ucr + 7200 * 256;            // 7200*256
    float* w5    = Utm + 7200 * 256;            // 256
    float* b5    = w5 + 256;                    // 1 (pad to 4)
    float* c2cr  = b5 + 4;                      // 256
    float* c2tm  = c2cr + 256;                  // 256
    float* b45   = c2tm + 256;                  // 256

    front_kernel<<<66, 256, 0, stream>>>(x,
        emW0, emB0, emW1, emB1, emW2, emB2, vW, vb,
        crW0, crW1, tmW0, tmW1, tmW2, tmB2,
        planes, w5, b5, c2cr, c2tm, b45,
        out + NB * NA, U1cr, U1tm);
    stage1m_kernel<<<30, 256, 0, stream>>>(U1cr, U1tm, planes,
        crW0, crB0, crB1, crW2, crB2, tmW0, tmB0, tmB1,
        c2cr, c2tm, rews0, U2cr, U2tm);
    stage2m_kernel<<<450, 256, 0, stream>>>(U2cr, U2tm, planes,
        crW0, crB0, crB1, crW2, crB2, tmW0, tmB0, tmB1,
        c2cr, c2tm, cont1, rews1, Ucr, Utm);
    k3ab_kernel<<<3938, 256, 0, stream>>>(Ucr, Utm, planes,
        crW0, crB0, crB1, crW2, crB2,
        tmW0, tmB0, tmB1, b45, emB1, w5, b5, cont2, Vns3);
    finalize_kernel<<<NB, 256, 0, stream>>>(Vns3, cont2, rews0, rews1, cont1, out);
}

// Round 19
// 272.486 us; speedup vs baseline: 1.2786x; 1.1293x over previous
//
#include <hip/hip_runtime.h>

#define NA 15
#define NB 32
#define DD 256
#define PL 65536  // shorts per weight plane (8 slices x 256 cols x 32 k)
#define ASTR 264  // act LDS row stride (shorts)

using bf16x8 = __attribute__((ext_vector_type(8))) short;
using f32x4  = __attribute__((ext_vector_type(4))) float;

__device__ __forceinline__ unsigned short f2bf(float f){
  unsigned int u = __float_as_uint(f);
  u = u + 0x7fffu + ((u >> 16) & 1u);
  return (unsigned short)(u >> 16);
}
__device__ __forceinline__ float bf2f(unsigned short h){
  return __uint_as_float(((unsigned int)h) << 16);
}
__device__ __forceinline__ unsigned int cvtpk_bf16(float lo, float hi){
    unsigned int r;
    asm("v_cvt_pk_bf16_f32 %0, %1, %2" : "=v"(r) : "v"(lo), "v"(hi));
    return r;
}
__device__ __forceinline__ void split2_write(const float v[4], short* pH, short* pL){
    unsigned int h01 = cvtpk_bf16(v[0], v[1]);
    unsigned int h23 = cvtpk_bf16(v[2], v[3]);
    float r0 = v[0] - __uint_as_float(h01 << 16);
    float r1 = v[1] - __uint_as_float(h01 & 0xffff0000u);
    float r2 = v[2] - __uint_as_float(h23 << 16);
    float r3 = v[3] - __uint_as_float(h23 & 0xffff0000u);
    unsigned int l01 = cvtpk_bf16(r0, r1);
    unsigned int l23 = cvtpk_bf16(r2, r3);
    *(uint2*)pH = make_uint2(h01, h23);
    *(uint2*)pL = make_uint2(l01, l23);
}
__device__ __forceinline__ void split3_write(const float v[4], short* pH, short* pM, short* pL){
    unsigned int h01 = cvtpk_bf16(v[0], v[1]);
    unsigned int h23 = cvtpk_bf16(v[2], v[3]);
    float r0 = v[0] - __uint_as_float(h01 << 16);
    float r1 = v[1] - __uint_as_float(h01 & 0xffff0000u);
    float r2 = v[2] - __uint_as_float(h23 << 16);
    float r3 = v[3] - __uint_as_float(h23 & 0xffff0000u);
    unsigned int m01 = cvtpk_bf16(r0, r1);
    unsigned int m23 = cvtpk_bf16(r2, r3);
    float s0 = r0 - __uint_as_float(m01 << 16);
    float s1 = r1 - __uint_as_float(m01 & 0xffff0000u);
    float s2 = r2 - __uint_as_float(m23 << 16);
    float s3 = r3 - __uint_as_float(m23 & 0xffff0000u);
    unsigned int l01 = cvtpk_bf16(s0, s1);
    unsigned int l23 = cvtpk_bf16(s2, s3);
    *(uint2*)pH = make_uint2(h01, h23);
    *(uint2*)pM = make_uint2(m01, m23);
    *(uint2*)pL = make_uint2(l01, l23);
}

// ---------------------------------------------------------------------------
// fp32 VALU primitives (value_x branch of front kernel)
// ---------------------------------------------------------------------------
template<int TM, bool RELU>
__device__ __forceinline__ void layer256(
    const float* __restrict__ W, const float* __restrict__ bias,
    const float* act, int K, int lda, float* out, int ldo)
{
    constexpr int RPG = TM / 4;
    const int tid = threadIdx.x;
    const int tr = tid >> 6;
    const int tc = tid & 63;
    float acc[RPG][4];
#pragma unroll
    for (int i = 0; i < RPG; ++i) { acc[i][0]=0.f; acc[i][1]=0.f; acc[i][2]=0.f; acc[i][3]=0.f; }
    const float* wp = W + 4 * tc;
    int k = 0;
    for (; k + 4 <= K; k += 4) {
        float4 w0 = *reinterpret_cast<const float4*>(wp + (k + 0) * DD);
        float4 w1 = *reinterpret_cast<const float4*>(wp + (k + 1) * DD);
        float4 w2 = *reinterpret_cast<const float4*>(wp + (k + 2) * DD);
        float4 w3 = *reinterpret_cast<const float4*>(wp + (k + 3) * DD);
#pragma unroll
        for (int i = 0; i < RPG; ++i) {
            float4 a = *reinterpret_cast<const float4*>(act + (RPG * tr + i) * lda + k);
            acc[i][0] += a.x * w0.x + a.y * w1.x + a.z * w2.x + a.w * w3.x;
            acc[i][1] += a.x * w0.y + a.y * w1.y + a.z * w2.y + a.w * w3.y;
            acc[i][2] += a.x * w0.z + a.y * w1.z + a.z * w2.z + a.w * w3.z;
            acc[i][3] += a.x * w0.w + a.y * w1.w + a.z * w2.w + a.w * w3.w;
        }
    }
    for (; k < K; ++k) {
        float4 w0 = *reinterpret_cast<const float4*>(wp + k * DD);
#pragma unroll
        for (int i = 0; i < RPG; ++i) {
            float a = act[(RPG * tr + i) * lda + k];
            acc[i][0] += a * w0.x; acc[i][1] += a * w0.y;
            acc[i][2] += a * w0.z; acc[i][3] += a * w0.w;
        }
    }
    float4 bb = *reinterpret_cast<const float4*>(bias + 4 * tc);
#pragma unroll
    for (int i = 0; i < RPG; ++i) {
        float4 o;
        o.x = acc[i][0] + bb.x; o.y = acc[i][1] + bb.y;
        o.z = acc[i][2] + bb.z; o.w = acc[i][3] + bb.w;
        if (RELU) {
            o.x = fmaxf(o.x, 0.f); o.y = fmaxf(o.y, 0.f);
            o.z = fmaxf(o.z, 0.f); o.w = fmaxf(o.w, 0.f);
        }
        *reinterpret_cast<float4*>(out + (RPG * tr + i) * ldo + 4 * tc) = o;
    }
}

template<int TM>
__device__ __forceinline__ void head1c(
    const float* h, int ldh, const float* __restrict__ W, int wstr, int col, float bias,
    float* __restrict__ gout, int gbase)
{
    const int wv = threadIdx.x >> 6;
    const int lane = threadIdx.x & 63;
    for (int rr = wv; rr < TM; rr += 4) {
        float p = 0.f;
#pragma unroll
        for (int t = 0; t < 4; ++t) {
            int k = lane + 64 * t;
            p += h[rr * ldh + k] * W[k * wstr + col];
        }
#pragma unroll
        for (int m = 1; m < 64; m <<= 1) p += __shfl_xor(p, m);
        if (lane == 0) gout[gbase + rr] = p + bias;
    }
}

// ---------------------------------------------------------------------------
// front_kernel (unchanged from R15/R16)
// ---------------------------------------------------------------------------
__global__ __launch_bounds__(256) void front_kernel(
    const float* __restrict__ x,
    const float* __restrict__ emW0, const float* __restrict__ emB0,
    const float* __restrict__ emW1, const float* __restrict__ emB1,
    const float* __restrict__ emW2, const float* __restrict__ emB2,
    const float* __restrict__ vW, const float* __restrict__ vb,
    const float* __restrict__ crW0, const float* __restrict__ crW1,
    const float* __restrict__ tmW0, const float* __restrict__ tmW1,
    const float* __restrict__ tmW2, const float* __restrict__ tmB2,
    short* __restrict__ planes, float* __restrict__ w5, float* __restrict__ b5,
    float* __restrict__ c2cr, float* __restrict__ c2tm, float* __restrict__ b45,
    float* __restrict__ vout, float* __restrict__ U1cr, float* __restrict__ U1tm)
{
    __shared__ __align__(16) float smem[32 * DD];
    const int blk = blockIdx.x;
    const int tid = threadIdx.x;

    if (blk < 24) {
        const int mat = blk >> 3;
        const int kk  = blk & 7;
        const float* W = (mat == 0) ? crW1 : (mat == 1) ? tmW1 : emW1;
        const int col = tid;
        short bh[32], bm[32], bl[32];
#pragma unroll
        for (int j = 0; j < 32; ++j) {
            float w = W[(kk * 32 + j) * 256 + col];
            unsigned short h = f2bf(w); float fh = bf2f(h);
            float r1 = w - fh;
            unsigned short m = f2bf(r1); float fm = bf2f(m);
            bh[j] = (short)h; bm[j] = (short)m; bl[j] = (short)f2bf(r1 - fm);
        }
        short* pH = planes + (size_t)(mat * 3 + 0) * PL + kk * 8192 + col * 32;
        short* pM = planes + (size_t)(mat * 3 + 1) * PL + kk * 8192 + col * 32;
        short* pLp = planes + (size_t)(mat * 3 + 2) * PL + kk * 8192 + col * 32;
#pragma unroll
        for (int j = 0; j < 32; j += 4) {
            *(short4*)(pH + j) = make_short4(bh[j], bh[j+1], bh[j+2], bh[j+3]);
            *(short4*)(pM + j) = make_short4(bm[j], bm[j+1], bm[j+2], bm[j+3]);
            *(short4*)(pLp + j) = make_short4(bl[j], bl[j+1], bl[j+2], bl[j+3]);
        }
    } else if (blk == 24) {
        float acc = 0.f;
        for (int j = 0; j < 256; j += 4) {
            float4 wrow = *(const float4*)(emW2 + tid * 256 + j);
            float4 vv   = *(const float4*)(vW + j);
            acc += wrow.x * vv.x + wrow.y * vv.y + wrow.z * vv.z + wrow.w * vv.w;
        }
        w5[tid] = acc;
        if (tid == 0) {
            float b = 0.f;
            for (int j = 0; j < 256; ++j) b += emB2[j] * vW[j];
            b5[0] = b + vb[0];
        }
    } else if (blk < 33) {
        constexpr int TM = 4;
        float* bufA = smem;
        float* bufB = bufA + TM * DD;
        float* bufC = bufB + TM * DD;
        const int row0 = (blk - 25) * TM;
        for (int i = 0; i < TM; ++i) bufA[i * DD + tid] = x[(row0 + i) * DD + tid];
        __syncthreads();
        layer256<TM, true >(emW0, emB0, bufA, 256, DD, bufB, DD); __syncthreads();
        layer256<TM, true >(emW1, emB1, bufB, 256, DD, bufC, DD); __syncthreads();
        layer256<TM, false>(emW2, emB2, bufC, 256, DD, bufB, DD); __syncthreads();
        head1c<TM>(bufB, DD, vW, 1, 0, vb[0], vout, row0);
    } else if (blk < 41) {
        const int row0 = (blk - 33) * 4;
        float* xs = smem;   // [4][256]
        for (int i = 0; i < 4; ++i) xs[i * 256 + tid] = x[(row0 + i) * 256 + tid];
        __syncthreads();
        float acr[4] = {0.f,0.f,0.f,0.f}, atm[4] = {0.f,0.f,0.f,0.f};
        for (int k = 0; k < 256; ++k) {
            float wc = crW0[k * 256 + tid];
            float wt = tmW0[k * 256 + tid];
#pragma unroll
            for (int i = 0; i < 4; ++i) {
                acr[i] += xs[i * 256 + k] * wc;
                atm[i] += xs[i * 256 + k] * wt;
            }
        }
        for (int i = 0; i < 4; ++i) {
            U1cr[(row0 + i) * 256 + tid] = acr[i];
            U1tm[(row0 + i) * 256 + tid] = atm[i];
        }
    } else if (blk < 65) {
        const int pb = blk - 41;
        const int prod = pb >> 3;           // 0=W45, 1=W2cr, 2=W2tm
        const int r0 = (pb & 7) * 32;
        const float* B = (prod == 0) ? emW0 : (prod == 1) ? crW0 : tmW0;
        const int pbase = 9 + prod * 3;
        float* As = smem;   // [32][256]
        for (int i = tid; i < 32 * 256; i += 256)
            As[i] = tmW2[(r0 + (i >> 8)) * 256 + (i & 255)];
        __syncthreads();
        float acc[32];
#pragma unroll
        for (int j = 0; j < 32; ++j) acc[j] = 0.f;
        for (int m = 0; m < 256; ++m) {
            float b = B[m * 256 + tid];
#pragma unroll
            for (int j = 0; j < 32; ++j) acc[j] += As[j * 256 + m] * b;
        }
        short bh[32], bm[32], bl[32];
#pragma unroll
        for (int j = 0; j < 32; ++j) {
            float w = acc[j];
            unsigned short h = f2bf(w); float fh = bf2f(h);
            float r1 = w - fh;
            unsigned short mm = f2bf(r1); float fm = bf2f(mm);
            bh[j] = (short)h; bm[j] = (short)mm; bl[j] = (short)f2bf(r1 - fm);
        }
        const int kk = r0 >> 5;
        short* pH = planes + (size_t)(pbase + 0) * PL + kk * 8192 + tid * 32;
        short* pM = planes + (size_t)(pbase + 1) * PL + kk * 8192 + tid * 32;
        short* pLp = planes + (size_t)(pbase + 2) * PL + kk * 8192 + tid * 32;
#pragma unroll
        for (int j = 0; j < 32; j += 4) {
            *(short4*)(pH + j) = make_short4(bh[j], bh[j+1], bh[j+2], bh[j+3]);
            *(short4*)(pM + j) = make_short4(bm[j], bm[j+1], bm[j+2], bm[j+3]);
            *(short4*)(pLp + j) = make_short4(bl[j], bl[j+1], bl[j+2], bl[j+3]);
        }
    } else {
        const int j = tid;
        float a0 = 0.f, a1 = 0.f, a2 = 0.f;
        for (int k = 0; k < 256; ++k) {
            float t = tmB2[k];
            a0 += t * crW0[k * 256 + j];
            a1 += t * tmW0[k * 256 + j];
            a2 += t * emW0[k * 256 + j];
        }
        c2cr[j] = a0;
        c2tm[j] = a1;
        b45[j] = a2 + emB0[j];
    }
}

__global__ __launch_bounds__(256) void finalize_kernel(
    const float* __restrict__ Vns3, const float* __restrict__ cont2,
    const float* __restrict__ rews0, const float* __restrict__ rews1,
    const float* __restrict__ cont1, float* __restrict__ out)
{
    const int b = blockIdx.x;
    const int tid = threadIdx.x;
    __shared__ float vs2[NA][NA];
    __shared__ float vs3[NA];
    if (tid < NA * NA) {
        const int x = tid / NA, y = tid % NA;
        float vals[NA];
        float m = -INFINITY;
#pragma unroll
        for (int z = 0; z < NA; ++z) {
            int vidx = ((b * NA + y) * NA + z) * NA + x;
            int cidx = ((b * NA + x) * NA + y) * NA + z;
            float c1 = rews0[b * NA + z] * 0.99f;
            float c2 = (c1 + rews1[(b * NA + x) * NA + z]) * 0.99f;
            float v = Vns3[vidx] * 0.970299f + c2;
            if (cont2[cidx] > 0.f) v = 0.f;
            vals[z] = v;
            m = fmaxf(m, v);
        }
        float se = 0.f, sw = 0.f;
#pragma unroll
        for (int z = 0; z < NA; ++z) { float e = expf(vals[z] - m); se += e; sw += e * vals[z]; }
        vs2[x][y] = sw / se;
    }
    __syncthreads();
    if (tid < NA) {
        const int x = tid;
        float vals[NA];
        float m = -INFINITY;
#pragma unroll
        for (int y = 0; y < NA; ++y) {
            float v = vs2[x][y];
            if (cont1[(b * NA + x) * NA + y] > 0.f) v = 0.f;
            vals[y] = v;
            m = fmaxf(m, v);
        }
        float se = 0.f, sw = 0.f;
#pragma unroll
        for (int y = 0; y < NA; ++y) { float e = expf(vals[y] - m); se += e; sw += e * vals[y]; }
        vs3[x] = sw / se;
    }
    __syncthreads();
    if (tid == 0) {
        float m = -INFINITY;
#pragma unroll
        for (int x = 0; x < NA; ++x) m = fmaxf(m, vs3[x]);
        float se = 0.f;
#pragma unroll
        for (int x = 0; x < NA; ++x) se += expf(vs3[x] - m);
        float l = logf(se);
#pragma unroll
        for (int x = 0; x < NA; ++x) out[b * NA + x] = vs3[x] - m - l;
    }
}

// ---------------------------------------------------------------------------
// mm3: accumulate RT row-tiles x 4 col-tiles over K=256 with NP passes.
// ---------------------------------------------------------------------------
template<int RT, int NP>
__device__ __forceinline__ void mm3(
    const short* __restrict__ plH, const short* __restrict__ plM, const short* __restrict__ plL,
    const short* actH, const short* actM, const short* actL,
    f32x4 (&acc)[4][RT])
{
    const int tid = threadIdx.x;
    const int ln15 = tid & 15, lng = (tid >> 4) & 3, wv = tid >> 6;
    const int wo = (wv * 64 + ln15) * 32 + lng * 8;
#pragma unroll
    for (int kk = 0; kk < 8; ++kk) {
        bf16x8 wH[4], wM[4], wL[4], xH[RT], xM[RT], xL[RT];
#pragma unroll
        for (int ct = 0; ct < 4; ++ct) {
            wH[ct] = *(const bf16x8*)(plH + wo + kk * 8192 + ct * 512);
            wM[ct] = *(const bf16x8*)(plM + wo + kk * 8192 + ct * 512);
            if (NP == 6) wL[ct] = *(const bf16x8*)(plL + wo + kk * 8192 + ct * 512);
        }
#pragma unroll
        for (int rt = 0; rt < RT; ++rt) {
            int off = (rt * 16 + ln15) * ASTR + kk * 32 + lng * 8;
            xH[rt] = *(const bf16x8*)(actH + off);
            xM[rt] = *(const bf16x8*)(actM + off);
            if (NP == 6) xL[rt] = *(const bf16x8*)(actL + off);
        }
        __builtin_amdgcn_s_setprio(1);
#pragma unroll
        for (int ct = 0; ct < 4; ++ct)
#pragma unroll
            for (int rt = 0; rt < RT; ++rt) {
                acc[ct][rt] = __builtin_amdgcn_mfma_f32_16x16x32_bf16(wH[ct], xH[rt], acc[ct][rt], 0, 0, 0);
                acc[ct][rt] = __builtin_amdgcn_mfma_f32_16x16x32_bf16(wH[ct], xM[rt], acc[ct][rt], 0, 0, 0);
                acc[ct][rt] = __builtin_amdgcn_mfma_f32_16x16x32_bf16(wM[ct], xH[rt], acc[ct][rt], 0, 0, 0);
                if (NP == 6) {
                    acc[ct][rt] = __builtin_amdgcn_mfma_f32_16x16x32_bf16(wM[ct], xM[rt], acc[ct][rt], 0, 0, 0);
                    acc[ct][rt] = __builtin_amdgcn_mfma_f32_16x16x32_bf16(wH[ct], xL[rt], acc[ct][rt], 0, 0, 0);
                    acc[ct][rt] = __builtin_amdgcn_mfma_f32_16x16x32_bf16(wL[ct], xH[rt], acc[ct][rt], 0, 0, 0);
                }
            }
        __builtin_amdgcn_s_setprio(0);
    }
}

// stage a 3-way-split activation row block from U + a*wrow + bias (relu)
template<int ROWS, bool CLAMP>
__device__ __forceinline__ void stage3w(
    const float* __restrict__ U, const float* __restrict__ wrow256,
    const float* __restrict__ bias, int row0,
    short* actH, short* actM, short* actL)
{
    const int tid = threadIdx.x;
    const int wv = tid >> 6, ln = tid & 63;
    constexpr int RPW = ROWS / 4;
    const float4 wr = *(const float4*)(wrow256 + ln * 4);
    const float4 bb = *(const float4*)(bias + ln * 4);
    for (int i = wv * RPW; i < wv * RPW + RPW; ++i) {
        int r = row0 + i;
        int srow = r / 15;
        if (CLAMP && srow > 7199) srow = 7199;
        float a = (float)(r % 15);
        float4 u = *(const float4*)(U + srow * 256 + ln * 4);
        float sv[4];
        sv[0] = fmaxf(u.x + a * wr.x + bb.x, 0.f);
        sv[1] = fmaxf(u.y + a * wr.y + bb.y, 0.f);
        sv[2] = fmaxf(u.z + a * wr.z + bb.z, 0.f);
        sv[3] = fmaxf(u.w + a * wr.w + bb.w, 0.f);
        split3_write(sv, actH + i * ASTR + ln * 4, actM + i * ASTR + ln * 4, actL + i * ASTR + ln * 4);
    }
}

// ---------------------------------------------------------------------------
// stage1m: 480 rows (b,a1), 30 blocks x 16 rows. rews0 + U2cr/U2tm.
// ---------------------------------------------------------------------------
__global__ __launch_bounds__(256, 2) void stage1m_kernel(
    const float* __restrict__ U1cr, const float* __restrict__ U1tm,
    const short* __restrict__ planes,
    const float* __restrict__ crW0, const float* __restrict__ crB0,
    const float* __restrict__ crB1, const float* __restrict__ crW2, const float* __restrict__ crB2,
    const float* __restrict__ tmW0, const float* __restrict__ tmB0,
    const float* __restrict__ tmB1,
    const float* __restrict__ c2cr, const float* __restrict__ c2tm,
    float* __restrict__ rews0, float* __restrict__ U2cr, float* __restrict__ U2tm)
{
    __shared__ short actH[16 * ASTR];
    __shared__ short actM[16 * ASTR];
    __shared__ short actL[16 * ASTR];
    __shared__ float hred[64];
    const int tid = threadIdx.x;
    const int row0 = blockIdx.x * 16;
    const int ln15 = tid & 15, lng = (tid >> 4) & 3, wv = tid >> 6;

    stage3w<16, false>(U1cr, crW0 + 65536, crB0, row0, actH, actM, actL);
    __syncthreads();
    {
        f32x4 acc[4][1];
#pragma unroll
        for (int a = 0; a < 4; ++a) acc[a][0] = f32x4{0.f,0.f,0.f,0.f};
        mm3<1, 6>(planes + 0*PL, planes + 1*PL, planes + 2*PL, actH, actM, actL, acc);
        float hp = 0.f;
#pragma unroll
        for (int ct = 0; ct < 4; ++ct) {
            const int colb = wv * 64 + ct * 16 + lng * 4;
            const float4 b1 = *(const float4*)(crB1 + colb);
            f32x4 v = acc[ct][0];
            v[0] += b1.x; v[1] += b1.y; v[2] += b1.z; v[3] += b1.w;
#pragma unroll
            for (int j = 0; j < 4; ++j) v[j] = fmaxf(v[j], 0.f);
#pragma unroll
            for (int j = 0; j < 4; ++j) hp += v[j] * crW2[(colb + j) * 2 + 1];
        }
        hp += __shfl_xor(hp, 16);
        hp += __shfl_xor(hp, 32);
        if (lng == 0) hred[wv * 16 + ln15] = hp;
        __syncthreads();
        if (tid < 16) rews0[row0 + tid] = hred[tid] + hred[16 + tid] + hred[32 + tid] + hred[48 + tid] + crB2[1];
        __syncthreads();
    }

    stage3w<16, false>(U1tm, tmW0 + 65536, tmB0, row0, actH, actM, actL);
    __syncthreads();
    {
        f32x4 acc[4][1];
#pragma unroll
        for (int a = 0; a < 4; ++a) acc[a][0] = f32x4{0.f,0.f,0.f,0.f};
        mm3<1, 6>(planes + 3*PL, planes + 4*PL, planes + 5*PL, actH, actM, actL, acc);
        __syncthreads();
#pragma unroll
        for (int ct = 0; ct < 4; ++ct) {
            const int colb = wv * 64 + ct * 16 + lng * 4;
            const float4 bb = *(const float4*)(tmB1 + colb);
            f32x4 v = acc[ct][0];
            v[0] += bb.x; v[1] += bb.y; v[2] += bb.z; v[3] += bb.w;
#pragma unroll
            for (int j = 0; j < 4; ++j) v[j] = fmaxf(v[j], 0.f);
            float sv[4] = {v[0], v[1], v[2], v[3]};
            const int ao = ln15 * ASTR + colb;
            split3_write(sv, actH + ao, actM + ao, actL + ao);
        }
        __syncthreads();
    }
    {
        f32x4 acc[4][1];
#pragma unroll
        for (int a = 0; a < 4; ++a) acc[a][0] = f32x4{0.f,0.f,0.f,0.f};
        mm3<1, 6>(planes + 12*PL, planes + 13*PL, planes + 14*PL, actH, actM, actL, acc);
#pragma unroll
        for (int ct = 0; ct < 4; ++ct) {
            const int colb = wv * 64 + ct * 16 + lng * 4;
            const float4 cc = *(const float4*)(c2cr + colb);
            float4 o; o.x = acc[ct][0][0] + cc.x; o.y = acc[ct][0][1] + cc.y;
            o.z = acc[ct][0][2] + cc.z; o.w = acc[ct][0][3] + cc.w;
            *(float4*)(U2cr + (row0 + ln15) * 256 + colb) = o;
        }
    }
    {
        f32x4 acc[4][1];
#pragma unroll
        for (int a = 0; a < 4; ++a) acc[a][0] = f32x4{0.f,0.f,0.f,0.f};
        mm3<1, 6>(planes + 15*PL, planes + 16*PL, planes + 17*PL, actH, actM, actL, acc);
#pragma unroll
        for (int ct = 0; ct < 4; ++ct) {
            const int colb = wv * 64 + ct * 16 + lng * 4;
            const float4 cc = *(const float4*)(c2tm + colb);
            float4 o; o.x = acc[ct][0][0] + cc.x; o.y = acc[ct][0][1] + cc.y;
            o.z = acc[ct][0][2] + cc.z; o.w = acc[ct][0][3] + cc.w;
            *(float4*)(U2tm + (row0 + ln15) * 256 + colb) = o;
        }
    }
}

// ---------------------------------------------------------------------------
// stage2m: 7200 rows, 450 blocks x 16 rows. cont1/rews1 + Ucr/Utm (permuted).
// ---------------------------------------------------------------------------
__global__ __launch_bounds__(256, 2) void stage2m_kernel(
    const float* __restrict__ U2cr, const float* __restrict__ U2tm,
    const short* __restrict__ planes,
    const float* __restrict__ crW0, const float* __restrict__ crB0,
    const float* __restrict__ crB1, const float* __restrict__ crW2, const float* __restrict__ crB2,
    const float* __restrict__ tmW0, const float* __restrict__ tmB0,
    const float* __restrict__ tmB1,
    const float* __restrict__ c2cr, const float* __restrict__ c2tm,
    float* __restrict__ cont1, float* __restrict__ rews1,
    float* __restrict__ Ucr, float* __restrict__ Utm)
{
    __shared__ short actH[16 * ASTR];
    __shared__ short actM[16 * ASTR];
    __shared__ short actL[16 * ASTR];
    __shared__ float hred[2][64];
    const int tid = threadIdx.x;
    const int row0 = blockIdx.x * 16;
    const int ln15 = tid & 15, lng = (tid >> 4) & 3, wv = tid >> 6;

    stage3w<16, false>(U2cr, crW0 + 65536, crB0, row0, actH, actM, actL);
    __syncthreads();
    {
        f32x4 acc[4][1];
#pragma unroll
        for (int a = 0; a < 4; ++a) acc[a][0] = f32x4{0.f,0.f,0.f,0.f};
        mm3<1, 6>(planes + 0*PL, planes + 1*PL, planes + 2*PL, actH, actM, actL, acc);
        float hp0 = 0.f, hp1 = 0.f;
#pragma unroll
        for (int ct = 0; ct < 4; ++ct) {
            const int colb = wv * 64 + ct * 16 + lng * 4;
            const float4 b1 = *(const float4*)(crB1 + colb);
            f32x4 v = acc[ct][0];
            v[0] += b1.x; v[1] += b1.y; v[2] += b1.z; v[3] += b1.w;
#pragma unroll
            for (int j = 0; j < 4; ++j) v[j] = fmaxf(v[j], 0.f);
#pragma unroll
            for (int j = 0; j < 4; ++j) {
                hp0 += v[j] * crW2[(colb + j) * 2 + 0];
                hp1 += v[j] * crW2[(colb + j) * 2 + 1];
            }
        }
        hp0 += __shfl_xor(hp0, 16); hp0 += __shfl_xor(hp0, 32);
        hp1 += __shfl_xor(hp1, 16); hp1 += __shfl_xor(hp1, 32);
        if (lng == 0) {
            hred[0][wv * 16 + ln15] = hp0;
            hred[1][wv * 16 + ln15] = hp1;
        }
        __syncthreads();
        if (tid < 16)
            cont1[row0 + tid] = hred[0][tid] + hred[0][16 + tid] + hred[0][32 + tid] + hred[0][48 + tid] + crB2[0];
        else if (tid >= 64 && tid < 80)
            rews1[row0 + tid - 64] = hred[1][tid - 64] + hred[1][16 + tid - 64] + hred[1][32 + tid - 64] + hred[1][48 + tid - 64] + crB2[1];
        __syncthreads();
    }

    stage3w<16, false>(U2tm, tmW0 + 65536, tmB0, row0, actH, actM, actL);
    __syncthreads();
    {
        f32x4 acc[4][1];
#pragma unroll
        for (int a = 0; a < 4; ++a) acc[a][0] = f32x4{0.f,0.f,0.f,0.f};
        mm3<1, 6>(planes + 3*PL, planes + 4*PL, planes + 5*PL, actH, actM, actL, acc);
        __syncthreads();
#pragma unroll
        for (int ct = 0; ct < 4; ++ct) {
            const int colb = wv * 64 + ct * 16 + lng * 4;
            const float4 bb = *(const float4*)(tmB1 + colb);
            f32x4 v = acc[ct][0];
            v[0] += bb.x; v[1] += bb.y; v[2] += bb.z; v[3] += bb.w;
#pragma unroll
            for (int j = 0; j < 4; ++j) v[j] = fmaxf(v[j], 0.f);
            float sv[4] = {v[0], v[1], v[2], v[3]};
            const int ao = ln15 * ASTR + colb;
            split3_write(sv, actH + ao, actM + ao, actL + ao);
        }
        __syncthreads();
    }
    int pr;
    {
        int r = row0 + ln15;
        int b = r / 225, a1 = (r / 15) % 15, a2 = r % 15;
        pr = (b * 15 + a2) * 15 + a1;
    }
    {
        f32x4 acc[4][1];
#pragma unroll
        for (int a = 0; a < 4; ++a) acc[a][0] = f32x4{0.f,0.f,0.f,0.f};
        mm3<1, 6>(planes + 12*PL, planes + 13*PL, planes + 14*PL, actH, actM, actL, acc);
#pragma unroll
        for (int ct = 0; ct < 4; ++ct) {
            const int colb = wv * 64 + ct * 16 + lng * 4;
            const float4 cc = *(const float4*)(c2cr + colb);
            float4 o; o.x = acc[ct][0][0] + cc.x; o.y = acc[ct][0][1] + cc.y;
            o.z = acc[ct][0][2] + cc.z; o.w = acc[ct][0][3] + cc.w;
            *(float4*)(Ucr + pr * 256 + colb) = o;
        }
    }
    {
        f32x4 acc[4][1];
#pragma unroll
        for (int a = 0; a < 4; ++a) acc[a][0] = f32x4{0.f,0.f,0.f,0.f};
        mm3<1, 3>(planes + 15*PL, planes + 16*PL, planes + 17*PL, actH, actM, actL, acc);
#pragma unroll
        for (int ct = 0; ct < 4; ++ct) {
            const int colb = wv * 64 + ct * 16 + lng * 4;
            const float4 cc = *(const float4*)(c2tm + colb);
            float4 o; o.x = acc[ct][0][0] + cc.x; o.y = acc[ct][0][1] + cc.y;
            o.z = acc[ct][0][2] + cc.z; o.w = acc[ct][0][3] + cc.w;
            *(float4*)(Utm + pr * 256 + colb) = o;
        }
    }
}

// ---------------------------------------------------------------------------
// layer_g2: NPASS-pass 16x16x32 layer over RT*16-row act tile.
// NPASS=3: wH.xH + wH.xL + wL.xH (fp32-grade weights, ~5e-5 rel).
// NPASS=2: wH.xH + wH.xL (bf16-grade weights, ~2e-3 rel) — mask-free paths only.
// ---------------------------------------------------------------------------
template<int RT, int NPASS, bool RELU, bool HEAD, bool WRITEACT>
__device__ __forceinline__ void layer_g2(
    const short* __restrict__ plH, const short* __restrict__ plL,
    const float* __restrict__ bias,
    const float* __restrict__ headW, const float* __restrict__ headB,
    float* __restrict__ headOut, int row0,
    short* actH, short* actL, float* hred)
{
    const int tid = threadIdx.x;
    const int ln15 = tid & 15, lng = (tid >> 4) & 3, wv = tid >> 6;
    const int wo = (wv * 64 + ln15) * 32 + lng * 8;
    f32x4 acc[4][RT];
#pragma unroll
    for (int a = 0; a < 4; ++a)
#pragma unroll
        for (int b = 0; b < RT; ++b) acc[a][b] = f32x4{0.f, 0.f, 0.f, 0.f};

#pragma unroll
    for (int kk = 0; kk < 8; ++kk) {
        bf16x8 aH[4], aL[4], bH[RT], bL[RT];
#pragma unroll
        for (int ct = 0; ct < 4; ++ct) {
            aH[ct] = *(const bf16x8*)(plH + wo + kk * 8192 + ct * 512);
            if (NPASS == 3) aL[ct] = *(const bf16x8*)(plL + wo + kk * 8192 + ct * 512);
        }
#pragma unroll
        for (int rt = 0; rt < RT; ++rt) {
            int off = (rt * 16 + ln15) * ASTR + kk * 32 + lng * 8;
            bH[rt] = *(const bf16x8*)(actH + off);
            bL[rt] = *(const bf16x8*)(actL + off);
        }
        __builtin_amdgcn_s_setprio(1);
#pragma unroll
        for (int ct = 0; ct < 4; ++ct)
#pragma unroll
            for (int rt = 0; rt < RT; ++rt) {
                acc[ct][rt] = __builtin_amdgcn_mfma_f32_16x16x32_bf16(aH[ct], bH[rt], acc[ct][rt], 0, 0, 0);
                acc[ct][rt] = __builtin_amdgcn_mfma_f32_16x16x32_bf16(aH[ct], bL[rt], acc[ct][rt], 0, 0, 0);
                if (NPASS == 3)
                    acc[ct][rt] = __builtin_amdgcn_mfma_f32_16x16x32_bf16(aL[ct], bH[rt], acc[ct][rt], 0, 0, 0);
            }
        __builtin_amdgcn_s_setprio(0);
    }
    __syncthreads();

    float hp[RT];
#pragma unroll
    for (int rt = 0; rt < RT; ++rt) hp[rt] = 0.f;
#pragma unroll
    for (int ct = 0; ct < 4; ++ct) {
        const int colb = wv * 64 + ct * 16 + lng * 4;
        const float4 bb = *(const float4*)(bias + colb);
#pragma unroll
        for (int rt = 0; rt < RT; ++rt) {
            f32x4 v = acc[ct][rt];
            v[0] += bb.x; v[1] += bb.y; v[2] += bb.z; v[3] += bb.w;
            if (RELU) {
#pragma unroll
                for (int j = 0; j < 4; ++j) v[j] = fmaxf(v[j], 0.f);
            }
            if (HEAD) {
                const float4 hw = *(const float4*)(headW + colb);
                hp[rt] += v[0] * hw.x + v[1] * hw.y + v[2] * hw.z + v[3] * hw.w;
            }
            if (WRITEACT) {
                float sv[4] = {v[0], v[1], v[2], v[3]};
                const int ao = (rt * 16 + ln15) * ASTR + colb;
                split2_write(sv, actH + ao, actL + ao);
            }
        }
    }
    if constexpr (HEAD) {
        constexpr int NR = RT * 16;
#pragma unroll
        for (int rt = 0; rt < RT; ++rt) {
            hp[rt] += __shfl_xor(hp[rt], 16);
            hp[rt] += __shfl_xor(hp[rt], 32);
        }
        if (lng == 0) {
#pragma unroll
            for (int rt = 0; rt < RT; ++rt) hred[wv * NR + rt * 16 + ln15] = hp[rt];
        }
        __syncthreads();
        if (tid < NR && row0 + tid < 108000) {
            float s = hred[tid] + hred[NR + tid] + hred[2 * NR + tid] + hred[3 * NR + tid] + headB[0];
            headOut[row0 + tid] = s;
        }
    }
    if constexpr (WRITEACT) __syncthreads();
}

// ---------------------------------------------------------------------------
// k3ab: fused stage-3, 2 blocks/CU (measured optimum). k3b uses NPASS=2
// (bf16-grade weights — mask-free, double-softmax-contracted path).
// k3b: 1688 x 64-row tiles (RT=4, last guarded). k3a: 2250 x 48-row (6-pass).
// Interleave 3:4 in groups of 7 (3938 blocks total).
// ---------------------------------------------------------------------------
__global__ __launch_bounds__(256, 2) void k3ab_kernel(
    const float* __restrict__ Ucr, const float* __restrict__ Utm,
    const short* __restrict__ planes,
    const float* __restrict__ crW0, const float* __restrict__ crB0,
    const float* __restrict__ crB1, const float* __restrict__ crW2,
    const float* __restrict__ crB2,
    const float* __restrict__ tmW0, const float* __restrict__ tmB0,
    const float* __restrict__ tmB1,
    const float* __restrict__ b45, const float* __restrict__ emB1,
    const float* __restrict__ w5, const float* __restrict__ b5,
    float* __restrict__ cont2, float* __restrict__ Vns3)
{
    __shared__ short lds[3 * 48 * ASTR];   // 76032 B >= 2*64*ASTR (67584 B)
    __shared__ float hred[256];
    const int tid = threadIdx.x;
    const int g = blockIdx.x / 7, rm = blockIdx.x % 7;
    bool isB; int idx;
    if (g < 562) {
        isB = rm < 3;
        idx = isB ? (g * 3 + rm) : (g * 4 + (rm - 3));
    } else {
        isB = rm < 2;
        idx = isB ? (1686 + rm) : (2248 + (rm - 2));
    }
    const int ln15 = tid & 15, lng = (tid >> 4) & 3, wv = tid >> 6;
    const short* P = planes;

    if (isB) {
        const int row0 = idx * 64;
        short* actH = lds;
        short* actL = lds + 64 * ASTR;
        const int ln = tid & 63;
        const float4 wr = *(const float4*)(tmW0 + 65536 + ln * 4);
        const float4 bb = *(const float4*)(tmB0 + ln * 4);
        for (int i = wv * 16; i < wv * 16 + 16; ++i) {
            int r = row0 + i;
            int srow = r / 15;
            if (srow > 7199) srow = 7199;
            float a = (float)(r % 15);
            float4 u = *(const float4*)(Utm + srow * 256 + ln * 4);
            float sv[4];
            sv[0] = fmaxf(u.x + a * wr.x + bb.x, 0.f);
            sv[1] = fmaxf(u.y + a * wr.y + bb.y, 0.f);
            sv[2] = fmaxf(u.z + a * wr.z + bb.z, 0.f);
            sv[3] = fmaxf(u.w + a * wr.w + bb.w, 0.f);
            split2_write(sv, actH + i * ASTR + ln * 4, actL + i * ASTR + ln * 4);
        }
        __syncthreads();
        layer_g2<4, 2, true,  false, true >(P + 3 * PL,  P + 4 * PL,  tmB1, nullptr, nullptr, nullptr, row0, actH, actL, hred);
        layer_g2<4, 2, true,  false, true >(P + 9 * PL,  P + 10 * PL, b45,  nullptr, nullptr, nullptr, row0, actH, actL, hred);
        layer_g2<4, 2, true,  true,  false>(P + 6 * PL,  P + 7 * PL,  emB1, w5, b5, Vns3, row0, actH, actL, hred);
    } else {
        const int row0 = idx * 48;
        short* actH = lds;
        short* actM = lds + 48 * ASTR;
        short* actL = lds + 2 * 48 * ASTR;
        stage3w<48, false>(Ucr, crW0 + 65536, crB0, row0, actH, actM, actL);
        __syncthreads();
        f32x4 acc[4][3];
#pragma unroll
        for (int a = 0; a < 4; ++a)
#pragma unroll
            for (int b = 0; b < 3; ++b) acc[a][b] = f32x4{0.f,0.f,0.f,0.f};
        mm3<3, 6>(P + 0*PL, P + 1*PL, P + 2*PL, actH, actM, actL, acc);
        float hp[3] = {0.f, 0.f, 0.f};
#pragma unroll
        for (int ct = 0; ct < 4; ++ct) {
            const int colb = wv * 64 + ct * 16 + lng * 4;
            const float4 b1 = *(const float4*)(crB1 + colb);
#pragma unroll
            for (int rt = 0; rt < 3; ++rt) {
                f32x4 v = acc[ct][rt];
                v[0] += b1.x; v[1] += b1.y; v[2] += b1.z; v[3] += b1.w;
#pragma unroll
                for (int j = 0; j < 4; ++j) v[j] = fmaxf(v[j], 0.f);
#pragma unroll
                for (int j = 0; j < 4; ++j) hp[rt] += v[j] * crW2[(colb + j) * 2];
            }
        }
#pragma unroll
        for (int rt = 0; rt < 3; ++rt) {
            hp[rt] += __shfl_xor(hp[rt], 16);
            hp[rt] += __shfl_xor(hp[rt], 32);
        }
        if (lng == 0) {
#pragma unroll
            for (int rt = 0; rt < 3; ++rt) hred[wv * 48 + rt * 16 + ln15] = hp[rt];
        }
        __syncthreads();
        if (tid < 48)
            cont2[row0 + tid] = hred[tid] + hred[48 + tid] + hred[96 + tid] + hred[144 + tid] + crB2[0];
    }
}

extern "C" void kernel_launch(void* const* d_in, const int* in_sizes, int n_in,
                              void* d_out, int out_size, void* d_ws, size_t ws_size,
                              hipStream_t stream)
{
    (void)in_sizes; (void)n_in; (void)out_size; (void)ws_size;
    const float* x    = (const float*)d_in[0];
    const float* emW0 = (const float*)d_in[1];
    const float* emB0 = (const float*)d_in[2];
    const float* emW1 = (const float*)d_in[3];
    const float* emB1 = (const float*)d_in[4];
    const float* emW2 = (const float*)d_in[5];
    const float* emB2 = (const float*)d_in[6];
    const float* vW   = (const float*)d_in[7];
    const float* vb   = (const float*)d_in[8];
    const float* crW0 = (const float*)d_in[9];
    const float* crB0 = (const float*)d_in[10];
    const float* crW1 = (const float*)d_in[11];
    const float* crB1 = (const float*)d_in[12];
    const float* crW2 = (const float*)d_in[13];
    const float* crB2 = (const float*)d_in[14];
    const float* tmW0 = (const float*)d_in[15];
    const float* tmB0 = (const float*)d_in[16];
    const float* tmW1 = (const float*)d_in[17];
    const float* tmB1 = (const float*)d_in[18];
    const float* tmW2 = (const float*)d_in[19];
    const float* tmB2 = (const float*)d_in[20];
    float* out = (float*)d_out;

    float* w     = (float*)d_ws;
    float* rews0 = w;                     // 480
    float* cont1 = rews0 + 480;           // 7200
    float* rews1 = cont1 + 7200;          // 7200
    float* cont2 = rews1 + 7200;          // 108000
    float* Vns3  = cont2 + 108000;        // 108000
    float* U1cr  = Vns3 + 108000;         // 32*256
    float* U1tm  = U1cr + 32 * 256;       // 32*256
    short* planes = (short*)(U1tm + 32 * 256);  // 18 * PL shorts = 2.25 MB
    float* U2cr  = (float*)(planes + 18 * PL);  // 480*256
    float* U2tm  = U2cr + 480 * 256;            // 480*256
    float* Ucr   = U2tm + 480 * 256;            // 7200*256
    float* Utm   = Ucr + 7200 * 256;            // 7200*256
    float* w5    = Utm + 7200 * 256;            // 256
    float* b5    = w5 + 256;                    // 1 (pad to 4)
    float* c2cr  = b5 + 4;                      // 256
    float* c2tm  = c2cr + 256;                  // 256
    float* b45   = c2tm + 256;                  // 256

    front_kernel<<<66, 256, 0, stream>>>(x,
        emW0, emB0, emW1, emB1, emW2, emB2, vW, vb,
        crW0, crW1, tmW0, tmW1, tmW2, tmB2,
        planes, w5, b5, c2cr, c2tm, b45,
        out + NB * NA, U1cr, U1tm);
    stage1m_kernel<<<30, 256, 0, stream>>>(U1cr, U1tm, planes,
        crW0, crB0, crB1, crW2, crB2, tmW0, tmB0, tmB1,
        c2cr, c2tm, rews0, U2cr, U2tm);
    stage2m_kernel<<<450, 256, 0, stream>>>(U2cr, U2tm, planes,
        crW0, crB0, crB1, crW2, crB2, tmW0, tmB0, tmB1,
        c2cr, c2tm, cont1, rews1, Ucr, Utm);
    k3ab_kernel<<<3938, 256, 0, stream>>>(Ucr, Utm, planes,
        crW0, crB0, crB1, crW2, crB2,
        tmW0, tmB0, tmB1, b45, emB1, w5, b5, cont2, Vns3);
    finalize_kernel<<<NB, 256, 0, stream>>>(Vns3, cont2, rews0, rews1, cont1, out);
}

// Round 20
// 244.261 us; speedup vs baseline: 1.4264x; 1.1156x over previous
//
#include <hip/hip_runtime.h>

#define NA 15
#define NB 32
#define DD 256
#define PL 65536  // shorts per weight plane (8 slices x 256 cols x 32 k)
#define ASTR 264  // act LDS row stride (shorts)

using bf16x8 = __attribute__((ext_vector_type(8))) short;
using f32x4  = __attribute__((ext_vector_type(4))) float;

__device__ __forceinline__ unsigned short f2bf(float f){
  unsigned int u = __float_as_uint(f);
  u = u + 0x7fffu + ((u >> 16) & 1u);
  return (unsigned short)(u >> 16);
}
__device__ __forceinline__ float bf2f(unsigned short h){
  return __uint_as_float(((unsigned int)h) << 16);
}
__device__ __forceinline__ unsigned int cvtpk_bf16(float lo, float hi){
    unsigned int r;
    asm("v_cvt_pk_bf16_f32 %0, %1, %2" : "=v"(r) : "v"(lo), "v"(hi));
    return r;
}
__device__ __forceinline__ void split1_write(const float v[4], short* pH){
    unsigned int h01 = cvtpk_bf16(v[0], v[1]);
    unsigned int h23 = cvtpk_bf16(v[2], v[3]);
    *(uint2*)pH = make_uint2(h01, h23);
}
__device__ __forceinline__ void split2_write(const float v[4], short* pH, short* pL){
    unsigned int h01 = cvtpk_bf16(v[0], v[1]);
    unsigned int h23 = cvtpk_bf16(v[2], v[3]);
    float r0 = v[0] - __uint_as_float(h01 << 16);
    float r1 = v[1] - __uint_as_float(h01 & 0xffff0000u);
    float r2 = v[2] - __uint_as_float(h23 << 16);
    float r3 = v[3] - __uint_as_float(h23 & 0xffff0000u);
    unsigned int l01 = cvtpk_bf16(r0, r1);
    unsigned int l23 = cvtpk_bf16(r2, r3);
    *(uint2*)pH = make_uint2(h01, h23);
    *(uint2*)pL = make_uint2(l01, l23);
}
__device__ __forceinline__ void split3_write(const float v[4], short* pH, short* pM, short* pL){
    unsigned int h01 = cvtpk_bf16(v[0], v[1]);
    unsigned int h23 = cvtpk_bf16(v[2], v[3]);
    float r0 = v[0] - __uint_as_float(h01 << 16);
    float r1 = v[1] - __uint_as_float(h01 & 0xffff0000u);
    float r2 = v[2] - __uint_as_float(h23 << 16);
    float r3 = v[3] - __uint_as_float(h23 & 0xffff0000u);
    unsigned int m01 = cvtpk_bf16(r0, r1);
    unsigned int m23 = cvtpk_bf16(r2, r3);
    float s0 = r0 - __uint_as_float(m01 << 16);
    float s1 = r1 - __uint_as_float(m01 & 0xffff0000u);
    float s2 = r2 - __uint_as_float(m23 << 16);
    float s3 = r3 - __uint_as_float(m23 & 0xffff0000u);
    unsigned int l01 = cvtpk_bf16(s0, s1);
    unsigned int l23 = cvtpk_bf16(s2, s3);
    *(uint2*)pH = make_uint2(h01, h23);
    *(uint2*)pM = make_uint2(m01, m23);
    *(uint2*)pL = make_uint2(l01, l23);
}

// ---------------------------------------------------------------------------
// fp32 VALU primitives (value_x branch of front kernel)
// ---------------------------------------------------------------------------
template<int TM, bool RELU>
__device__ __forceinline__ void layer256(
    const float* __restrict__ W, const float* __restrict__ bias,
    const float* act, int K, int lda, float* out, int ldo)
{
    constexpr int RPG = TM / 4;
    const int tid = threadIdx.x;
    const int tr = tid >> 6;
    const int tc = tid & 63;
    float acc[RPG][4];
#pragma unroll
    for (int i = 0; i < RPG; ++i) { acc[i][0]=0.f; acc[i][1]=0.f; acc[i][2]=0.f; acc[i][3]=0.f; }
    const float* wp = W + 4 * tc;
    int k = 0;
    for (; k + 4 <= K; k += 4) {
        float4 w0 = *reinterpret_cast<const float4*>(wp + (k + 0) * DD);
        float4 w1 = *reinterpret_cast<const float4*>(wp + (k + 1) * DD);
        float4 w2 = *reinterpret_cast<const float4*>(wp + (k + 2) * DD);
        float4 w3 = *reinterpret_cast<const float4*>(wp + (k + 3) * DD);
#pragma unroll
        for (int i = 0; i < RPG; ++i) {
            float4 a = *reinterpret_cast<const float4*>(act + (RPG * tr + i) * lda + k);
            acc[i][0] += a.x * w0.x + a.y * w1.x + a.z * w2.x + a.w * w3.x;
            acc[i][1] += a.x * w0.y + a.y * w1.y + a.z * w2.y + a.w * w3.y;
            acc[i][2] += a.x * w0.z + a.y * w1.z + a.z * w2.z + a.w * w3.z;
            acc[i][3] += a.x * w0.w + a.y * w1.w + a.z * w2.w + a.w * w3.w;
        }
    }
    for (; k < K; ++k) {
        float4 w0 = *reinterpret_cast<const float4*>(wp + k * DD);
#pragma unroll
        for (int i = 0; i < RPG; ++i) {
            float a = act[(RPG * tr + i) * lda + k];
            acc[i][0] += a * w0.x; acc[i][1] += a * w0.y;
            acc[i][2] += a * w0.z; acc[i][3] += a * w0.w;
        }
    }
    float4 bb = *reinterpret_cast<const float4*>(bias + 4 * tc);
#pragma unroll
    for (int i = 0; i < RPG; ++i) {
        float4 o;
        o.x = acc[i][0] + bb.x; o.y = acc[i][1] + bb.y;
        o.z = acc[i][2] + bb.z; o.w = acc[i][3] + bb.w;
        if (RELU) {
            o.x = fmaxf(o.x, 0.f); o.y = fmaxf(o.y, 0.f);
            o.z = fmaxf(o.z, 0.f); o.w = fmaxf(o.w, 0.f);
        }
        *reinterpret_cast<float4*>(out + (RPG * tr + i) * ldo + 4 * tc) = o;
    }
}

template<int TM>
__device__ __forceinline__ void head1c(
    const float* h, int ldh, const float* __restrict__ W, int wstr, int col, float bias,
    float* __restrict__ gout, int gbase)
{
    const int wv = threadIdx.x >> 6;
    const int lane = threadIdx.x & 63;
    for (int rr = wv; rr < TM; rr += 4) {
        float p = 0.f;
#pragma unroll
        for (int t = 0; t < 4; ++t) {
            int k = lane + 64 * t;
            p += h[rr * ldh + k] * W[k * wstr + col];
        }
#pragma unroll
        for (int m = 1; m < 64; m <<= 1) p += __shfl_xor(p, m);
        if (lane == 0) gout[gbase + rr] = p + bias;
    }
}

// ---------------------------------------------------------------------------
// front_kernel (unchanged from R15/R16)
// ---------------------------------------------------------------------------
__global__ __launch_bounds__(256) void front_kernel(
    const float* __restrict__ x,
    const float* __restrict__ emW0, const float* __restrict__ emB0,
    const float* __restrict__ emW1, const float* __restrict__ emB1,
    const float* __restrict__ emW2, const float* __restrict__ emB2,
    const float* __restrict__ vW, const float* __restrict__ vb,
    const float* __restrict__ crW0, const float* __restrict__ crW1,
    const float* __restrict__ tmW0, const float* __restrict__ tmW1,
    const float* __restrict__ tmW2, const float* __restrict__ tmB2,
    short* __restrict__ planes, float* __restrict__ w5, float* __restrict__ b5,
    float* __restrict__ c2cr, float* __restrict__ c2tm, float* __restrict__ b45,
    float* __restrict__ vout, float* __restrict__ U1cr, float* __restrict__ U1tm)
{
    __shared__ __align__(16) float smem[32 * DD];
    const int blk = blockIdx.x;
    const int tid = threadIdx.x;

    if (blk < 24) {
        const int mat = blk >> 3;
        const int kk  = blk & 7;
        const float* W = (mat == 0) ? crW1 : (mat == 1) ? tmW1 : emW1;
        const int col = tid;
        short bh[32], bm[32], bl[32];
#pragma unroll
        for (int j = 0; j < 32; ++j) {
            float w = W[(kk * 32 + j) * 256 + col];
            unsigned short h = f2bf(w); float fh = bf2f(h);
            float r1 = w - fh;
            unsigned short m = f2bf(r1); float fm = bf2f(m);
            bh[j] = (short)h; bm[j] = (short)m; bl[j] = (short)f2bf(r1 - fm);
        }
        short* pH = planes + (size_t)(mat * 3 + 0) * PL + kk * 8192 + col * 32;
        short* pM = planes + (size_t)(mat * 3 + 1) * PL + kk * 8192 + col * 32;
        short* pLp = planes + (size_t)(mat * 3 + 2) * PL + kk * 8192 + col * 32;
#pragma unroll
        for (int j = 0; j < 32; j += 4) {
            *(short4*)(pH + j) = make_short4(bh[j], bh[j+1], bh[j+2], bh[j+3]);
            *(short4*)(pM + j) = make_short4(bm[j], bm[j+1], bm[j+2], bm[j+3]);
            *(short4*)(pLp + j) = make_short4(bl[j], bl[j+1], bl[j+2], bl[j+3]);
        }
    } else if (blk == 24) {
        float acc = 0.f;
        for (int j = 0; j < 256; j += 4) {
            float4 wrow = *(const float4*)(emW2 + tid * 256 + j);
            float4 vv   = *(const float4*)(vW + j);
            acc += wrow.x * vv.x + wrow.y * vv.y + wrow.z * vv.z + wrow.w * vv.w;
        }
        w5[tid] = acc;
        if (tid == 0) {
            float b = 0.f;
            for (int j = 0; j < 256; ++j) b += emB2[j] * vW[j];
            b5[0] = b + vb[0];
        }
    } else if (blk < 33) {
        constexpr int TM = 4;
        float* bufA = smem;
        float* bufB = bufA + TM * DD;
        float* bufC = bufB + TM * DD;
        const int row0 = (blk - 25) * TM;
        for (int i = 0; i < TM; ++i) bufA[i * DD + tid] = x[(row0 + i) * DD + tid];
        __syncthreads();
        layer256<TM, true >(emW0, emB0, bufA, 256, DD, bufB, DD); __syncthreads();
        layer256<TM, true >(emW1, emB1, bufB, 256, DD, bufC, DD); __syncthreads();
        layer256<TM, false>(emW2, emB2, bufC, 256, DD, bufB, DD); __syncthreads();
        head1c<TM>(bufB, DD, vW, 1, 0, vb[0], vout, row0);
    } else if (blk < 41) {
        const int row0 = (blk - 33) * 4;
        float* xs = smem;   // [4][256]
        for (int i = 0; i < 4; ++i) xs[i * 256 + tid] = x[(row0 + i) * 256 + tid];
        __syncthreads();
        float acr[4] = {0.f,0.f,0.f,0.f}, atm[4] = {0.f,0.f,0.f,0.f};
        for (int k = 0; k < 256; ++k) {
            float wc = crW0[k * 256 + tid];
            float wt = tmW0[k * 256 + tid];
#pragma unroll
            for (int i = 0; i < 4; ++i) {
                acr[i] += xs[i * 256 + k] * wc;
                atm[i] += xs[i * 256 + k] * wt;
            }
        }
        for (int i = 0; i < 4; ++i) {
            U1cr[(row0 + i) * 256 + tid] = acr[i];
            U1tm[(row0 + i) * 256 + tid] = atm[i];
        }
    } else if (blk < 65) {
        const int pb = blk - 41;
        const int prod = pb >> 3;           // 0=W45, 1=W2cr, 2=W2tm
        const int r0 = (pb & 7) * 32;
        const float* B = (prod == 0) ? emW0 : (prod == 1) ? crW0 : tmW0;
        const int pbase = 9 + prod * 3;
        float* As = smem;   // [32][256]
        for (int i = tid; i < 32 * 256; i += 256)
            As[i] = tmW2[(r0 + (i >> 8)) * 256 + (i & 255)];
        __syncthreads();
        float acc[32];
#pragma unroll
        for (int j = 0; j < 32; ++j) acc[j] = 0.f;
        for (int m = 0; m < 256; ++m) {
            float b = B[m * 256 + tid];
#pragma unroll
            for (int j = 0; j < 32; ++j) acc[j] += As[j * 256 + m] * b;
        }
        short bh[32], bm[32], bl[32];
#pragma unroll
        for (int j = 0; j < 32; ++j) {
            float w = acc[j];
            unsigned short h = f2bf(w); float fh = bf2f(h);
            float r1 = w - fh;
            unsigned short mm = f2bf(r1); float fm = bf2f(mm);
            bh[j] = (short)h; bm[j] = (short)mm; bl[j] = (short)f2bf(r1 - fm);
        }
        const int kk = r0 >> 5;
        short* pH = planes + (size_t)(pbase + 0) * PL + kk * 8192 + tid * 32;
        short* pM = planes + (size_t)(pbase + 1) * PL + kk * 8192 + tid * 32;
        short* pLp = planes + (size_t)(pbase + 2) * PL + kk * 8192 + tid * 32;
#pragma unroll
        for (int j = 0; j < 32; j += 4) {
            *(short4*)(pH + j) = make_short4(bh[j], bh[j+1], bh[j+2], bh[j+3]);
            *(short4*)(pM + j) = make_short4(bm[j], bm[j+1], bm[j+2], bm[j+3]);
            *(short4*)(pLp + j) = make_short4(bl[j], bl[j+1], bl[j+2], bl[j+3]);
        }
    } else {
        const int j = tid;
        float a0 = 0.f, a1 = 0.f, a2 = 0.f;
        for (int k = 0; k < 256; ++k) {
            float t = tmB2[k];
            a0 += t * crW0[k * 256 + j];
            a1 += t * tmW0[k * 256 + j];
            a2 += t * emW0[k * 256 + j];
        }
        c2cr[j] = a0;
        c2tm[j] = a1;
        b45[j] = a2 + emB0[j];
    }
}

__global__ __launch_bounds__(256) void finalize_kernel(
    const float* __restrict__ Vns3, const float* __restrict__ cont2,
    const float* __restrict__ rews0, const float* __restrict__ rews1,
    const float* __restrict__ cont1, float* __restrict__ out)
{
    const int b = blockIdx.x;
    const int tid = threadIdx.x;
    __shared__ float vs2[NA][NA];
    __shared__ float vs3[NA];
    if (tid < NA * NA) {
        const int x = tid / NA, y = tid % NA;
        float vals[NA];
        float m = -INFINITY;
#pragma unroll
        for (int z = 0; z < NA; ++z) {
            int vidx = ((b * NA + y) * NA + z) * NA + x;
            int cidx = ((b * NA + x) * NA + y) * NA + z;
            float c1 = rews0[b * NA + z] * 0.99f;
            float c2 = (c1 + rews1[(b * NA + x) * NA + z]) * 0.99f;
            float v = Vns3[vidx] * 0.970299f + c2;
            if (cont2[cidx] > 0.f) v = 0.f;
            vals[z] = v;
            m = fmaxf(m, v);
        }
        float se = 0.f, sw = 0.f;
#pragma unroll
        for (int z = 0; z < NA; ++z) { float e = expf(vals[z] - m); se += e; sw += e * vals[z]; }
        vs2[x][y] = sw / se;
    }
    __syncthreads();
    if (tid < NA) {
        const int x = tid;
        float vals[NA];
        float m = -INFINITY;
#pragma unroll
        for (int y = 0; y < NA; ++y) {
            float v = vs2[x][y];
            if (cont1[(b * NA + x) * NA + y] > 0.f) v = 0.f;
            vals[y] = v;
            m = fmaxf(m, v);
        }
        float se = 0.f, sw = 0.f;
#pragma unroll
        for (int y = 0; y < NA; ++y) { float e = expf(vals[y] - m); se += e; sw += e * vals[y]; }
        vs3[x] = sw / se;
    }
    __syncthreads();
    if (tid == 0) {
        float m = -INFINITY;
#pragma unroll
        for (int x = 0; x < NA; ++x) m = fmaxf(m, vs3[x]);
        float se = 0.f;
#pragma unroll
        for (int x = 0; x < NA; ++x) se += expf(vs3[x] - m);
        float l = logf(se);
#pragma unroll
        for (int x = 0; x < NA; ++x) out[b * NA + x] = vs3[x] - m - l;
    }
}

// ---------------------------------------------------------------------------
// mm3: accumulate RT row-tiles x 4 col-tiles over K=256 with NP passes.
// ---------------------------------------------------------------------------
template<int RT, int NP>
__device__ __forceinline__ void mm3(
    const short* __restrict__ plH, const short* __restrict__ plM, const short* __restrict__ plL,
    const short* actH, const short* actM, const short* actL,
    f32x4 (&acc)[4][RT])
{
    const int tid = threadIdx.x;
    const int ln15 = tid & 15, lng = (tid >> 4) & 3, wv = tid >> 6;
    const int wo = (wv * 64 + ln15) * 32 + lng * 8;
#pragma unroll
    for (int kk = 0; kk < 8; ++kk) {
        bf16x8 wH[4], wM[4], wL[4], xH[RT], xM[RT], xL[RT];
#pragma unroll
        for (int ct = 0; ct < 4; ++ct) {
            wH[ct] = *(const bf16x8*)(plH + wo + kk * 8192 + ct * 512);
            wM[ct] = *(const bf16x8*)(plM + wo + kk * 8192 + ct * 512);
            if (NP == 6) wL[ct] = *(const bf16x8*)(plL + wo + kk * 8192 + ct * 512);
        }
#pragma unroll
        for (int rt = 0; rt < RT; ++rt) {
            int off = (rt * 16 + ln15) * ASTR + kk * 32 + lng * 8;
            xH[rt] = *(const bf16x8*)(actH + off);
            xM[rt] = *(const bf16x8*)(actM + off);
            if (NP == 6) xL[rt] = *(const bf16x8*)(actL + off);
        }
        __builtin_amdgcn_s_setprio(1);
#pragma unroll
        for (int ct = 0; ct < 4; ++ct)
#pragma unroll
            for (int rt = 0; rt < RT; ++rt) {
                acc[ct][rt] = __builtin_amdgcn_mfma_f32_16x16x32_bf16(wH[ct], xH[rt], acc[ct][rt], 0, 0, 0);
                acc[ct][rt] = __builtin_amdgcn_mfma_f32_16x16x32_bf16(wH[ct], xM[rt], acc[ct][rt], 0, 0, 0);
                acc[ct][rt] = __builtin_amdgcn_mfma_f32_16x16x32_bf16(wM[ct], xH[rt], acc[ct][rt], 0, 0, 0);
                if (NP == 6) {
                    acc[ct][rt] = __builtin_amdgcn_mfma_f32_16x16x32_bf16(wM[ct], xM[rt], acc[ct][rt], 0, 0, 0);
                    acc[ct][rt] = __builtin_amdgcn_mfma_f32_16x16x32_bf16(wH[ct], xL[rt], acc[ct][rt], 0, 0, 0);
                    acc[ct][rt] = __builtin_amdgcn_mfma_f32_16x16x32_bf16(wL[ct], xH[rt], acc[ct][rt], 0, 0, 0);
                }
            }
        __builtin_amdgcn_s_setprio(0);
    }
}

// stage a 3-way-split activation row block from U + a*wrow + bias (relu)
template<int ROWS, bool CLAMP>
__device__ __forceinline__ void stage3w(
    const float* __restrict__ U, const float* __restrict__ wrow256,
    const float* __restrict__ bias, int row0,
    short* actH, short* actM, short* actL)
{
    const int tid = threadIdx.x;
    const int wv = tid >> 6, ln = tid & 63;
    constexpr int RPW = ROWS / 4;
    const float4 wr = *(const float4*)(wrow256 + ln * 4);
    const float4 bb = *(const float4*)(bias + ln * 4);
    for (int i = wv * RPW; i < wv * RPW + RPW; ++i) {
        int r = row0 + i;
        int srow = r / 15;
        if (CLAMP && srow > 7199) srow = 7199;
        float a = (float)(r % 15);
        float4 u = *(const float4*)(U + srow * 256 + ln * 4);
        float sv[4];
        sv[0] = fmaxf(u.x + a * wr.x + bb.x, 0.f);
        sv[1] = fmaxf(u.y + a * wr.y + bb.y, 0.f);
        sv[2] = fmaxf(u.z + a * wr.z + bb.z, 0.f);
        sv[3] = fmaxf(u.w + a * wr.w + bb.w, 0.f);
        split3_write(sv, actH + i * ASTR + ln * 4, actM + i * ASTR + ln * 4, actL + i * ASTR + ln * 4);
    }
}

// ---------------------------------------------------------------------------
// stage1m: 480 rows (b,a1), 30 blocks x 16 rows. rews0 + U2cr/U2tm.
// ---------------------------------------------------------------------------
__global__ __launch_bounds__(256, 2) void stage1m_kernel(
    const float* __restrict__ U1cr, const float* __restrict__ U1tm,
    const short* __restrict__ planes,
    const float* __restrict__ crW0, const float* __restrict__ crB0,
    const float* __restrict__ crB1, const float* __restrict__ crW2, const float* __restrict__ crB2,
    const float* __restrict__ tmW0, const float* __restrict__ tmB0,
    const float* __restrict__ tmB1,
    const float* __restrict__ c2cr, const float* __restrict__ c2tm,
    float* __restrict__ rews0, float* __restrict__ U2cr, float* __restrict__ U2tm)
{
    __shared__ short actH[16 * ASTR];
    __shared__ short actM[16 * ASTR];
    __shared__ short actL[16 * ASTR];
    __shared__ float hred[64];
    const int tid = threadIdx.x;
    const int row0 = blockIdx.x * 16;
    const int ln15 = tid & 15, lng = (tid >> 4) & 3, wv = tid >> 6;

    stage3w<16, false>(U1cr, crW0 + 65536, crB0, row0, actH, actM, actL);
    __syncthreads();
    {
        f32x4 acc[4][1];
#pragma unroll
        for (int a = 0; a < 4; ++a) acc[a][0] = f32x4{0.f,0.f,0.f,0.f};
        mm3<1, 6>(planes + 0*PL, planes + 1*PL, planes + 2*PL, actH, actM, actL, acc);
        float hp = 0.f;
#pragma unroll
        for (int ct = 0; ct < 4; ++ct) {
            const int colb = wv * 64 + ct * 16 + lng * 4;
            const float4 b1 = *(const float4*)(crB1 + colb);
            f32x4 v = acc[ct][0];
            v[0] += b1.x; v[1] += b1.y; v[2] += b1.z; v[3] += b1.w;
#pragma unroll
            for (int j = 0; j < 4; ++j) v[j] = fmaxf(v[j], 0.f);
#pragma unroll
            for (int j = 0; j < 4; ++j) hp += v[j] * crW2[(colb + j) * 2 + 1];
        }
        hp += __shfl_xor(hp, 16);
        hp += __shfl_xor(hp, 32);
        if (lng == 0) hred[wv * 16 + ln15] = hp;
        __syncthreads();
        if (tid < 16) rews0[row0 + tid] = hred[tid] + hred[16 + tid] + hred[32 + tid] + hred[48 + tid] + crB2[1];
        __syncthreads();
    }

    stage3w<16, false>(U1tm, tmW0 + 65536, tmB0, row0, actH, actM, actL);
    __syncthreads();
    {
        f32x4 acc[4][1];
#pragma unroll
        for (int a = 0; a < 4; ++a) acc[a][0] = f32x4{0.f,0.f,0.f,0.f};
        mm3<1, 6>(planes + 3*PL, planes + 4*PL, planes + 5*PL, actH, actM, actL, acc);
        __syncthreads();
#pragma unroll
        for (int ct = 0; ct < 4; ++ct) {
            const int colb = wv * 64 + ct * 16 + lng * 4;
            const float4 bb = *(const float4*)(tmB1 + colb);
            f32x4 v = acc[ct][0];
            v[0] += bb.x; v[1] += bb.y; v[2] += bb.z; v[3] += bb.w;
#pragma unroll
            for (int j = 0; j < 4; ++j) v[j] = fmaxf(v[j], 0.f);
            float sv[4] = {v[0], v[1], v[2], v[3]};
            const int ao = ln15 * ASTR + colb;
            split3_write(sv, actH + ao, actM + ao, actL + ao);
        }
        __syncthreads();
    }
    {
        f32x4 acc[4][1];
#pragma unroll
        for (int a = 0; a < 4; ++a) acc[a][0] = f32x4{0.f,0.f,0.f,0.f};
        mm3<1, 6>(planes + 12*PL, planes + 13*PL, planes + 14*PL, actH, actM, actL, acc);
#pragma unroll
        for (int ct = 0; ct < 4; ++ct) {
            const int colb = wv * 64 + ct * 16 + lng * 4;
            const float4 cc = *(const float4*)(c2cr + colb);
            float4 o; o.x = acc[ct][0][0] + cc.x; o.y = acc[ct][0][1] + cc.y;
            o.z = acc[ct][0][2] + cc.z; o.w = acc[ct][0][3] + cc.w;
            *(float4*)(U2cr + (row0 + ln15) * 256 + colb) = o;
        }
    }
    {
        f32x4 acc[4][1];
#pragma unroll
        for (int a = 0; a < 4; ++a) acc[a][0] = f32x4{0.f,0.f,0.f,0.f};
        mm3<1, 6>(planes + 15*PL, planes + 16*PL, planes + 17*PL, actH, actM, actL, acc);
#pragma unroll
        for (int ct = 0; ct < 4; ++ct) {
            const int colb = wv * 64 + ct * 16 + lng * 4;
            const float4 cc = *(const float4*)(c2tm + colb);
            float4 o; o.x = acc[ct][0][0] + cc.x; o.y = acc[ct][0][1] + cc.y;
            o.z = acc[ct][0][2] + cc.z; o.w = acc[ct][0][3] + cc.w;
            *(float4*)(U2tm + (row0 + ln15) * 256 + colb) = o;
        }
    }
}

// ---------------------------------------------------------------------------
// stage2m: 7200 rows, 450 blocks x 16 rows. cont1/rews1 + Ucr/Utm (permuted).
// ---------------------------------------------------------------------------
__global__ __launch_bounds__(256, 2) void stage2m_kernel(
    const float* __restrict__ U2cr, const float* __restrict__ U2tm,
    const short* __restrict__ planes,
    const float* __restrict__ crW0, const float* __restrict__ crB0,
    const float* __restrict__ crB1, const float* __restrict__ crW2, const float* __restrict__ crB2,
    const float* __restrict__ tmW0, const float* __restrict__ tmB0,
    const float* __restrict__ tmB1,
    const float* __restrict__ c2cr, const float* __restrict__ c2tm,
    float* __restrict__ cont1, float* __restrict__ rews1,
    float* __restrict__ Ucr, float* __restrict__ Utm)
{
    __shared__ short actH[16 * ASTR];
    __shared__ short actM[16 * ASTR];
    __shared__ short actL[16 * ASTR];
    __shared__ float hred[2][64];
    const int tid = threadIdx.x;
    const int row0 = blockIdx.x * 16;
    const int ln15 = tid & 15, lng = (tid >> 4) & 3, wv = tid >> 6;

    stage3w<16, false>(U2cr, crW0 + 65536, crB0, row0, actH, actM, actL);
    __syncthreads();
    {
        f32x4 acc[4][1];
#pragma unroll
        for (int a = 0; a < 4; ++a) acc[a][0] = f32x4{0.f,0.f,0.f,0.f};
        mm3<1, 6>(planes + 0*PL, planes + 1*PL, planes + 2*PL, actH, actM, actL, acc);
        float hp0 = 0.f, hp1 = 0.f;
#pragma unroll
        for (int ct = 0; ct < 4; ++ct) {
            const int colb = wv * 64 + ct * 16 + lng * 4;
            const float4 b1 = *(const float4*)(crB1 + colb);
            f32x4 v = acc[ct][0];
            v[0] += b1.x; v[1] += b1.y; v[2] += b1.z; v[3] += b1.w;
#pragma unroll
            for (int j = 0; j < 4; ++j) v[j] = fmaxf(v[j], 0.f);
#pragma unroll
            for (int j = 0; j < 4; ++j) {
                hp0 += v[j] * crW2[(colb + j) * 2 + 0];
                hp1 += v[j] * crW2[(colb + j) * 2 + 1];
            }
        }
        hp0 += __shfl_xor(hp0, 16); hp0 += __shfl_xor(hp0, 32);
        hp1 += __shfl_xor(hp1, 16); hp1 += __shfl_xor(hp1, 32);
        if (lng == 0) {
            hred[0][wv * 16 + ln15] = hp0;
            hred[1][wv * 16 + ln15] = hp1;
        }
        __syncthreads();
        if (tid < 16)
            cont1[row0 + tid] = hred[0][tid] + hred[0][16 + tid] + hred[0][32 + tid] + hred[0][48 + tid] + crB2[0];
        else if (tid >= 64 && tid < 80)
            rews1[row0 + tid - 64] = hred[1][tid - 64] + hred[1][16 + tid - 64] + hred[1][32 + tid - 64] + hred[1][48 + tid - 64] + crB2[1];
        __syncthreads();
    }

    stage3w<16, false>(U2tm, tmW0 + 65536, tmB0, row0, actH, actM, actL);
    __syncthreads();
    {
        f32x4 acc[4][1];
#pragma unroll
        for (int a = 0; a < 4; ++a) acc[a][0] = f32x4{0.f,0.f,0.f,0.f};
        mm3<1, 6>(planes + 3*PL, planes + 4*PL, planes + 5*PL, actH, actM, actL, acc);
        __syncthreads();
#pragma unroll
        for (int ct = 0; ct < 4; ++ct) {
            const int colb = wv * 64 + ct * 16 + lng * 4;
            const float4 bb = *(const float4*)(tmB1 + colb);
            f32x4 v = acc[ct][0];
            v[0] += bb.x; v[1] += bb.y; v[2] += bb.z; v[3] += bb.w;
#pragma unroll
            for (int j = 0; j < 4; ++j) v[j] = fmaxf(v[j], 0.f);
            float sv[4] = {v[0], v[1], v[2], v[3]};
            const int ao = ln15 * ASTR + colb;
            split3_write(sv, actH + ao, actM + ao, actL + ao);
        }
        __syncthreads();
    }
    int pr;
    {
        int r = row0 + ln15;
        int b = r / 225, a1 = (r / 15) % 15, a2 = r % 15;
        pr = (b * 15 + a2) * 15 + a1;
    }
    {
        f32x4 acc[4][1];
#pragma unroll
        for (int a = 0; a < 4; ++a) acc[a][0] = f32x4{0.f,0.f,0.f,0.f};
        mm3<1, 6>(planes + 12*PL, planes + 13*PL, planes + 14*PL, actH, actM, actL, acc);
#pragma unroll
        for (int ct = 0; ct < 4; ++ct) {
            const int colb = wv * 64 + ct * 16 + lng * 4;
            const float4 cc = *(const float4*)(c2cr + colb);
            float4 o; o.x = acc[ct][0][0] + cc.x; o.y = acc[ct][0][1] + cc.y;
            o.z = acc[ct][0][2] + cc.z; o.w = acc[ct][0][3] + cc.w;
            *(float4*)(Ucr + pr * 256 + colb) = o;
        }
    }
    {
        f32x4 acc[4][1];
#pragma unroll
        for (int a = 0; a < 4; ++a) acc[a][0] = f32x4{0.f,0.f,0.f,0.f};
        mm3<1, 3>(planes + 15*PL, planes + 16*PL, planes + 17*PL, actH, actM, actL, acc);
#pragma unroll
        for (int ct = 0; ct < 4; ++ct) {
            const int colb = wv * 64 + ct * 16 + lng * 4;
            const float4 cc = *(const float4*)(c2tm + colb);
            float4 o; o.x = acc[ct][0][0] + cc.x; o.y = acc[ct][0][1] + cc.y;
            o.z = acc[ct][0][2] + cc.z; o.w = acc[ct][0][3] + cc.w;
            *(float4*)(Utm + pr * 256 + colb) = o;
        }
    }
}

// ---------------------------------------------------------------------------
// layer_b1: pure-bf16 1-pass 16x16x32 layer over RT*16-row act tile
// (mask-free, double-softmax-contracted k3b path only; single act plane).
// ---------------------------------------------------------------------------
template<int RT, bool RELU, bool HEAD, bool WRITEACT>
__device__ __forceinline__ void layer_b1(
    const short* __restrict__ plH,
    const float* __restrict__ bias,
    const float* __restrict__ headW, const float* __restrict__ headB,
    float* __restrict__ headOut, int row0,
    short* actH, float* hred)
{
    const int tid = threadIdx.x;
    const int ln15 = tid & 15, lng = (tid >> 4) & 3, wv = tid >> 6;
    const int wo = (wv * 64 + ln15) * 32 + lng * 8;
    f32x4 acc[4][RT];
#pragma unroll
    for (int a = 0; a < 4; ++a)
#pragma unroll
        for (int b = 0; b < RT; ++b) acc[a][b] = f32x4{0.f, 0.f, 0.f, 0.f};

#pragma unroll
    for (int kk = 0; kk < 8; ++kk) {
        bf16x8 aH[4], bH[RT];
#pragma unroll
        for (int ct = 0; ct < 4; ++ct)
            aH[ct] = *(const bf16x8*)(plH + wo + kk * 8192 + ct * 512);
#pragma unroll
        for (int rt = 0; rt < RT; ++rt) {
            int off = (rt * 16 + ln15) * ASTR + kk * 32 + lng * 8;
            bH[rt] = *(const bf16x8*)(actH + off);
        }
        __builtin_amdgcn_s_setprio(1);
#pragma unroll
        for (int ct = 0; ct < 4; ++ct)
#pragma unroll
            for (int rt = 0; rt < RT; ++rt)
                acc[ct][rt] = __builtin_amdgcn_mfma_f32_16x16x32_bf16(aH[ct], bH[rt], acc[ct][rt], 0, 0, 0);
        __builtin_amdgcn_s_setprio(0);
    }
    __syncthreads();

    float hp[RT];
#pragma unroll
    for (int rt = 0; rt < RT; ++rt) hp[rt] = 0.f;
#pragma unroll
    for (int ct = 0; ct < 4; ++ct) {
        const int colb = wv * 64 + ct * 16 + lng * 4;
        const float4 bb = *(const float4*)(bias + colb);
#pragma unroll
        for (int rt = 0; rt < RT; ++rt) {
            f32x4 v = acc[ct][rt];
            v[0] += bb.x; v[1] += bb.y; v[2] += bb.z; v[3] += bb.w;
            if (RELU) {
#pragma unroll
                for (int j = 0; j < 4; ++j) v[j] = fmaxf(v[j], 0.f);
            }
            if (HEAD) {
                const float4 hw = *(const float4*)(headW + colb);
                hp[rt] += v[0] * hw.x + v[1] * hw.y + v[2] * hw.z + v[3] * hw.w;
            }
            if (WRITEACT) {
                float sv[4] = {v[0], v[1], v[2], v[3]};
                const int ao = (rt * 16 + ln15) * ASTR + colb;
                split1_write(sv, actH + ao);
            }
        }
    }
    if constexpr (HEAD) {
        constexpr int NR = RT * 16;
#pragma unroll
        for (int rt = 0; rt < RT; ++rt) {
            hp[rt] += __shfl_xor(hp[rt], 16);
            hp[rt] += __shfl_xor(hp[rt], 32);
        }
        if (lng == 0) {
#pragma unroll
            for (int rt = 0; rt < RT; ++rt) hred[wv * NR + rt * 16 + ln15] = hp[rt];
        }
        __syncthreads();
        if (tid < NR && row0 + tid < 108000) {
            float s = hred[tid] + hred[NR + tid] + hred[2 * NR + tid] + hred[3 * NR + tid] + headB[0];
            headOut[row0 + tid] = s;
        }
    }
    if constexpr (WRITEACT) __syncthreads();
}

// ---------------------------------------------------------------------------
// k3ab: fused stage-3, 2 blocks/CU. k3b: pure-bf16 1-pass, 128-row tiles
// (single act plane = 67.5KB), 844 blocks. k3a: 48-row 6-pass fp32-grade,
// 2250 blocks. Interleave 3:8 in groups of 11 (281 groups) + 3 = 3094 blocks.
// LDS: max(3*48, 128)*ASTR*2 = 76032 B + hred 2KB -> 2 blocks/CU.
// ---------------------------------------------------------------------------
__global__ __launch_bounds__(256, 2) void k3ab_kernel(
    const float* __restrict__ Ucr, const float* __restrict__ Utm,
    const short* __restrict__ planes,
    const float* __restrict__ crW0, const float* __restrict__ crB0,
    const float* __restrict__ crB1, const float* __restrict__ crW2,
    const float* __restrict__ crB2,
    const float* __restrict__ tmW0, const float* __restrict__ tmB0,
    const float* __restrict__ tmB1,
    const float* __restrict__ b45, const float* __restrict__ emB1,
    const float* __restrict__ w5, const float* __restrict__ b5,
    float* __restrict__ cont2, float* __restrict__ Vns3)
{
    __shared__ short lds[3 * 48 * ASTR];   // 76032 B >= 128*ASTR (67584 B)
    __shared__ float hred[512];
    const int tid = threadIdx.x;
    const int g = blockIdx.x / 11, rm = blockIdx.x % 11;
    bool isB; int idx;
    if (g < 281) {
        isB = rm < 3;
        idx = isB ? (g * 3 + rm) : (g * 8 + (rm - 3));
    } else {   // g == 281, rm in 0..2
        isB = rm < 1;
        idx = isB ? 843 : (2248 + (rm - 1));
    }
    const int ln15 = tid & 15, lng = (tid >> 4) & 3, wv = tid >> 6;
    const short* P = planes;

    if (isB) {
        const int row0 = idx * 128;
        short* actH = lds;
        const int ln = tid & 63;
        const float4 wr = *(const float4*)(tmW0 + 65536 + ln * 4);
        const float4 bb = *(const float4*)(tmB0 + ln * 4);
        for (int i = wv * 32; i < wv * 32 + 32; ++i) {
            int r = row0 + i;
            int srow = r / 15;
            if (srow > 7199) srow = 7199;
            float a = (float)(r % 15);
            float4 u = *(const float4*)(Utm + srow * 256 + ln * 4);
            float sv[4];
            sv[0] = fmaxf(u.x + a * wr.x + bb.x, 0.f);
            sv[1] = fmaxf(u.y + a * wr.y + bb.y, 0.f);
            sv[2] = fmaxf(u.z + a * wr.z + bb.z, 0.f);
            sv[3] = fmaxf(u.w + a * wr.w + bb.w, 0.f);
            split1_write(sv, actH + i * ASTR + ln * 4);
        }
        __syncthreads();
        layer_b1<8, true,  false, true >(P + 3 * PL, tmB1, nullptr, nullptr, nullptr, row0, actH, hred);
        layer_b1<8, true,  false, true >(P + 9 * PL, b45,  nullptr, nullptr, nullptr, row0, actH, hred);
        layer_b1<8, true,  true,  false>(P + 6 * PL, emB1, w5, b5, Vns3, row0, actH, hred);
    } else {
        const int row0 = idx * 48;
        short* actH = lds;
        short* actM = lds + 48 * ASTR;
        short* actL = lds + 2 * 48 * ASTR;
        stage3w<48, false>(Ucr, crW0 + 65536, crB0, row0, actH, actM, actL);
        __syncthreads();
        f32x4 acc[4][3];
#pragma unroll
        for (int a = 0; a < 4; ++a)
#pragma unroll
            for (int b = 0; b < 3; ++b) acc[a][b] = f32x4{0.f,0.f,0.f,0.f};
        mm3<3, 6>(P + 0*PL, P + 1*PL, P + 2*PL, actH, actM, actL, acc);
        float hp[3] = {0.f, 0.f, 0.f};
#pragma unroll
        for (int ct = 0; ct < 4; ++ct) {
            const int colb = wv * 64 + ct * 16 + lng * 4;
            const float4 b1 = *(const float4*)(crB1 + colb);
#pragma unroll
            for (int rt = 0; rt < 3; ++rt) {
                f32x4 v = acc[ct][rt];
                v[0] += b1.x; v[1] += b1.y; v[2] += b1.z; v[3] += b1.w;
#pragma unroll
                for (int j = 0; j < 4; ++j) v[j] = fmaxf(v[j], 0.f);
#pragma unroll
                for (int j = 0; j < 4; ++j) hp[rt] += v[j] * crW2[(colb + j) * 2];
            }
        }
#pragma unroll
        for (int rt = 0; rt < 3; ++rt) {
            hp[rt] += __shfl_xor(hp[rt], 16);
            hp[rt] += __shfl_xor(hp[rt], 32);
        }
        if (lng == 0) {
#pragma unroll
            for (int rt = 0; rt < 3; ++rt) hred[wv * 48 + rt * 16 + ln15] = hp[rt];
        }
        __syncthreads();
        if (tid < 48)
            cont2[row0 + tid] = hred[tid] + hred[48 + tid] + hred[96 + tid] + hred[144 + tid] + crB2[0];
    }
}

extern "C" void kernel_launch(void* const* d_in, const int* in_sizes, int n_in,
                              void* d_out, int out_size, void* d_ws, size_t ws_size,
                              hipStream_t stream)
{
    (void)in_sizes; (void)n_in; (void)out_size; (void)ws_size;
    const float* x    = (const float*)d_in[0];
    const float* emW0 = (const float*)d_in[1];
    const float* emB0 = (const float*)d_in[2];
    const float* emW1 = (const float*)d_in[3];
    const float* emB1 = (const float*)d_in[4];
    const float* emW2 = (const float*)d_in[5];
    const float* emB2 = (const float*)d_in[6];
    const float* vW   = (const float*)d_in[7];
    const float* vb   = (const float*)d_in[8];
    const float* crW0 = (const float*)d_in[9];
    const float* crB0 = (const float*)d_in[10];
    const float* crW1 = (const float*)d_in[11];
    const float* crB1 = (const float*)d_in[12];
    const float* crW2 = (const float*)d_in[13];
    const float* crB2 = (const float*)d_in[14];
    const float* tmW0 = (const float*)d_in[15];
    const float* tmB0 = (const float*)d_in[16];
    const float* tmW1 = (const float*)d_in[17];
    const float* tmB1 = (const float*)d_in[18];
    const float* tmW2 = (const float*)d_in[19];
    const float* tmB2 = (const float*)d_in[20];
    float* out = (float*)d_out;

    float* w     = (float*)d_ws;
    float* rews0 = w;                     // 480
    float* cont1 = rews0 + 480;           // 7200
    float* rews1 = cont1 + 7200;          // 7200
    float* cont2 = rews1 + 7200;          // 108000
    float* Vns3  = cont2 + 108000;        // 108000
    float* U1cr  = Vns3 + 108000;         // 32*256
    float* U1tm  = U1cr + 32 * 256;       // 32*256
    short* planes = (short*)(U1tm + 32 * 256);  // 18 * PL shorts = 2.25 MB
    float* U2cr  = (float*)(planes + 18 * PL);  // 480*256
    float* U2tm  = U2cr + 480 * 256;            // 480*256
    float* Ucr   = U2tm + 480 * 256;            // 7200*256
    float* Utm   = Ucr + 7200 * 256;            // 7200*256
    float* w5    = Utm + 7200 * 256;            // 256
    float* b5    = w5 + 256;                    // 1 (pad to 4)
    float* c2cr  = b5 + 4;                      // 256
    float* c2tm  = c2cr + 256;                  // 256
    float* b45   = c2tm + 256;                  // 256

    front_kernel<<<66, 256, 0, stream>>>(x,
        emW0, emB0, emW1, emB1, emW2, emB2, vW, vb,
        crW0, crW1, tmW0, tmW1, tmW2, tmB2,
        planes, w5, b5, c2cr, c2tm, b45,
        out + NB * NA, U1cr, U1tm);
    stage1m_kernel<<<30, 256, 0, stream>>>(U1cr, U1tm, planes,
        crW0, crB0, crB1, crW2, crB2, tmW0, tmB0, tmB1,
        c2cr, c2tm, rews0, U2cr, U2tm);
    stage2m_kernel<<<450, 256, 0, stream>>>(U2cr, U2tm, planes,
        crW0, crB0, crB1, crW2, crB2, tmW0, tmB0, tmB1,
        c2cr, c2tm, cont1, rews1, Ucr, Utm);
    k3ab_kernel<<<3094, 256, 0, stream>>>(Ucr, Utm, planes,
        crW0, crB0, crB1, crW2, crB2,
        tmW0, tmB0, tmB1, b45, emB1, w5, b5, cont2, Vns3);
    finalize_kernel<<<NB, 256, 0, stream>>>(Vns3, cont2, rews0, rews1, cont1, out);
}

// Round 21
// 221.203 us; speedup vs baseline: 1.5751x; 1.1042x over previous
//
#include <hip/hip_runtime.h>

#define NA 15
#define NB 32
#define DD 256
#define PL 65536  // shorts per weight plane (8 slices x 256 cols x 32 k)
#define ASTR 264  // act LDS row stride (shorts)

using bf16x8 = __attribute__((ext_vector_type(8))) short;
using f32x4  = __attribute__((ext_vector_type(4))) float;

__device__ __forceinline__ unsigned short f2bf(float f){
  unsigned int u = __float_as_uint(f);
  u = u + 0x7fffu + ((u >> 16) & 1u);
  return (unsigned short)(u >> 16);
}
__device__ __forceinline__ float bf2f(unsigned short h){
  return __uint_as_float(((unsigned int)h) << 16);
}
__device__ __forceinline__ unsigned int cvtpk_bf16(float lo, float hi){
    unsigned int r;
    asm("v_cvt_pk_bf16_f32 %0, %1, %2" : "=v"(r) : "v"(lo), "v"(hi));
    return r;
}
__device__ __forceinline__ void split1_write(const float v[4], short* pH){
    unsigned int h01 = cvtpk_bf16(v[0], v[1]);
    unsigned int h23 = cvtpk_bf16(v[2], v[3]);
    *(uint2*)pH = make_uint2(h01, h23);
}
__device__ __forceinline__ void split2_write(const float v[4], short* pH, short* pL){
    unsigned int h01 = cvtpk_bf16(v[0], v[1]);
    unsigned int h23 = cvtpk_bf16(v[2], v[3]);
    float r0 = v[0] - __uint_as_float(h01 << 16);
    float r1 = v[1] - __uint_as_float(h01 & 0xffff0000u);
    float r2 = v[2] - __uint_as_float(h23 << 16);
    float r3 = v[3] - __uint_as_float(h23 & 0xffff0000u);
    unsigned int l01 = cvtpk_bf16(r0, r1);
    unsigned int l23 = cvtpk_bf16(r2, r3);
    *(uint2*)pH = make_uint2(h01, h23);
    *(uint2*)pL = make_uint2(l01, l23);
}
__device__ __forceinline__ void split3_write(const float v[4], short* pH, short* pM, short* pL){
    unsigned int h01 = cvtpk_bf16(v[0], v[1]);
    unsigned int h23 = cvtpk_bf16(v[2], v[3]);
    float r0 = v[0] - __uint_as_float(h01 << 16);
    float r1 = v[1] - __uint_as_float(h01 & 0xffff0000u);
    float r2 = v[2] - __uint_as_float(h23 << 16);
    float r3 = v[3] - __uint_as_float(h23 & 0xffff0000u);
    unsigned int m01 = cvtpk_bf16(r0, r1);
    unsigned int m23 = cvtpk_bf16(r2, r3);
    float s0 = r0 - __uint_as_float(m01 << 16);
    float s1 = r1 - __uint_as_float(m01 & 0xffff0000u);
    float s2 = r2 - __uint_as_float(m23 << 16);
    float s3 = r3 - __uint_as_float(m23 & 0xffff0000u);
    unsigned int l01 = cvtpk_bf16(s0, s1);
    unsigned int l23 = cvtpk_bf16(s2, s3);
    *(uint2*)pH = make_uint2(h01, h23);
    *(uint2*)pM = make_uint2(m01, m23);
    *(uint2*)pL = make_uint2(l01, l23);
}

// ---------------------------------------------------------------------------
// fp32 VALU primitives (value_x branch of front kernel)
// ---------------------------------------------------------------------------
template<int TM, bool RELU>
__device__ __forceinline__ void layer256(
    const float* __restrict__ W, const float* __restrict__ bias,
    const float* act, int K, int lda, float* out, int ldo)
{
    constexpr int RPG = TM / 4;
    const int tid = threadIdx.x;
    const int tr = tid >> 6;
    const int tc = tid & 63;
    float acc[RPG][4];
#pragma unroll
    for (int i = 0; i < RPG; ++i) { acc[i][0]=0.f; acc[i][1]=0.f; acc[i][2]=0.f; acc[i][3]=0.f; }
    const float* wp = W + 4 * tc;
    int k = 0;
    for (; k + 4 <= K; k += 4) {
        float4 w0 = *reinterpret_cast<const float4*>(wp + (k + 0) * DD);
        float4 w1 = *reinterpret_cast<const float4*>(wp + (k + 1) * DD);
        float4 w2 = *reinterpret_cast<const float4*>(wp + (k + 2) * DD);
        float4 w3 = *reinterpret_cast<const float4*>(wp + (k + 3) * DD);
#pragma unroll
        for (int i = 0; i < RPG; ++i) {
            float4 a = *reinterpret_cast<const float4*>(act + (RPG * tr + i) * lda + k);
            acc[i][0] += a.x * w0.x + a.y * w1.x + a.z * w2.x + a.w * w3.x;
            acc[i][1] += a.x * w0.y + a.y * w1.y + a.z * w2.y + a.w * w3.y;
            acc[i][2] += a.x * w0.z + a.y * w1.z + a.z * w2.z + a.w * w3.z;
            acc[i][3] += a.x * w0.w + a.y * w1.w + a.z * w2.w + a.w * w3.w;
        }
    }
    for (; k < K; ++k) {
        float4 w0 = *reinterpret_cast<const float4*>(wp + k * DD);
#pragma unroll
        for (int i = 0; i < RPG; ++i) {
            float a = act[(RPG * tr + i) * lda + k];
            acc[i][0] += a * w0.x; acc[i][1] += a * w0.y;
            acc[i][2] += a * w0.z; acc[i][3] += a * w0.w;
        }
    }
    float4 bb = *reinterpret_cast<const float4*>(bias + 4 * tc);
#pragma unroll
    for (int i = 0; i < RPG; ++i) {
        float4 o;
        o.x = acc[i][0] + bb.x; o.y = acc[i][1] + bb.y;
        o.z = acc[i][2] + bb.z; o.w = acc[i][3] + bb.w;
        if (RELU) {
            o.x = fmaxf(o.x, 0.f); o.y = fmaxf(o.y, 0.f);
            o.z = fmaxf(o.z, 0.f); o.w = fmaxf(o.w, 0.f);
        }
        *reinterpret_cast<float4*>(out + (RPG * tr + i) * ldo + 4 * tc) = o;
    }
}

template<int TM>
__device__ __forceinline__ void head1c(
    const float* h, int ldh, const float* __restrict__ W, int wstr, int col, float bias,
    float* __restrict__ gout, int gbase)
{
    const int wv = threadIdx.x >> 6;
    const int lane = threadIdx.x & 63;
    for (int rr = wv; rr < TM; rr += 4) {
        float p = 0.f;
#pragma unroll
        for (int t = 0; t < 4; ++t) {
            int k = lane + 64 * t;
            p += h[rr * ldh + k] * W[k * wstr + col];
        }
#pragma unroll
        for (int m = 1; m < 64; m <<= 1) p += __shfl_xor(p, m);
        if (lane == 0) gout[gbase + rr] = p + bias;
    }
}

// ---------------------------------------------------------------------------
// front_kernel (unchanged)
// ---------------------------------------------------------------------------
__global__ __launch_bounds__(256) void front_kernel(
    const float* __restrict__ x,
    const float* __restrict__ emW0, const float* __restrict__ emB0,
    const float* __restrict__ emW1, const float* __restrict__ emB1,
    const float* __restrict__ emW2, const float* __restrict__ emB2,
    const float* __restrict__ vW, const float* __restrict__ vb,
    const float* __restrict__ crW0, const float* __restrict__ crW1,
    const float* __restrict__ tmW0, const float* __restrict__ tmW1,
    const float* __restrict__ tmW2, const float* __restrict__ tmB2,
    short* __restrict__ planes, float* __restrict__ w5, float* __restrict__ b5,
    float* __restrict__ c2cr, float* __restrict__ c2tm, float* __restrict__ b45,
    float* __restrict__ vout, float* __restrict__ U1cr, float* __restrict__ U1tm)
{
    __shared__ __align__(16) float smem[32 * DD];
    const int blk = blockIdx.x;
    const int tid = threadIdx.x;

    if (blk < 24) {
        const int mat = blk >> 3;
        const int kk  = blk & 7;
        const float* W = (mat == 0) ? crW1 : (mat == 1) ? tmW1 : emW1;
        const int col = tid;
        short bh[32], bm[32], bl[32];
#pragma unroll
        for (int j = 0; j < 32; ++j) {
            float w = W[(kk * 32 + j) * 256 + col];
            unsigned short h = f2bf(w); float fh = bf2f(h);
            float r1 = w - fh;
            unsigned short m = f2bf(r1); float fm = bf2f(m);
            bh[j] = (short)h; bm[j] = (short)m; bl[j] = (short)f2bf(r1 - fm);
        }
        short* pH = planes + (size_t)(mat * 3 + 0) * PL + kk * 8192 + col * 32;
        short* pM = planes + (size_t)(mat * 3 + 1) * PL + kk * 8192 + col * 32;
        short* pLp = planes + (size_t)(mat * 3 + 2) * PL + kk * 8192 + col * 32;
#pragma unroll
        for (int j = 0; j < 32; j += 4) {
            *(short4*)(pH + j) = make_short4(bh[j], bh[j+1], bh[j+2], bh[j+3]);
            *(short4*)(pM + j) = make_short4(bm[j], bm[j+1], bm[j+2], bm[j+3]);
            *(short4*)(pLp + j) = make_short4(bl[j], bl[j+1], bl[j+2], bl[j+3]);
        }
    } else if (blk == 24) {
        float acc = 0.f;
        for (int j = 0; j < 256; j += 4) {
            float4 wrow = *(const float4*)(emW2 + tid * 256 + j);
            float4 vv   = *(const float4*)(vW + j);
            acc += wrow.x * vv.x + wrow.y * vv.y + wrow.z * vv.z + wrow.w * vv.w;
        }
        w5[tid] = acc;
        if (tid == 0) {
            float b = 0.f;
            for (int j = 0; j < 256; ++j) b += emB2[j] * vW[j];
            b5[0] = b + vb[0];
        }
    } else if (blk < 33) {
        constexpr int TM = 4;
        float* bufA = smem;
        float* bufB = bufA + TM * DD;
        float* bufC = bufB + TM * DD;
        const int row0 = (blk - 25) * TM;
        for (int i = 0; i < TM; ++i) bufA[i * DD + tid] = x[(row0 + i) * DD + tid];
        __syncthreads();
        layer256<TM, true >(emW0, emB0, bufA, 256, DD, bufB, DD); __syncthreads();
        layer256<TM, true >(emW1, emB1, bufB, 256, DD, bufC, DD); __syncthreads();
        layer256<TM, false>(emW2, emB2, bufC, 256, DD, bufB, DD); __syncthreads();
        head1c<TM>(bufB, DD, vW, 1, 0, vb[0], vout, row0);
    } else if (blk < 41) {
        const int row0 = (blk - 33) * 4;
        float* xs = smem;   // [4][256]
        for (int i = 0; i < 4; ++i) xs[i * 256 + tid] = x[(row0 + i) * 256 + tid];
        __syncthreads();
        float acr[4] = {0.f,0.f,0.f,0.f}, atm[4] = {0.f,0.f,0.f,0.f};
        for (int k = 0; k < 256; ++k) {
            float wc = crW0[k * 256 + tid];
            float wt = tmW0[k * 256 + tid];
#pragma unroll
            for (int i = 0; i < 4; ++i) {
                acr[i] += xs[i * 256 + k] * wc;
                atm[i] += xs[i * 256 + k] * wt;
            }
        }
        for (int i = 0; i < 4; ++i) {
            U1cr[(row0 + i) * 256 + tid] = acr[i];
            U1tm[(row0 + i) * 256 + tid] = atm[i];
        }
    } else if (blk < 65) {
        const int pb = blk - 41;
        const int prod = pb >> 3;           // 0=W45, 1=W2cr, 2=W2tm
        const int r0 = (pb & 7) * 32;
        const float* B = (prod == 0) ? emW0 : (prod == 1) ? crW0 : tmW0;
        const int pbase = 9 + prod * 3;
        float* As = smem;   // [32][256]
        for (int i = tid; i < 32 * 256; i += 256)
            As[i] = tmW2[(r0 + (i >> 8)) * 256 + (i & 255)];
        __syncthreads();
        float acc[32];
#pragma unroll
        for (int j = 0; j < 32; ++j) acc[j] = 0.f;
        for (int m = 0; m < 256; ++m) {
            float b = B[m * 256 + tid];
#pragma unroll
            for (int j = 0; j < 32; ++j) acc[j] += As[j * 256 + m] * b;
        }
        short bh[32], bm[32], bl[32];
#pragma unroll
        for (int j = 0; j < 32; ++j) {
            float w = acc[j];
            unsigned short h = f2bf(w); float fh = bf2f(h);
            float r1 = w - fh;
            unsigned short mm = f2bf(r1); float fm = bf2f(mm);
            bh[j] = (short)h; bm[j] = (short)mm; bl[j] = (short)f2bf(r1 - fm);
        }
        const int kk = r0 >> 5;
        short* pH = planes + (size_t)(pbase + 0) * PL + kk * 8192 + tid * 32;
        short* pM = planes + (size_t)(pbase + 1) * PL + kk * 8192 + tid * 32;
        short* pLp = planes + (size_t)(pbase + 2) * PL + kk * 8192 + tid * 32;
#pragma unroll
        for (int j = 0; j < 32; j += 4) {
            *(short4*)(pH + j) = make_short4(bh[j], bh[j+1], bh[j+2], bh[j+3]);
            *(short4*)(pM + j) = make_short4(bm[j], bm[j+1], bm[j+2], bm[j+3]);
            *(short4*)(pLp + j) = make_short4(bl[j], bl[j+1], bl[j+2], bl[j+3]);
        }
    } else {
        const int j = tid;
        float a0 = 0.f, a1 = 0.f, a2 = 0.f;
        for (int k = 0; k < 256; ++k) {
            float t = tmB2[k];
            a0 += t * crW0[k * 256 + j];
            a1 += t * tmW0[k * 256 + j];
            a2 += t * emW0[k * 256 + j];
        }
        c2cr[j] = a0;
        c2tm[j] = a1;
        b45[j] = a2 + emB0[j];
    }
}

__global__ __launch_bounds__(256) void finalize_kernel(
    const float* __restrict__ Vns3, const float* __restrict__ cont2,
    const float* __restrict__ rews0, const float* __restrict__ rews1,
    const float* __restrict__ cont1, float* __restrict__ out)
{
    const int b = blockIdx.x;
    const int tid = threadIdx.x;
    __shared__ float vs2[NA][NA];
    __shared__ float vs3[NA];
    if (tid < NA * NA) {
        const int x = tid / NA, y = tid % NA;
        float vals[NA];
        float m = -INFINITY;
#pragma unroll
        for (int z = 0; z < NA; ++z) {
            int vidx = ((b * NA + y) * NA + z) * NA + x;
            int cidx = ((b * NA + x) * NA + y) * NA + z;
            float c1 = rews0[b * NA + z] * 0.99f;
            float c2 = (c1 + rews1[(b * NA + x) * NA + z]) * 0.99f;
            float v = Vns3[vidx] * 0.970299f + c2;
            if (cont2[cidx] > 0.f) v = 0.f;
            vals[z] = v;
            m = fmaxf(m, v);
        }
        float se = 0.f, sw = 0.f;
#pragma unroll
        for (int z = 0; z < NA; ++z) { float e = expf(vals[z] - m); se += e; sw += e * vals[z]; }
        vs2[x][y] = sw / se;
    }
    __syncthreads();
    if (tid < NA) {
        const int x = tid;
        float vals[NA];
        float m = -INFINITY;
#pragma unroll
        for (int y = 0; y < NA; ++y) {
            float v = vs2[x][y];
            if (cont1[(b * NA + x) * NA + y] > 0.f) v = 0.f;
            vals[y] = v;
            m = fmaxf(m, v);
        }
        float se = 0.f, sw = 0.f;
#pragma unroll
        for (int y = 0; y < NA; ++y) { float e = expf(vals[y] - m); se += e; sw += e * vals[y]; }
        vs3[x] = sw / se;
    }
    __syncthreads();
    if (tid == 0) {
        float m = -INFINITY;
#pragma unroll
        for (int x = 0; x < NA; ++x) m = fmaxf(m, vs3[x]);
        float se = 0.f;
#pragma unroll
        for (int x = 0; x < NA; ++x) se += expf(vs3[x] - m);
        float l = logf(se);
#pragma unroll
        for (int x = 0; x < NA; ++x) out[b * NA + x] = vs3[x] - m - l;
    }
}

// ---------------------------------------------------------------------------
// mm3: RT row-tiles x 4 col-tiles over K=256 with NP passes (3-way act planes).
// ---------------------------------------------------------------------------
template<int RT, int NP>
__device__ __forceinline__ void mm3(
    const short* __restrict__ plH, const short* __restrict__ plM, const short* __restrict__ plL,
    const short* actH, const short* actM, const short* actL,
    f32x4 (&acc)[4][RT])
{
    const int tid = threadIdx.x;
    const int ln15 = tid & 15, lng = (tid >> 4) & 3, wv = tid >> 6;
    const int wo = (wv * 64 + ln15) * 32 + lng * 8;
#pragma unroll
    for (int kk = 0; kk < 8; ++kk) {
        bf16x8 wH[4], wM[4], wL[4], xH[RT], xM[RT], xL[RT];
#pragma unroll
        for (int ct = 0; ct < 4; ++ct) {
            wH[ct] = *(const bf16x8*)(plH + wo + kk * 8192 + ct * 512);
            wM[ct] = *(const bf16x8*)(plM + wo + kk * 8192 + ct * 512);
            if (NP == 6) wL[ct] = *(const bf16x8*)(plL + wo + kk * 8192 + ct * 512);
        }
#pragma unroll
        for (int rt = 0; rt < RT; ++rt) {
            int off = (rt * 16 + ln15) * ASTR + kk * 32 + lng * 8;
            xH[rt] = *(const bf16x8*)(actH + off);
            xM[rt] = *(const bf16x8*)(actM + off);
            if (NP == 6) xL[rt] = *(const bf16x8*)(actL + off);
        }
        __builtin_amdgcn_s_setprio(1);
#pragma unroll
        for (int ct = 0; ct < 4; ++ct)
#pragma unroll
            for (int rt = 0; rt < RT; ++rt) {
                acc[ct][rt] = __builtin_amdgcn_mfma_f32_16x16x32_bf16(wH[ct], xH[rt], acc[ct][rt], 0, 0, 0);
                acc[ct][rt] = __builtin_amdgcn_mfma_f32_16x16x32_bf16(wH[ct], xM[rt], acc[ct][rt], 0, 0, 0);
                acc[ct][rt] = __builtin_amdgcn_mfma_f32_16x16x32_bf16(wM[ct], xH[rt], acc[ct][rt], 0, 0, 0);
                if (NP == 6) {
                    acc[ct][rt] = __builtin_amdgcn_mfma_f32_16x16x32_bf16(wM[ct], xM[rt], acc[ct][rt], 0, 0, 0);
                    acc[ct][rt] = __builtin_amdgcn_mfma_f32_16x16x32_bf16(wH[ct], xL[rt], acc[ct][rt], 0, 0, 0);
                    acc[ct][rt] = __builtin_amdgcn_mfma_f32_16x16x32_bf16(wL[ct], xH[rt], acc[ct][rt], 0, 0, 0);
                }
            }
        __builtin_amdgcn_s_setprio(0);
    }
}

// ---------------------------------------------------------------------------
// mm24: exact (wH+wM) x (xH+xL) product — 4 passes, 2-way weights x 2-way act.
// Error ~2^-18 relative: sufficient for mask logits (min |logit| >> 1e-5).
// ---------------------------------------------------------------------------
template<int RT>
__device__ __forceinline__ void mm24(
    const short* __restrict__ plH, const short* __restrict__ plM,
    const short* actH, const short* actL,
    f32x4 (&acc)[4][RT])
{
    const int tid = threadIdx.x;
    const int ln15 = tid & 15, lng = (tid >> 4) & 3, wv = tid >> 6;
    const int wo = (wv * 64 + ln15) * 32 + lng * 8;
#pragma unroll
    for (int kk = 0; kk < 8; ++kk) {
        bf16x8 wH[4], wM[4], xH[RT], xL[RT];
#pragma unroll
        for (int ct = 0; ct < 4; ++ct) {
            wH[ct] = *(const bf16x8*)(plH + wo + kk * 8192 + ct * 512);
            wM[ct] = *(const bf16x8*)(plM + wo + kk * 8192 + ct * 512);
        }
#pragma unroll
        for (int rt = 0; rt < RT; ++rt) {
            int off = (rt * 16 + ln15) * ASTR + kk * 32 + lng * 8;
            xH[rt] = *(const bf16x8*)(actH + off);
            xL[rt] = *(const bf16x8*)(actL + off);
        }
        __builtin_amdgcn_s_setprio(1);
#pragma unroll
        for (int ct = 0; ct < 4; ++ct)
#pragma unroll
            for (int rt = 0; rt < RT; ++rt) {
                acc[ct][rt] = __builtin_amdgcn_mfma_f32_16x16x32_bf16(wH[ct], xH[rt], acc[ct][rt], 0, 0, 0);
                acc[ct][rt] = __builtin_amdgcn_mfma_f32_16x16x32_bf16(wH[ct], xL[rt], acc[ct][rt], 0, 0, 0);
                acc[ct][rt] = __builtin_amdgcn_mfma_f32_16x16x32_bf16(wM[ct], xH[rt], acc[ct][rt], 0, 0, 0);
                acc[ct][rt] = __builtin_amdgcn_mfma_f32_16x16x32_bf16(wM[ct], xL[rt], acc[ct][rt], 0, 0, 0);
            }
        __builtin_amdgcn_s_setprio(0);
    }
}

// stage a 3-way-split activation row block from U + a*wrow + bias (relu)
template<int ROWS, bool CLAMP>
__device__ __forceinline__ void stage3w(
    const float* __restrict__ U, const float* __restrict__ wrow256,
    const float* __restrict__ bias, int row0,
    short* actH, short* actM, short* actL)
{
    const int tid = threadIdx.x;
    const int wv = tid >> 6, ln = tid & 63;
    constexpr int RPW = ROWS / 4;
    const float4 wr = *(const float4*)(wrow256 + ln * 4);
    const float4 bb = *(const float4*)(bias + ln * 4);
    for (int i = wv * RPW; i < wv * RPW + RPW; ++i) {
        int r = row0 + i;
        int srow = r / 15;
        if (CLAMP && srow > 7199) srow = 7199;
        float a = (float)(r % 15);
        float4 u = *(const float4*)(U + srow * 256 + ln * 4);
        float sv[4];
        sv[0] = fmaxf(u.x + a * wr.x + bb.x, 0.f);
        sv[1] = fmaxf(u.y + a * wr.y + bb.y, 0.f);
        sv[2] = fmaxf(u.z + a * wr.z + bb.z, 0.f);
        sv[3] = fmaxf(u.w + a * wr.w + bb.w, 0.f);
        split3_write(sv, actH + i * ASTR + ln * 4, actM + i * ASTR + ln * 4, actL + i * ASTR + ln * 4);
    }
}

// stage a 2-way-split activation row block (H + L covering ~2^-18)
template<int ROWS, bool CLAMP>
__device__ __forceinline__ void stage2wact(
    const float* __restrict__ U, const float* __restrict__ wrow256,
    const float* __restrict__ bias, int row0,
    short* actH, short* actL)
{
    const int tid = threadIdx.x;
    const int wv = tid >> 6, ln = tid & 63;
    constexpr int RPW = ROWS / 4;
    const float4 wr = *(const float4*)(wrow256 + ln * 4);
    const float4 bb = *(const float4*)(bias + ln * 4);
    for (int i = wv * RPW; i < wv * RPW + RPW; ++i) {
        int r = row0 + i;
        int srow = r / 15;
        if (CLAMP && srow > 7199) srow = 7199;
        float a = (float)(r % 15);
        float4 u = *(const float4*)(U + srow * 256 + ln * 4);
        float sv[4];
        sv[0] = fmaxf(u.x + a * wr.x + bb.x, 0.f);
        sv[1] = fmaxf(u.y + a * wr.y + bb.y, 0.f);
        sv[2] = fmaxf(u.z + a * wr.z + bb.z, 0.f);
        sv[3] = fmaxf(u.w + a * wr.w + bb.w, 0.f);
        split2_write(sv, actH + i * ASTR + ln * 4, actL + i * ASTR + ln * 4);
    }
}

// ---------------------------------------------------------------------------
// stage1m: 480 rows (b,a1), 30 blocks x 16 rows. rews0 + U2cr/U2tm.
// Phase A (rews0, continuous) uses 4-pass; phase B stays 6-pass (mask chain).
// ---------------------------------------------------------------------------
__global__ __launch_bounds__(256, 2) void stage1m_kernel(
    const float* __restrict__ U1cr, const float* __restrict__ U1tm,
    const short* __restrict__ planes,
    const float* __restrict__ crW0, const float* __restrict__ crB0,
    const float* __restrict__ crB1, const float* __restrict__ crW2, const float* __restrict__ crB2,
    const float* __restrict__ tmW0, const float* __restrict__ tmB0,
    const float* __restrict__ tmB1,
    const float* __restrict__ c2cr, const float* __restrict__ c2tm,
    float* __restrict__ rews0, float* __restrict__ U2cr, float* __restrict__ U2tm)
{
    __shared__ short actH[16 * ASTR];
    __shared__ short actM[16 * ASTR];
    __shared__ short actL[16 * ASTR];
    __shared__ float hred[64];
    const int tid = threadIdx.x;
    const int row0 = blockIdx.x * 16;
    const int ln15 = tid & 15, lng = (tid >> 4) & 3, wv = tid >> 6;

    stage2wact<16, false>(U1cr, crW0 + 65536, crB0, row0, actH, actL);
    __syncthreads();
    {
        f32x4 acc[4][1];
#pragma unroll
        for (int a = 0; a < 4; ++a) acc[a][0] = f32x4{0.f,0.f,0.f,0.f};
        mm24<1>(planes + 0*PL, planes + 1*PL, actH, actL, acc);
        float hp = 0.f;
#pragma unroll
        for (int ct = 0; ct < 4; ++ct) {
            const int colb = wv * 64 + ct * 16 + lng * 4;
            const float4 b1 = *(const float4*)(crB1 + colb);
            f32x4 v = acc[ct][0];
            v[0] += b1.x; v[1] += b1.y; v[2] += b1.z; v[3] += b1.w;
#pragma unroll
            for (int j = 0; j < 4; ++j) v[j] = fmaxf(v[j], 0.f);
#pragma unroll
            for (int j = 0; j < 4; ++j) hp += v[j] * crW2[(colb + j) * 2 + 1];
        }
        hp += __shfl_xor(hp, 16);
        hp += __shfl_xor(hp, 32);
        if (lng == 0) hred[wv * 16 + ln15] = hp;
        __syncthreads();
        if (tid < 16) rews0[row0 + tid] = hred[tid] + hred[16 + tid] + hred[32 + tid] + hred[48 + tid] + crB2[1];
        __syncthreads();
    }

    stage3w<16, false>(U1tm, tmW0 + 65536, tmB0, row0, actH, actM, actL);
    __syncthreads();
    {
        f32x4 acc[4][1];
#pragma unroll
        for (int a = 0; a < 4; ++a) acc[a][0] = f32x4{0.f,0.f,0.f,0.f};
        mm3<1, 6>(planes + 3*PL, planes + 4*PL, planes + 5*PL, actH, actM, actL, acc);
        __syncthreads();
#pragma unroll
        for (int ct = 0; ct < 4; ++ct) {
            const int colb = wv * 64 + ct * 16 + lng * 4;
            const float4 bb = *(const float4*)(tmB1 + colb);
            f32x4 v = acc[ct][0];
            v[0] += bb.x; v[1] += bb.y; v[2] += bb.z; v[3] += bb.w;
#pragma unroll
            for (int j = 0; j < 4; ++j) v[j] = fmaxf(v[j], 0.f);
            float sv[4] = {v[0], v[1], v[2], v[3]};
            const int ao = ln15 * ASTR + colb;
            split3_write(sv, actH + ao, actM + ao, actL + ao);
        }
        __syncthreads();
    }
    {
        f32x4 acc[4][1];
#pragma unroll
        for (int a = 0; a < 4; ++a) acc[a][0] = f32x4{0.f,0.f,0.f,0.f};
        mm3<1, 6>(planes + 12*PL, planes + 13*PL, planes + 14*PL, actH, actM, actL, acc);
#pragma unroll
        for (int ct = 0; ct < 4; ++ct) {
            const int colb = wv * 64 + ct * 16 + lng * 4;
            const float4 cc = *(const float4*)(c2cr + colb);
            float4 o; o.x = acc[ct][0][0] + cc.x; o.y = acc[ct][0][1] + cc.y;
            o.z = acc[ct][0][2] + cc.z; o.w = acc[ct][0][3] + cc.w;
            *(float4*)(U2cr + (row0 + ln15) * 256 + colb) = o;
        }
    }
    {
        f32x4 acc[4][1];
#pragma unroll
        for (int a = 0; a < 4; ++a) acc[a][0] = f32x4{0.f,0.f,0.f,0.f};
        mm3<1, 6>(planes + 15*PL, planes + 16*PL, planes + 17*PL, actH, actM, actL, acc);
#pragma unroll
        for (int ct = 0; ct < 4; ++ct) {
            const int colb = wv * 64 + ct * 16 + lng * 4;
            const float4 cc = *(const float4*)(c2tm + colb);
            float4 o; o.x = acc[ct][0][0] + cc.x; o.y = acc[ct][0][1] + cc.y;
            o.z = acc[ct][0][2] + cc.z; o.w = acc[ct][0][3] + cc.w;
            *(float4*)(U2tm + (row0 + ln15) * 256 + colb) = o;
        }
    }
}

// ---------------------------------------------------------------------------
// stage2m: 7200 rows, 450 blocks x 16 rows. Phase A (cont1/rews1) 4-pass;
// phase B (feeds Ucr mask chain) stays 6-pass.
// ---------------------------------------------------------------------------
__global__ __launch_bounds__(256, 2) void stage2m_kernel(
    const float* __restrict__ U2cr, const float* __restrict__ U2tm,
    const short* __restrict__ planes,
    const float* __restrict__ crW0, const float* __restrict__ crB0,
    const float* __restrict__ crB1, const float* __restrict__ crW2, const float* __restrict__ crB2,
    const float* __restrict__ tmW0, const float* __restrict__ tmB0,
    const float* __restrict__ tmB1,
    const float* __restrict__ c2cr, const float* __restrict__ c2tm,
    float* __restrict__ cont1, float* __restrict__ rews1,
    float* __restrict__ Ucr, float* __restrict__ Utm)
{
    __shared__ short actH[16 * ASTR];
    __shared__ short actM[16 * ASTR];
    __shared__ short actL[16 * ASTR];
    __shared__ float hred[2][64];
    const int tid = threadIdx.x;
    const int row0 = blockIdx.x * 16;
    const int ln15 = tid & 15, lng = (tid >> 4) & 3, wv = tid >> 6;

    stage2wact<16, false>(U2cr, crW0 + 65536, crB0, row0, actH, actL);
    __syncthreads();
    {
        f32x4 acc[4][1];
#pragma unroll
        for (int a = 0; a < 4; ++a) acc[a][0] = f32x4{0.f,0.f,0.f,0.f};
        mm24<1>(planes + 0*PL, planes + 1*PL, actH, actL, acc);
        float hp0 = 0.f, hp1 = 0.f;
#pragma unroll
        for (int ct = 0; ct < 4; ++ct) {
            const int colb = wv * 64 + ct * 16 + lng * 4;
            const float4 b1 = *(const float4*)(crB1 + colb);
            f32x4 v = acc[ct][0];
            v[0] += b1.x; v[1] += b1.y; v[2] += b1.z; v[3] += b1.w;
#pragma unroll
            for (int j = 0; j < 4; ++j) v[j] = fmaxf(v[j], 0.f);
#pragma unroll
            for (int j = 0; j < 4; ++j) {
                hp0 += v[j] * crW2[(colb + j) * 2 + 0];
                hp1 += v[j] * crW2[(colb + j) * 2 + 1];
            }
        }
        hp0 += __shfl_xor(hp0, 16); hp0 += __shfl_xor(hp0, 32);
        hp1 += __shfl_xor(hp1, 16); hp1 += __shfl_xor(hp1, 32);
        if (lng == 0) {
            hred[0][wv * 16 + ln15] = hp0;
            hred[1][wv * 16 + ln15] = hp1;
        }
        __syncthreads();
        if (tid < 16)
            cont1[row0 + tid] = hred[0][tid] + hred[0][16 + tid] + hred[0][32 + tid] + hred[0][48 + tid] + crB2[0];
        else if (tid >= 64 && tid < 80)
            rews1[row0 + tid - 64] = hred[1][tid - 64] + hred[1][16 + tid - 64] + hred[1][32 + tid - 64] + hred[1][48 + tid - 64] + crB2[1];
        __syncthreads();
    }

    stage3w<16, false>(U2tm, tmW0 + 65536, tmB0, row0, actH, actM, actL);
    __syncthreads();
    {
        f32x4 acc[4][1];
#pragma unroll
        for (int a = 0; a < 4; ++a) acc[a][0] = f32x4{0.f,0.f,0.f,0.f};
        mm3<1, 6>(planes + 3*PL, planes + 4*PL, planes + 5*PL, actH, actM, actL, acc);
        __syncthreads();
#pragma unroll
        for (int ct = 0; ct < 4; ++ct) {
            const int colb = wv * 64 + ct * 16 + lng * 4;
            const float4 bb = *(const float4*)(tmB1 + colb);
            f32x4 v = acc[ct][0];
            v[0] += bb.x; v[1] += bb.y; v[2] += bb.z; v[3] += bb.w;
#pragma unroll
            for (int j = 0; j < 4; ++j) v[j] = fmaxf(v[j], 0.f);
            float sv[4] = {v[0], v[1], v[2], v[3]};
            const int ao = ln15 * ASTR + colb;
            split3_write(sv, actH + ao, actM + ao, actL + ao);
        }
        __syncthreads();
    }
    int pr;
    {
        int r = row0 + ln15;
        int b = r / 225, a1 = (r / 15) % 15, a2 = r % 15;
        pr = (b * 15 + a2) * 15 + a1;
    }
    {
        f32x4 acc[4][1];
#pragma unroll
        for (int a = 0; a < 4; ++a) acc[a][0] = f32x4{0.f,0.f,0.f,0.f};
        mm3<1, 6>(planes + 12*PL, planes + 13*PL, planes + 14*PL, actH, actM, actL, acc);
#pragma unroll
        for (int ct = 0; ct < 4; ++ct) {
            const int colb = wv * 64 + ct * 16 + lng * 4;
            const float4 cc = *(const float4*)(c2cr + colb);
            float4 o; o.x = acc[ct][0][0] + cc.x; o.y = acc[ct][0][1] + cc.y;
            o.z = acc[ct][0][2] + cc.z; o.w = acc[ct][0][3] + cc.w;
            *(float4*)(Ucr + pr * 256 + colb) = o;
        }
    }
    {
        f32x4 acc[4][1];
#pragma unroll
        for (int a = 0; a < 4; ++a) acc[a][0] = f32x4{0.f,0.f,0.f,0.f};
        mm3<1, 3>(planes + 15*PL, planes + 16*PL, planes + 17*PL, actH, actM, actL, acc);
#pragma unroll
        for (int ct = 0; ct < 4; ++ct) {
            const int colb = wv * 64 + ct * 16 + lng * 4;
            const float4 cc = *(const float4*)(c2tm + colb);
            float4 o; o.x = acc[ct][0][0] + cc.x; o.y = acc[ct][0][1] + cc.y;
            o.z = acc[ct][0][2] + cc.z; o.w = acc[ct][0][3] + cc.w;
            *(float4*)(Utm + pr * 256 + colb) = o;
        }
    }
}

// ---------------------------------------------------------------------------
// layer_b1: pure-bf16 1-pass 16x16x32 layer over RT*16-row act tile.
// ---------------------------------------------------------------------------
template<int RT, bool RELU, bool HEAD, bool WRITEACT>
__device__ __forceinline__ void layer_b1(
    const short* __restrict__ plH,
    const float* __restrict__ bias,
    const float* __restrict__ headW, const float* __restrict__ headB,
    float* __restrict__ headOut, int row0,
    short* actH, float* hred)
{
    const int tid = threadIdx.x;
    const int ln15 = tid & 15, lng = (tid >> 4) & 3, wv = tid >> 6;
    const int wo = (wv * 64 + ln15) * 32 + lng * 8;
    f32x4 acc[4][RT];
#pragma unroll
    for (int a = 0; a < 4; ++a)
#pragma unroll
        for (int b = 0; b < RT; ++b) acc[a][b] = f32x4{0.f, 0.f, 0.f, 0.f};

#pragma unroll
    for (int kk = 0; kk < 8; ++kk) {
        bf16x8 aH[4], bH[RT];
#pragma unroll
        for (int ct = 0; ct < 4; ++ct)
            aH[ct] = *(const bf16x8*)(plH + wo + kk * 8192 + ct * 512);
#pragma unroll
        for (int rt = 0; rt < RT; ++rt) {
            int off = (rt * 16 + ln15) * ASTR + kk * 32 + lng * 8;
            bH[rt] = *(const bf16x8*)(actH + off);
        }
        __builtin_amdgcn_s_setprio(1);
#pragma unroll
        for (int ct = 0; ct < 4; ++ct)
#pragma unroll
            for (int rt = 0; rt < RT; ++rt)
                acc[ct][rt] = __builtin_amdgcn_mfma_f32_16x16x32_bf16(aH[ct], bH[rt], acc[ct][rt], 0, 0, 0);
        __builtin_amdgcn_s_setprio(0);
    }
    __syncthreads();

    float hp[RT];
#pragma unroll
    for (int rt = 0; rt < RT; ++rt) hp[rt] = 0.f;
#pragma unroll
    for (int ct = 0; ct < 4; ++ct) {
        const int colb = wv * 64 + ct * 16 + lng * 4;
        const float4 bb = *(const float4*)(bias + colb);
#pragma unroll
        for (int rt = 0; rt < RT; ++rt) {
            f32x4 v = acc[ct][rt];
            v[0] += bb.x; v[1] += bb.y; v[2] += bb.z; v[3] += bb.w;
            if (RELU) {
#pragma unroll
                for (int j = 0; j < 4; ++j) v[j] = fmaxf(v[j], 0.f);
            }
            if (HEAD) {
                const float4 hw = *(const float4*)(headW + colb);
                hp[rt] += v[0] * hw.x + v[1] * hw.y + v[2] * hw.z + v[3] * hw.w;
            }
            if (WRITEACT) {
                float sv[4] = {v[0], v[1], v[2], v[3]};
                const int ao = (rt * 16 + ln15) * ASTR + colb;
                split1_write(sv, actH + ao);
            }
        }
    }
    if constexpr (HEAD) {
        constexpr int NR = RT * 16;
#pragma unroll
        for (int rt = 0; rt < RT; ++rt) {
            hp[rt] += __shfl_xor(hp[rt], 16);
            hp[rt] += __shfl_xor(hp[rt], 32);
        }
        if (lng == 0) {
#pragma unroll
            for (int rt = 0; rt < RT; ++rt) hred[wv * NR + rt * 16 + ln15] = hp[rt];
        }
        __syncthreads();
        if (tid < NR && row0 + tid < 108000) {
            float s = hred[tid] + hred[NR + tid] + hred[2 * NR + tid] + hred[3 * NR + tid] + headB[0];
            headOut[row0 + tid] = s;
        }
    }
    if constexpr (WRITEACT) __syncthreads();
}

// ---------------------------------------------------------------------------
// k3ab: fused stage-3, 2 blocks/CU.
// k3b: 750 x 144-row tiles (1-pass bf16, single act plane).
// k3a: 1688 x 64-row tiles (4-pass, 2 act planes; last block guarded).
// Interleave 3:7 in groups of 10 (250 groups = 2500 blocks; k3a idx>=1688 exits).
// LDS: max(144, 2*64)*ASTR*2 = 76032 B + hred 2304 B <= 80K -> 2 blocks/CU.
// ---------------------------------------------------------------------------
__global__ __launch_bounds__(256, 2) void k3ab_kernel(
    const float* __restrict__ Ucr, const float* __restrict__ Utm,
    const short* __restrict__ planes,
    const float* __restrict__ crW0, const float* __restrict__ crB0,
    const float* __restrict__ crB1, const float* __restrict__ crW2,
    const float* __restrict__ crB2,
    const float* __restrict__ tmW0, const float* __restrict__ tmB0,
    const float* __restrict__ tmB1,
    const float* __restrict__ b45, const float* __restrict__ emB1,
    const float* __restrict__ w5, const float* __restrict__ b5,
    float* __restrict__ cont2, float* __restrict__ Vns3)
{
    __shared__ short lds[144 * ASTR];   // 76032 B (>= 2*64*ASTR = 67584)
    __shared__ float hred[576];
    const int tid = threadIdx.x;
    const int g = blockIdx.x / 10, rm = blockIdx.x % 10;
    const bool isB = rm < 3;
    const int idx = isB ? (g * 3 + rm) : (g * 7 + (rm - 3));
    const int ln15 = tid & 15, lng = (tid >> 4) & 3, wv = tid >> 6;
    const short* P = planes;

    if (isB) {
        const int row0 = idx * 144;
        short* actH = lds;
        const int ln = tid & 63;
        const float4 wr = *(const float4*)(tmW0 + 65536 + ln * 4);
        const float4 bb = *(const float4*)(tmB0 + ln * 4);
        for (int i = wv * 36; i < wv * 36 + 36; ++i) {
            int r = row0 + i;
            int srow = r / 15;
            if (srow > 7199) srow = 7199;
            float a = (float)(r % 15);
            float4 u = *(const float4*)(Utm + srow * 256 + ln * 4);
            float sv[4];
            sv[0] = fmaxf(u.x + a * wr.x + bb.x, 0.f);
            sv[1] = fmaxf(u.y + a * wr.y + bb.y, 0.f);
            sv[2] = fmaxf(u.z + a * wr.z + bb.z, 0.f);
            sv[3] = fmaxf(u.w + a * wr.w + bb.w, 0.f);
            split1_write(sv, actH + i * ASTR + ln * 4);
        }
        __syncthreads();
        layer_b1<9, true,  false, true >(P + 3 * PL, tmB1, nullptr, nullptr, nullptr, row0, actH, hred);
        layer_b1<9, true,  false, true >(P + 9 * PL, b45,  nullptr, nullptr, nullptr, row0, actH, hred);
        layer_b1<9, true,  true,  false>(P + 6 * PL, emB1, w5, b5, Vns3, row0, actH, hred);
    } else {
        if (idx >= 1688) return;
        const int row0 = idx * 64;
        short* actH = lds;
        short* actL = lds + 64 * ASTR;
        stage2wact<64, true>(Ucr, crW0 + 65536, crB0, row0, actH, actL);
        __syncthreads();
        f32x4 acc[4][4];
#pragma unroll
        for (int a = 0; a < 4; ++a)
#pragma unroll
            for (int b = 0; b < 4; ++b) acc[a][b] = f32x4{0.f,0.f,0.f,0.f};
        mm24<4>(P + 0*PL, P + 1*PL, actH, actL, acc);
        float hp[4] = {0.f, 0.f, 0.f, 0.f};
#pragma unroll
        for (int ct = 0; ct < 4; ++ct) {
            const int colb = wv * 64 + ct * 16 + lng * 4;
            const float4 b1 = *(const float4*)(crB1 + colb);
#pragma unroll
            for (int rt = 0; rt < 4; ++rt) {
                f32x4 v = acc[ct][rt];
                v[0] += b1.x; v[1] += b1.y; v[2] += b1.z; v[3] += b1.w;
#pragma unroll
                for (int j = 0; j < 4; ++j) v[j] = fmaxf(v[j], 0.f);
#pragma unroll
                for (int j = 0; j < 4; ++j) hp[rt] += v[j] * crW2[(colb + j) * 2];
            }
        }
#pragma unroll
        for (int rt = 0; rt < 4; ++rt) {
            hp[rt] += __shfl_xor(hp[rt], 16);
            hp[rt] += __shfl_xor(hp[rt], 32);
        }
        if (lng == 0) {
#pragma unroll
            for (int rt = 0; rt < 4; ++rt) hred[wv * 64 + rt * 16 + ln15] = hp[rt];
        }
        __syncthreads();
        if (tid < 64 && row0 + tid < 108000)
            cont2[row0 + tid] = hred[tid] + hred[64 + tid] + hred[128 + tid] + hred[192 + tid] + crB2[0];
    }
}

extern "C" void kernel_launch(void* const* d_in, const int* in_sizes, int n_in,
                              void* d_out, int out_size, void* d_ws, size_t ws_size,
                              hipStream_t stream)
{
    (void)in_sizes; (void)n_in; (void)out_size; (void)ws_size;
    const float* x    = (const float*)d_in[0];
    const float* emW0 = (const float*)d_in[1];
    const float* emB0 = (const float*)d_in[2];
    const float* emW1 = (const float*)d_in[3];
    const float* emB1 = (const float*)d_in[4];
    const float* emW2 = (const float*)d_in[5];
    const float* emB2 = (const float*)d_in[6];
    const float* vW   = (const float*)d_in[7];
    const float* vb   = (const float*)d_in[8];
    const float* crW0 = (const float*)d_in[9];
    const float* crB0 = (const float*)d_in[10];
    const float* crW1 = (const float*)d_in[11];
    const float* crB1 = (const float*)d_in[12];
    const float* crW2 = (const float*)d_in[13];
    const float* crB2 = (const float*)d_in[14];
    const float* tmW0 = (const float*)d_in[15];
    const float* tmB0 = (const float*)d_in[16];
    const float* tmW1 = (const float*)d_in[17];
    const float* tmB1 = (const float*)d_in[18];
    const float* tmW2 = (const float*)d_in[19];
    const float* tmB2 = (const float*)d_in[20];
    float* out = (float*)d_out;

    float* w     = (float*)d_ws;
    float* rews0 = w;                     // 480
    float* cont1 = rews0 + 480;           // 7200
    float* rews1 = cont1 + 7200;          // 7200
    float* cont2 = rews1 + 7200;          // 108000
    float* Vns3  = cont2 + 108000;        // 108000
    float* U1cr  = Vns3 + 108000;         // 32*256
    float* U1tm  = U1cr + 32 * 256;       // 32*256
    short* planes = (short*)(U1tm + 32 * 256);  // 18 * PL shorts = 2.25 MB
    float* U2cr  = (float*)(planes + 18 * PL);  // 480*256
    float* U2tm  = U2cr + 480 * 256;            // 480*256
    float* Ucr   = U2tm + 480 * 256;            // 7200*256
    float* Utm   = Ucr + 7200 * 256;            // 7200*256
    float* w5    = Utm + 7200 * 256;            // 256
    float* b5    = w5 + 256;                    // 1 (pad to 4)
    float* c2cr  = b5 + 4;                      // 256
    float* c2tm  = c2cr + 256;                  // 256
    float* b45   = c2tm + 256;                  // 256

    front_kernel<<<66, 256, 0, stream>>>(x,
        emW0, emB0, emW1, emB1, emW2, emB2, vW, vb,
        crW0, crW1, tmW0, tmW1, tmW2, tmB2,
        planes, w5, b5, c2cr, c2tm, b45,
        out + NB * NA, U1cr, U1tm);
    stage1m_kernel<<<30, 256, 0, stream>>>(U1cr, U1tm, planes,
        crW0, crB0, crB1, crW2, crB2, tmW0, tmB0, tmB1,
        c2cr, c2tm, rews0, U2cr, U2tm);
    stage2m_kernel<<<450, 256, 0, stream>>>(U2cr, U2tm, planes,
        crW0, crB0, crB1, crW2, crB2, tmW0, tmB0, tmB1,
        c2cr, c2tm, cont1, rews1, Ucr, Utm);
    k3ab_kernel<<<2500, 256, 0, stream>>>(Ucr, Utm, planes,
        crW0, crB0, crB1, crW2, crB2,
        tmW0, tmB0, tmB1, b45, emB1, w5, b5, cont2, Vns3);
    finalize_kernel<<<NB, 256, 0, stream>>>(Vns3, cont2, rews0, rews1, cont1, out);
}

// Round 22
// 216.342 us; speedup vs baseline: 1.6104x; 1.0225x over previous
//
#include <hip/hip_runtime.h>

#define NA 15
#define NB 32
#define DD 256
#define PL 65536  // shorts per weight plane (8 slices x 256 cols x 32 k)
#define ASTR 264  // act LDS row stride (shorts)

using bf16x8 = __attribute__((ext_vector_type(8))) short;
using f32x4  = __attribute__((ext_vector_type(4))) float;

__device__ __forceinline__ unsigned short f2bf(float f){
  unsigned int u = __float_as_uint(f);
  u = u + 0x7fffu + ((u >> 16) & 1u);
  return (unsigned short)(u >> 16);
}
__device__ __forceinline__ float bf2f(unsigned short h){
  return __uint_as_float(((unsigned int)h) << 16);
}
__device__ __forceinline__ unsigned int cvtpk_bf16(float lo, float hi){
    unsigned int r;
    asm("v_cvt_pk_bf16_f32 %0, %1, %2" : "=v"(r) : "v"(lo), "v"(hi));
    return r;
}
__device__ __forceinline__ void split1_write(const float v[4], short* pH){
    unsigned int h01 = cvtpk_bf16(v[0], v[1]);
    unsigned int h23 = cvtpk_bf16(v[2], v[3]);
    *(uint2*)pH = make_uint2(h01, h23);
}
__device__ __forceinline__ void split2_write(const float v[4], short* pH, short* pL){
    unsigned int h01 = cvtpk_bf16(v[0], v[1]);
    unsigned int h23 = cvtpk_bf16(v[2], v[3]);
    float r0 = v[0] - __uint_as_float(h01 << 16);
    float r1 = v[1] - __uint_as_float(h01 & 0xffff0000u);
    float r2 = v[2] - __uint_as_float(h23 << 16);
    float r3 = v[3] - __uint_as_float(h23 & 0xffff0000u);
    unsigned int l01 = cvtpk_bf16(r0, r1);
    unsigned int l23 = cvtpk_bf16(r2, r3);
    *(uint2*)pH = make_uint2(h01, h23);
    *(uint2*)pL = make_uint2(l01, l23);
}
__device__ __forceinline__ void split3_write(const float v[4], short* pH, short* pM, short* pL){
    unsigned int h01 = cvtpk_bf16(v[0], v[1]);
    unsigned int h23 = cvtpk_bf16(v[2], v[3]);
    float r0 = v[0] - __uint_as_float(h01 << 16);
    float r1 = v[1] - __uint_as_float(h01 & 0xffff0000u);
    float r2 = v[2] - __uint_as_float(h23 << 16);
    float r3 = v[3] - __uint_as_float(h23 & 0xffff0000u);
    unsigned int m01 = cvtpk_bf16(r0, r1);
    unsigned int m23 = cvtpk_bf16(r2, r3);
    float s0 = r0 - __uint_as_float(m01 << 16);
    float s1 = r1 - __uint_as_float(m01 & 0xffff0000u);
    float s2 = r2 - __uint_as_float(m23 << 16);
    float s3 = r3 - __uint_as_float(m23 & 0xffff0000u);
    unsigned int l01 = cvtpk_bf16(s0, s1);
    unsigned int l23 = cvtpk_bf16(s2, s3);
    *(uint2*)pH = make_uint2(h01, h23);
    *(uint2*)pM = make_uint2(m01, m23);
    *(uint2*)pL = make_uint2(l01, l23);
}

// ---------------------------------------------------------------------------
// fp32 VALU primitives (value_x branch of front kernel)
// ---------------------------------------------------------------------------
template<int TM, bool RELU>
__device__ __forceinline__ void layer256(
    const float* __restrict__ W, const float* __restrict__ bias,
    const float* act, int K, int lda, float* out, int ldo)
{
    constexpr int RPG = TM / 4;
    const int tid = threadIdx.x;
    const int tr = tid >> 6;
    const int tc = tid & 63;
    float acc[RPG][4];
#pragma unroll
    for (int i = 0; i < RPG; ++i) { acc[i][0]=0.f; acc[i][1]=0.f; acc[i][2]=0.f; acc[i][3]=0.f; }
    const float* wp = W + 4 * tc;
    int k = 0;
    for (; k + 4 <= K; k += 4) {
        float4 w0 = *reinterpret_cast<const float4*>(wp + (k + 0) * DD);
        float4 w1 = *reinterpret_cast<const float4*>(wp + (k + 1) * DD);
        float4 w2 = *reinterpret_cast<const float4*>(wp + (k + 2) * DD);
        float4 w3 = *reinterpret_cast<const float4*>(wp + (k + 3) * DD);
#pragma unroll
        for (int i = 0; i < RPG; ++i) {
            float4 a = *reinterpret_cast<const float4*>(act + (RPG * tr + i) * lda + k);
            acc[i][0] += a.x * w0.x + a.y * w1.x + a.z * w2.x + a.w * w3.x;
            acc[i][1] += a.x * w0.y + a.y * w1.y + a.z * w2.y + a.w * w3.y;
            acc[i][2] += a.x * w0.z + a.y * w1.z + a.z * w2.z + a.w * w3.z;
            acc[i][3] += a.x * w0.w + a.y * w1.w + a.z * w2.w + a.w * w3.w;
        }
    }
    for (; k < K; ++k) {
        float4 w0 = *reinterpret_cast<const float4*>(wp + k * DD);
#pragma unroll
        for (int i = 0; i < RPG; ++i) {
            float a = act[(RPG * tr + i) * lda + k];
            acc[i][0] += a * w0.x; acc[i][1] += a * w0.y;
            acc[i][2] += a * w0.z; acc[i][3] += a * w0.w;
        }
    }
    float4 bb = *reinterpret_cast<const float4*>(bias + 4 * tc);
#pragma unroll
    for (int i = 0; i < RPG; ++i) {
        float4 o;
        o.x = acc[i][0] + bb.x; o.y = acc[i][1] + bb.y;
        o.z = acc[i][2] + bb.z; o.w = acc[i][3] + bb.w;
        if (RELU) {
            o.x = fmaxf(o.x, 0.f); o.y = fmaxf(o.y, 0.f);
            o.z = fmaxf(o.z, 0.f); o.w = fmaxf(o.w, 0.f);
        }
        *reinterpret_cast<float4*>(out + (RPG * tr + i) * ldo + 4 * tc) = o;
    }
}

template<int TM>
__device__ __forceinline__ void head1c(
    const float* h, int ldh, const float* __restrict__ W, int wstr, int col, float bias,
    float* __restrict__ gout, int gbase)
{
    const int wv = threadIdx.x >> 6;
    const int lane = threadIdx.x & 63;
    for (int rr = wv; rr < TM; rr += 4) {
        float p = 0.f;
#pragma unroll
        for (int t = 0; t < 4; ++t) {
            int k = lane + 64 * t;
            p += h[rr * ldh + k] * W[k * wstr + col];
        }
#pragma unroll
        for (int m = 1; m < 64; m <<= 1) p += __shfl_xor(p, m);
        if (lane == 0) gout[gbase + rr] = p + bias;
    }
}

// ---------------------------------------------------------------------------
// front_kernel (unchanged)
// ---------------------------------------------------------------------------
__global__ __launch_bounds__(256) void front_kernel(
    const float* __restrict__ x,
    const float* __restrict__ emW0, const float* __restrict__ emB0,
    const float* __restrict__ emW1, const float* __restrict__ emB1,
    const float* __restrict__ emW2, const float* __restrict__ emB2,
    const float* __restrict__ vW, const float* __restrict__ vb,
    const float* __restrict__ crW0, const float* __restrict__ crW1,
    const float* __restrict__ tmW0, const float* __restrict__ tmW1,
    const float* __restrict__ tmW2, const float* __restrict__ tmB2,
    short* __restrict__ planes, float* __restrict__ w5, float* __restrict__ b5,
    float* __restrict__ c2cr, float* __restrict__ c2tm, float* __restrict__ b45,
    float* __restrict__ vout, float* __restrict__ U1cr, float* __restrict__ U1tm)
{
    __shared__ __align__(16) float smem[32 * DD];
    const int blk = blockIdx.x;
    const int tid = threadIdx.x;

    if (blk < 24) {
        const int mat = blk >> 3;
        const int kk  = blk & 7;
        const float* W = (mat == 0) ? crW1 : (mat == 1) ? tmW1 : emW1;
        const int col = tid;
        short bh[32], bm[32], bl[32];
#pragma unroll
        for (int j = 0; j < 32; ++j) {
            float w = W[(kk * 32 + j) * 256 + col];
            unsigned short h = f2bf(w); float fh = bf2f(h);
            float r1 = w - fh;
            unsigned short m = f2bf(r1); float fm = bf2f(m);
            bh[j] = (short)h; bm[j] = (short)m; bl[j] = (short)f2bf(r1 - fm);
        }
        short* pH = planes + (size_t)(mat * 3 + 0) * PL + kk * 8192 + col * 32;
        short* pM = planes + (size_t)(mat * 3 + 1) * PL + kk * 8192 + col * 32;
        short* pLp = planes + (size_t)(mat * 3 + 2) * PL + kk * 8192 + col * 32;
#pragma unroll
        for (int j = 0; j < 32; j += 4) {
            *(short4*)(pH + j) = make_short4(bh[j], bh[j+1], bh[j+2], bh[j+3]);
            *(short4*)(pM + j) = make_short4(bm[j], bm[j+1], bm[j+2], bm[j+3]);
            *(short4*)(pLp + j) = make_short4(bl[j], bl[j+1], bl[j+2], bl[j+3]);
        }
    } else if (blk == 24) {
        float acc = 0.f;
        for (int j = 0; j < 256; j += 4) {
            float4 wrow = *(const float4*)(emW2 + tid * 256 + j);
            float4 vv   = *(const float4*)(vW + j);
            acc += wrow.x * vv.x + wrow.y * vv.y + wrow.z * vv.z + wrow.w * vv.w;
        }
        w5[tid] = acc;
        if (tid == 0) {
            float b = 0.f;
            for (int j = 0; j < 256; ++j) b += emB2[j] * vW[j];
            b5[0] = b + vb[0];
        }
    } else if (blk < 33) {
        constexpr int TM = 4;
        float* bufA = smem;
        float* bufB = bufA + TM * DD;
        float* bufC = bufB + TM * DD;
        const int row0 = (blk - 25) * TM;
        for (int i = 0; i < TM; ++i) bufA[i * DD + tid] = x[(row0 + i) * DD + tid];
        __syncthreads();
        layer256<TM, true >(emW0, emB0, bufA, 256, DD, bufB, DD); __syncthreads();
        layer256<TM, true >(emW1, emB1, bufB, 256, DD, bufC, DD); __syncthreads();
        layer256<TM, false>(emW2, emB2, bufC, 256, DD, bufB, DD); __syncthreads();
        head1c<TM>(bufB, DD, vW, 1, 0, vb[0], vout, row0);
    } else if (blk < 41) {
        const int row0 = (blk - 33) * 4;
        float* xs = smem;   // [4][256]
        for (int i = 0; i < 4; ++i) xs[i * 256 + tid] = x[(row0 + i) * 256 + tid];
        __syncthreads();
        float acr[4] = {0.f,0.f,0.f,0.f}, atm[4] = {0.f,0.f,0.f,0.f};
        for (int k = 0; k < 256; ++k) {
            float wc = crW0[k * 256 + tid];
            float wt = tmW0[k * 256 + tid];
#pragma unroll
            for (int i = 0; i < 4; ++i) {
                acr[i] += xs[i * 256 + k] * wc;
                atm[i] += xs[i * 256 + k] * wt;
            }
        }
        for (int i = 0; i < 4; ++i) {
            U1cr[(row0 + i) * 256 + tid] = acr[i];
            U1tm[(row0 + i) * 256 + tid] = atm[i];
        }
    } else if (blk < 65) {
        const int pb = blk - 41;
        const int prod = pb >> 3;           // 0=W45, 1=W2cr, 2=W2tm
        const int r0 = (pb & 7) * 32;
        const float* B = (prod == 0) ? emW0 : (prod == 1) ? crW0 : tmW0;
        const int pbase = 9 + prod * 3;
        float* As = smem;   // [32][256]
        for (int i = tid; i < 32 * 256; i += 256)
            As[i] = tmW2[(r0 + (i >> 8)) * 256 + (i & 255)];
        __syncthreads();
        float acc[32];
#pragma unroll
        for (int j = 0; j < 32; ++j) acc[j] = 0.f;
        for (int m = 0; m < 256; ++m) {
            float b = B[m * 256 + tid];
#pragma unroll
            for (int j = 0; j < 32; ++j) acc[j] += As[j * 256 + m] * b;
        }
        short bh[32], bm[32], bl[32];
#pragma unroll
        for (int j = 0; j < 32; ++j) {
            float w = acc[j];
            unsigned short h = f2bf(w); float fh = bf2f(h);
            float r1 = w - fh;
            unsigned short mm = f2bf(r1); float fm = bf2f(mm);
            bh[j] = (short)h; bm[j] = (short)mm; bl[j] = (short)f2bf(r1 - fm);
        }
        const int kk = r0 >> 5;
        short* pH = planes + (size_t)(pbase + 0) * PL + kk * 8192 + tid * 32;
        short* pM = planes + (size_t)(pbase + 1) * PL + kk * 8192 + tid * 32;
        short* pLp = planes + (size_t)(pbase + 2) * PL + kk * 8192 + tid * 32;
#pragma unroll
        for (int j = 0; j < 32; j += 4) {
            *(short4*)(pH + j) = make_short4(bh[j], bh[j+1], bh[j+2], bh[j+3]);
            *(short4*)(pM + j) = make_short4(bm[j], bm[j+1], bm[j+2], bm[j+3]);
            *(short4*)(pLp + j) = make_short4(bl[j], bl[j+1], bl[j+2], bl[j+3]);
        }
    } else {
        const int j = tid;
        float a0 = 0.f, a1 = 0.f, a2 = 0.f;
        for (int k = 0; k < 256; ++k) {
            float t = tmB2[k];
            a0 += t * crW0[k * 256 + j];
            a1 += t * tmW0[k * 256 + j];
            a2 += t * emW0[k * 256 + j];
        }
        c2cr[j] = a0;
        c2tm[j] = a1;
        b45[j] = a2 + emB0[j];
    }
}

__global__ __launch_bounds__(256) void finalize_kernel(
    const float* __restrict__ Vns3, const float* __restrict__ cont2,
    const float* __restrict__ rews0, const float* __restrict__ rews1,
    const float* __restrict__ cont1, float* __restrict__ out)
{
    const int b = blockIdx.x;
    const int tid = threadIdx.x;
    __shared__ float vs2[NA][NA];
    __shared__ float vs3[NA];
    if (tid < NA * NA) {
        const int x = tid / NA, y = tid % NA;
        float vals[NA];
        float m = -INFINITY;
#pragma unroll
        for (int z = 0; z < NA; ++z) {
            int vidx = ((b * NA + y) * NA + z) * NA + x;
            int cidx = ((b * NA + x) * NA + y) * NA + z;
            float c1 = rews0[b * NA + z] * 0.99f;
            float c2 = (c1 + rews1[(b * NA + x) * NA + z]) * 0.99f;
            float v = Vns3[vidx] * 0.970299f + c2;
            if (cont2[cidx] > 0.f) v = 0.f;
            vals[z] = v;
            m = fmaxf(m, v);
        }
        float se = 0.f, sw = 0.f;
#pragma unroll
        for (int z = 0; z < NA; ++z) { float e = expf(vals[z] - m); se += e; sw += e * vals[z]; }
        vs2[x][y] = sw / se;
    }
    __syncthreads();
    if (tid < NA) {
        const int x = tid;
        float vals[NA];
        float m = -INFINITY;
#pragma unroll
        for (int y = 0; y < NA; ++y) {
            float v = vs2[x][y];
            if (cont1[(b * NA + x) * NA + y] > 0.f) v = 0.f;
            vals[y] = v;
            m = fmaxf(m, v);
        }
        float se = 0.f, sw = 0.f;
#pragma unroll
        for (int y = 0; y < NA; ++y) { float e = expf(vals[y] - m); se += e; sw += e * vals[y]; }
        vs3[x] = sw / se;
    }
    __syncthreads();
    if (tid == 0) {
        float m = -INFINITY;
#pragma unroll
        for (int x = 0; x < NA; ++x) m = fmaxf(m, vs3[x]);
        float se = 0.f;
#pragma unroll
        for (int x = 0; x < NA; ++x) se += expf(vs3[x] - m);
        float l = logf(se);
#pragma unroll
        for (int x = 0; x < NA; ++x) out[b * NA + x] = vs3[x] - m - l;
    }
}

// ---------------------------------------------------------------------------
// mm3: RT row-tiles x 4 col-tiles over K=256 with NP passes (3-way act planes).
// ---------------------------------------------------------------------------
template<int RT, int NP>
__device__ __forceinline__ void mm3(
    const short* __restrict__ plH, const short* __restrict__ plM, const short* __restrict__ plL,
    const short* actH, const short* actM, const short* actL,
    f32x4 (&acc)[4][RT])
{
    const int tid = threadIdx.x;
    const int ln15 = tid & 15, lng = (tid >> 4) & 3, wv = tid >> 6;
    const int wo = (wv * 64 + ln15) * 32 + lng * 8;
#pragma unroll
    for (int kk = 0; kk < 8; ++kk) {
        bf16x8 wH[4], wM[4], wL[4], xH[RT], xM[RT], xL[RT];
#pragma unroll
        for (int ct = 0; ct < 4; ++ct) {
            wH[ct] = *(const bf16x8*)(plH + wo + kk * 8192 + ct * 512);
            wM[ct] = *(const bf16x8*)(plM + wo + kk * 8192 + ct * 512);
            if (NP == 6) wL[ct] = *(const bf16x8*)(plL + wo + kk * 8192 + ct * 512);
        }
#pragma unroll
        for (int rt = 0; rt < RT; ++rt) {
            int off = (rt * 16 + ln15) * ASTR + kk * 32 + lng * 8;
            xH[rt] = *(const bf16x8*)(actH + off);
            xM[rt] = *(const bf16x8*)(actM + off);
            if (NP == 6) xL[rt] = *(const bf16x8*)(actL + off);
        }
        __builtin_amdgcn_s_setprio(1);
#pragma unroll
        for (int ct = 0; ct < 4; ++ct)
#pragma unroll
            for (int rt = 0; rt < RT; ++rt) {
                acc[ct][rt] = __builtin_amdgcn_mfma_f32_16x16x32_bf16(wH[ct], xH[rt], acc[ct][rt], 0, 0, 0);
                acc[ct][rt] = __builtin_amdgcn_mfma_f32_16x16x32_bf16(wH[ct], xM[rt], acc[ct][rt], 0, 0, 0);
                acc[ct][rt] = __builtin_amdgcn_mfma_f32_16x16x32_bf16(wM[ct], xH[rt], acc[ct][rt], 0, 0, 0);
                if (NP == 6) {
                    acc[ct][rt] = __builtin_amdgcn_mfma_f32_16x16x32_bf16(wM[ct], xM[rt], acc[ct][rt], 0, 0, 0);
                    acc[ct][rt] = __builtin_amdgcn_mfma_f32_16x16x32_bf16(wH[ct], xL[rt], acc[ct][rt], 0, 0, 0);
                    acc[ct][rt] = __builtin_amdgcn_mfma_f32_16x16x32_bf16(wL[ct], xH[rt], acc[ct][rt], 0, 0, 0);
                }
            }
        __builtin_amdgcn_s_setprio(0);
    }
}

// ---------------------------------------------------------------------------
// mm24: exact (wH+wM) x (xH+xL) product — 4 passes, 2-way weights x 2-way act.
// Error ~2^-18 relative: sufficient for mask logits (min |logit| >> 1e-5).
// ---------------------------------------------------------------------------
template<int RT>
__device__ __forceinline__ void mm24(
    const short* __restrict__ plH, const short* __restrict__ plM,
    const short* actH, const short* actL,
    f32x4 (&acc)[4][RT])
{
    const int tid = threadIdx.x;
    const int ln15 = tid & 15, lng = (tid >> 4) & 3, wv = tid >> 6;
    const int wo = (wv * 64 + ln15) * 32 + lng * 8;
#pragma unroll
    for (int kk = 0; kk < 8; ++kk) {
        bf16x8 wH[4], wM[4], xH[RT], xL[RT];
#pragma unroll
        for (int ct = 0; ct < 4; ++ct) {
            wH[ct] = *(const bf16x8*)(plH + wo + kk * 8192 + ct * 512);
            wM[ct] = *(const bf16x8*)(plM + wo + kk * 8192 + ct * 512);
        }
#pragma unroll
        for (int rt = 0; rt < RT; ++rt) {
            int off = (rt * 16 + ln15) * ASTR + kk * 32 + lng * 8;
            xH[rt] = *(const bf16x8*)(actH + off);
            xL[rt] = *(const bf16x8*)(actL + off);
        }
        __builtin_amdgcn_s_setprio(1);
#pragma unroll
        for (int ct = 0; ct < 4; ++ct)
#pragma unroll
            for (int rt = 0; rt < RT; ++rt) {
                acc[ct][rt] = __builtin_amdgcn_mfma_f32_16x16x32_bf16(wH[ct], xH[rt], acc[ct][rt], 0, 0, 0);
                acc[ct][rt] = __builtin_amdgcn_mfma_f32_16x16x32_bf16(wH[ct], xL[rt], acc[ct][rt], 0, 0, 0);
                acc[ct][rt] = __builtin_amdgcn_mfma_f32_16x16x32_bf16(wM[ct], xH[rt], acc[ct][rt], 0, 0, 0);
                acc[ct][rt] = __builtin_amdgcn_mfma_f32_16x16x32_bf16(wM[ct], xL[rt], acc[ct][rt], 0, 0, 0);
            }
        __builtin_amdgcn_s_setprio(0);
    }
}

// stage a 3-way-split activation row block from U + a*wrow + bias (relu)
template<int ROWS, bool CLAMP>
__device__ __forceinline__ void stage3w(
    const float* __restrict__ U, const float* __restrict__ wrow256,
    const float* __restrict__ bias, int row0,
    short* actH, short* actM, short* actL)
{
    const int tid = threadIdx.x;
    const int wv = tid >> 6, ln = tid & 63;
    constexpr int RPW = ROWS / 4;
    const float4 wr = *(const float4*)(wrow256 + ln * 4);
    const float4 bb = *(const float4*)(bias + ln * 4);
    for (int i = wv * RPW; i < wv * RPW + RPW; ++i) {
        int r = row0 + i;
        int srow = r / 15;
        if (CLAMP && srow > 7199) srow = 7199;
        float a = (float)(r % 15);
        float4 u = *(const float4*)(U + srow * 256 + ln * 4);
        float sv[4];
        sv[0] = fmaxf(u.x + a * wr.x + bb.x, 0.f);
        sv[1] = fmaxf(u.y + a * wr.y + bb.y, 0.f);
        sv[2] = fmaxf(u.z + a * wr.z + bb.z, 0.f);
        sv[3] = fmaxf(u.w + a * wr.w + bb.w, 0.f);
        split3_write(sv, actH + i * ASTR + ln * 4, actM + i * ASTR + ln * 4, actL + i * ASTR + ln * 4);
    }
}

// stage a 2-way-split activation row block (H + L covering ~2^-18)
template<int ROWS, bool CLAMP>
__device__ __forceinline__ void stage2wact(
    const float* __restrict__ U, const float* __restrict__ wrow256,
    const float* __restrict__ bias, int row0,
    short* actH, short* actL)
{
    const int tid = threadIdx.x;
    const int wv = tid >> 6, ln = tid & 63;
    constexpr int RPW = ROWS / 4;
    const float4 wr = *(const float4*)(wrow256 + ln * 4);
    const float4 bb = *(const float4*)(bias + ln * 4);
    for (int i = wv * RPW; i < wv * RPW + RPW; ++i) {
        int r = row0 + i;
        int srow = r / 15;
        if (CLAMP && srow > 7199) srow = 7199;
        float a = (float)(r % 15);
        float4 u = *(const float4*)(U + srow * 256 + ln * 4);
        float sv[4];
        sv[0] = fmaxf(u.x + a * wr.x + bb.x, 0.f);
        sv[1] = fmaxf(u.y + a * wr.y + bb.y, 0.f);
        sv[2] = fmaxf(u.z + a * wr.z + bb.z, 0.f);
        sv[3] = fmaxf(u.w + a * wr.w + bb.w, 0.f);
        split2_write(sv, actH + i * ASTR + ln * 4, actL + i * ASTR + ln * 4);
    }
}

// ---------------------------------------------------------------------------
// stage1m: 480 rows (b,a1), 30 blocks x 16 rows. rews0 + U2cr/U2tm.
// Phase A (rews0, continuous) uses 4-pass; phase B stays 6-pass (mask chain).
// ---------------------------------------------------------------------------
__global__ __launch_bounds__(256, 2) void stage1m_kernel(
    const float* __restrict__ U1cr, const float* __restrict__ U1tm,
    const short* __restrict__ planes,
    const float* __restrict__ crW0, const float* __restrict__ crB0,
    const float* __restrict__ crB1, const float* __restrict__ crW2, const float* __restrict__ crB2,
    const float* __restrict__ tmW0, const float* __restrict__ tmB0,
    const float* __restrict__ tmB1,
    const float* __restrict__ c2cr, const float* __restrict__ c2tm,
    float* __restrict__ rews0, float* __restrict__ U2cr, float* __restrict__ U2tm)
{
    __shared__ short actH[16 * ASTR];
    __shared__ short actM[16 * ASTR];
    __shared__ short actL[16 * ASTR];
    __shared__ float hred[64];
    const int tid = threadIdx.x;
    const int row0 = blockIdx.x * 16;
    const int ln15 = tid & 15, lng = (tid >> 4) & 3, wv = tid >> 6;

    stage2wact<16, false>(U1cr, crW0 + 65536, crB0, row0, actH, actL);
    __syncthreads();
    {
        f32x4 acc[4][1];
#pragma unroll
        for (int a = 0; a < 4; ++a) acc[a][0] = f32x4{0.f,0.f,0.f,0.f};
        mm24<1>(planes + 0*PL, planes + 1*PL, actH, actL, acc);
        float hp = 0.f;
#pragma unroll
        for (int ct = 0; ct < 4; ++ct) {
            const int colb = wv * 64 + ct * 16 + lng * 4;
            const float4 b1 = *(const float4*)(crB1 + colb);
            f32x4 v = acc[ct][0];
            v[0] += b1.x; v[1] += b1.y; v[2] += b1.z; v[3] += b1.w;
#pragma unroll
            for (int j = 0; j < 4; ++j) v[j] = fmaxf(v[j], 0.f);
#pragma unroll
            for (int j = 0; j < 4; ++j) hp += v[j] * crW2[(colb + j) * 2 + 1];
        }
        hp += __shfl_xor(hp, 16);
        hp += __shfl_xor(hp, 32);
        if (lng == 0) hred[wv * 16 + ln15] = hp;
        __syncthreads();
        if (tid < 16) rews0[row0 + tid] = hred[tid] + hred[16 + tid] + hred[32 + tid] + hred[48 + tid] + crB2[1];
        __syncthreads();
    }

    stage3w<16, false>(U1tm, tmW0 + 65536, tmB0, row0, actH, actM, actL);
    __syncthreads();
    {
        f32x4 acc[4][1];
#pragma unroll
        for (int a = 0; a < 4; ++a) acc[a][0] = f32x4{0.f,0.f,0.f,0.f};
        mm3<1, 6>(planes + 3*PL, planes + 4*PL, planes + 5*PL, actH, actM, actL, acc);
        __syncthreads();
#pragma unroll
        for (int ct = 0; ct < 4; ++ct) {
            const int colb = wv * 64 + ct * 16 + lng * 4;
            const float4 bb = *(const float4*)(tmB1 + colb);
            f32x4 v = acc[ct][0];
            v[0] += bb.x; v[1] += bb.y; v[2] += bb.z; v[3] += bb.w;
#pragma unroll
            for (int j = 0; j < 4; ++j) v[j] = fmaxf(v[j], 0.f);
            float sv[4] = {v[0], v[1], v[2], v[3]};
            const int ao = ln15 * ASTR + colb;
            split3_write(sv, actH + ao, actM + ao, actL + ao);
        }
        __syncthreads();
    }
    {
        f32x4 acc[4][1];
#pragma unroll
        for (int a = 0; a < 4; ++a) acc[a][0] = f32x4{0.f,0.f,0.f,0.f};
        mm3<1, 6>(planes + 12*PL, planes + 13*PL, planes + 14*PL, actH, actM, actL, acc);
#pragma unroll
        for (int ct = 0; ct < 4; ++ct) {
            const int colb = wv * 64 + ct * 16 + lng * 4;
            const float4 cc = *(const float4*)(c2cr + colb);
            float4 o; o.x = acc[ct][0][0] + cc.x; o.y = acc[ct][0][1] + cc.y;
            o.z = acc[ct][0][2] + cc.z; o.w = acc[ct][0][3] + cc.w;
            *(float4*)(U2cr + (row0 + ln15) * 256 + colb) = o;
        }
    }
    {
        f32x4 acc[4][1];
#pragma unroll
        for (int a = 0; a < 4; ++a) acc[a][0] = f32x4{0.f,0.f,0.f,0.f};
        mm3<1, 6>(planes + 15*PL, planes + 16*PL, planes + 17*PL, actH, actM, actL, acc);
#pragma unroll
        for (int ct = 0; ct < 4; ++ct) {
            const int colb = wv * 64 + ct * 16 + lng * 4;
            const float4 cc = *(const float4*)(c2tm + colb);
            float4 o; o.x = acc[ct][0][0] + cc.x; o.y = acc[ct][0][1] + cc.y;
            o.z = acc[ct][0][2] + cc.z; o.w = acc[ct][0][3] + cc.w;
            *(float4*)(U2tm + (row0 + ln15) * 256 + colb) = o;
        }
    }
}

// ---------------------------------------------------------------------------
// stage2m: 7200 rows, 225 blocks x 32 rows (RT=2 — weight-amortization lever:
// halves weight-issue per row vs 16-row tiles; accumulation order per output
// unchanged -> bit-identical results). Phase A (cont1/rews1) 4-pass; phase B
// (feeds Ucr mask chain) stays 6-pass.
// LDS: 3 x 32 x ASTR x 2 = 50688 B + hred 1 KB.
// ---------------------------------------------------------------------------
__global__ __launch_bounds__(256, 2) void stage2m_kernel(
    const float* __restrict__ U2cr, const float* __restrict__ U2tm,
    const short* __restrict__ planes,
    const float* __restrict__ crW0, const float* __restrict__ crB0,
    const float* __restrict__ crB1, const float* __restrict__ crW2, const float* __restrict__ crB2,
    const float* __restrict__ tmW0, const float* __restrict__ tmB0,
    const float* __restrict__ tmB1,
    const float* __restrict__ c2cr, const float* __restrict__ c2tm,
    float* __restrict__ cont1, float* __restrict__ rews1,
    float* __restrict__ Ucr, float* __restrict__ Utm)
{
    __shared__ short actH[32 * ASTR];
    __shared__ short actM[32 * ASTR];
    __shared__ short actL[32 * ASTR];
    __shared__ float hred[2][128];
    const int tid = threadIdx.x;
    const int row0 = blockIdx.x * 32;
    const int ln15 = tid & 15, lng = (tid >> 4) & 3, wv = tid >> 6;

    stage2wact<32, false>(U2cr, crW0 + 65536, crB0, row0, actH, actL);
    __syncthreads();
    {
        f32x4 acc[4][2];
#pragma unroll
        for (int a = 0; a < 4; ++a)
#pragma unroll
            for (int b = 0; b < 2; ++b) acc[a][b] = f32x4{0.f,0.f,0.f,0.f};
        mm24<2>(planes + 0*PL, planes + 1*PL, actH, actL, acc);
        float hp0[2] = {0.f, 0.f}, hp1[2] = {0.f, 0.f};
#pragma unroll
        for (int ct = 0; ct < 4; ++ct) {
            const int colb = wv * 64 + ct * 16 + lng * 4;
            const float4 b1 = *(const float4*)(crB1 + colb);
#pragma unroll
            for (int rt = 0; rt < 2; ++rt) {
                f32x4 v = acc[ct][rt];
                v[0] += b1.x; v[1] += b1.y; v[2] += b1.z; v[3] += b1.w;
#pragma unroll
                for (int j = 0; j < 4; ++j) v[j] = fmaxf(v[j], 0.f);
#pragma unroll
                for (int j = 0; j < 4; ++j) {
                    hp0[rt] += v[j] * crW2[(colb + j) * 2 + 0];
                    hp1[rt] += v[j] * crW2[(colb + j) * 2 + 1];
                }
            }
        }
#pragma unroll
        for (int rt = 0; rt < 2; ++rt) {
            hp0[rt] += __shfl_xor(hp0[rt], 16); hp0[rt] += __shfl_xor(hp0[rt], 32);
            hp1[rt] += __shfl_xor(hp1[rt], 16); hp1[rt] += __shfl_xor(hp1[rt], 32);
        }
        if (lng == 0) {
#pragma unroll
            for (int rt = 0; rt < 2; ++rt) {
                hred[0][wv * 32 + rt * 16 + ln15] = hp0[rt];
                hred[1][wv * 32 + rt * 16 + ln15] = hp1[rt];
            }
        }
        __syncthreads();
        if (tid < 32)
            cont1[row0 + tid] = hred[0][tid] + hred[0][32 + tid] + hred[0][64 + tid] + hred[0][96 + tid] + crB2[0];
        else if (tid >= 64 && tid < 96)
            rews1[row0 + tid - 64] = hred[1][tid - 64] + hred[1][32 + tid - 64] + hred[1][64 + tid - 64] + hred[1][96 + tid - 64] + crB2[1];
        __syncthreads();
    }

    stage3w<32, false>(U2tm, tmW0 + 65536, tmB0, row0, actH, actM, actL);
    __syncthreads();
    {
        f32x4 acc[4][2];
#pragma unroll
        for (int a = 0; a < 4; ++a)
#pragma unroll
            for (int b = 0; b < 2; ++b) acc[a][b] = f32x4{0.f,0.f,0.f,0.f};
        mm3<2, 6>(planes + 3*PL, planes + 4*PL, planes + 5*PL, actH, actM, actL, acc);
        __syncthreads();
#pragma unroll
        for (int ct = 0; ct < 4; ++ct) {
            const int colb = wv * 64 + ct * 16 + lng * 4;
            const float4 bb = *(const float4*)(tmB1 + colb);
#pragma unroll
            for (int rt = 0; rt < 2; ++rt) {
                f32x4 v = acc[ct][rt];
                v[0] += bb.x; v[1] += bb.y; v[2] += bb.z; v[3] += bb.w;
#pragma unroll
                for (int j = 0; j < 4; ++j) v[j] = fmaxf(v[j], 0.f);
                float sv[4] = {v[0], v[1], v[2], v[3]};
                const int ao = (rt * 16 + ln15) * ASTR + colb;
                split3_write(sv, actH + ao, actM + ao, actL + ao);
            }
        }
        __syncthreads();
    }
    int pr[2];
#pragma unroll
    for (int rt = 0; rt < 2; ++rt) {
        int r = row0 + rt * 16 + ln15;
        int b = r / 225, a1 = (r / 15) % 15, a2 = r % 15;
        pr[rt] = (b * 15 + a2) * 15 + a1;
    }
    {
        f32x4 acc[4][2];
#pragma unroll
        for (int a = 0; a < 4; ++a)
#pragma unroll
            for (int b = 0; b < 2; ++b) acc[a][b] = f32x4{0.f,0.f,0.f,0.f};
        mm3<2, 6>(planes + 12*PL, planes + 13*PL, planes + 14*PL, actH, actM, actL, acc);
#pragma unroll
        for (int ct = 0; ct < 4; ++ct) {
            const int colb = wv * 64 + ct * 16 + lng * 4;
            const float4 cc = *(const float4*)(c2cr + colb);
#pragma unroll
            for (int rt = 0; rt < 2; ++rt) {
                float4 o; o.x = acc[ct][rt][0] + cc.x; o.y = acc[ct][rt][1] + cc.y;
                o.z = acc[ct][rt][2] + cc.z; o.w = acc[ct][rt][3] + cc.w;
                *(float4*)(Ucr + pr[rt] * 256 + colb) = o;
            }
        }
    }
    {
        f32x4 acc[4][2];
#pragma unroll
        for (int a = 0; a < 4; ++a)
#pragma unroll
            for (int b = 0; b < 2; ++b) acc[a][b] = f32x4{0.f,0.f,0.f,0.f};
        mm3<2, 3>(planes + 15*PL, planes + 16*PL, planes + 17*PL, actH, actM, actL, acc);
#pragma unroll
        for (int ct = 0; ct < 4; ++ct) {
            const int colb = wv * 64 + ct * 16 + lng * 4;
            const float4 cc = *(const float4*)(c2tm + colb);
#pragma unroll
            for (int rt = 0; rt < 2; ++rt) {
                float4 o; o.x = acc[ct][rt][0] + cc.x; o.y = acc[ct][rt][1] + cc.y;
                o.z = acc[ct][rt][2] + cc.z; o.w = acc[ct][rt][3] + cc.w;
                *(float4*)(Utm + pr[rt] * 256 + colb) = o;
            }
        }
    }
}

// ---------------------------------------------------------------------------
// layer_b1: pure-bf16 1-pass 16x16x32 layer over RT*16-row act tile.
// ---------------------------------------------------------------------------
template<int RT, bool RELU, bool HEAD, bool WRITEACT>
__device__ __forceinline__ void layer_b1(
    const short* __restrict__ plH,
    const float* __restrict__ bias,
    const float* __restrict__ headW, const float* __restrict__ headB,
    float* __restrict__ headOut, int row0,
    short* actH, float* hred)
{
    const int tid = threadIdx.x;
    const int ln15 = tid & 15, lng = (tid >> 4) & 3, wv = tid >> 6;
    const int wo = (wv * 64 + ln15) * 32 + lng * 8;
    f32x4 acc[4][RT];
#pragma unroll
    for (int a = 0; a < 4; ++a)
#pragma unroll
        for (int b = 0; b < RT; ++b) acc[a][b] = f32x4{0.f, 0.f, 0.f, 0.f};

#pragma unroll
    for (int kk = 0; kk < 8; ++kk) {
        bf16x8 aH[4], bH[RT];
#pragma unroll
        for (int ct = 0; ct < 4; ++ct)
            aH[ct] = *(const bf16x8*)(plH + wo + kk * 8192 + ct * 512);
#pragma unroll
        for (int rt = 0; rt < RT; ++rt) {
            int off = (rt * 16 + ln15) * ASTR + kk * 32 + lng * 8;
            bH[rt] = *(const bf16x8*)(actH + off);
        }
        __builtin_amdgcn_s_setprio(1);
#pragma unroll
        for (int ct = 0; ct < 4; ++ct)
#pragma unroll
            for (int rt = 0; rt < RT; ++rt)
                acc[ct][rt] = __builtin_amdgcn_mfma_f32_16x16x32_bf16(aH[ct], bH[rt], acc[ct][rt], 0, 0, 0);
        __builtin_amdgcn_s_setprio(0);
    }
    __syncthreads();

    float hp[RT];
#pragma unroll
    for (int rt = 0; rt < RT; ++rt) hp[rt] = 0.f;
#pragma unroll
    for (int ct = 0; ct < 4; ++ct) {
        const int colb = wv * 64 + ct * 16 + lng * 4;
        const float4 bb = *(const float4*)(bias + colb);
#pragma unroll
        for (int rt = 0; rt < RT; ++rt) {
            f32x4 v = acc[ct][rt];
            v[0] += bb.x; v[1] += bb.y; v[2] += bb.z; v[3] += bb.w;
            if (RELU) {
#pragma unroll
                for (int j = 0; j < 4; ++j) v[j] = fmaxf(v[j], 0.f);
            }
            if (HEAD) {
                const float4 hw = *(const float4*)(headW + colb);
                hp[rt] += v[0] * hw.x + v[1] * hw.y + v[2] * hw.z + v[3] * hw.w;
            }
            if (WRITEACT) {
                float sv[4] = {v[0], v[1], v[2], v[3]};
                const int ao = (rt * 16 + ln15) * ASTR + colb;
                split1_write(sv, actH + ao);
            }
        }
    }
    if constexpr (HEAD) {
        constexpr int NR = RT * 16;
#pragma unroll
        for (int rt = 0; rt < RT; ++rt) {
            hp[rt] += __shfl_xor(hp[rt], 16);
            hp[rt] += __shfl_xor(hp[rt], 32);
        }
        if (lng == 0) {
#pragma unroll
            for (int rt = 0; rt < RT; ++rt) hred[wv * NR + rt * 16 + ln15] = hp[rt];
        }
        __syncthreads();
        if (tid < NR && row0 + tid < 108000) {
            float s = hred[tid] + hred[NR + tid] + hred[2 * NR + tid] + hred[3 * NR + tid] + headB[0];
            headOut[row0 + tid] = s;
        }
    }
    if constexpr (WRITEACT) __syncthreads();
}

// ---------------------------------------------------------------------------
// k3ab: fused stage-3, 2 blocks/CU.
// k3b: 750 x 144-row tiles (1-pass bf16, single act plane).
// k3a: 1688 x 64-row tiles (4-pass, 2 act planes; last block guarded).
// Interleave 3:7 in groups of 10 (250 groups = 2500 blocks; k3a idx>=1688 exits).
// LDS: max(144, 2*64)*ASTR*2 = 76032 B + hred 2304 B <= 80K -> 2 blocks/CU.
// ---------------------------------------------------------------------------
__global__ __launch_bounds__(256, 2) void k3ab_kernel(
    const float* __restrict__ Ucr, const float* __restrict__ Utm,
    const short* __restrict__ planes,
    const float* __restrict__ crW0, const float* __restrict__ crB0,
    const float* __restrict__ crB1, const float* __restrict__ crW2,
    const float* __restrict__ crB2,
    const float* __restrict__ tmW0, const float* __restrict__ tmB0,
    const float* __restrict__ tmB1,
    const float* __restrict__ b45, const float* __restrict__ emB1,
    const float* __restrict__ w5, const float* __restrict__ b5,
    float* __restrict__ cont2, float* __restrict__ Vns3)
{
    __shared__ short lds[144 * ASTR];   // 76032 B (>= 2*64*ASTR = 67584)
    __shared__ float hred[576];
    const int tid = threadIdx.x;
    const int g = blockIdx.x / 10, rm = blockIdx.x % 10;
    const bool isB = rm < 3;
    const int idx = isB ? (g * 3 + rm) : (g * 7 + (rm - 3));
    const int ln15 = tid & 15, lng = (tid >> 4) & 3, wv = tid >> 6;
    const short* P = planes;

    if (isB) {
        const int row0 = idx * 144;
        short* actH = lds;
        const int ln = tid & 63;
        const float4 wr = *(const float4*)(tmW0 + 65536 + ln * 4);
        const float4 bb = *(const float4*)(tmB0 + ln * 4);
        for (int i = wv * 36; i < wv * 36 + 36; ++i) {
            int r = row0 + i;
            int srow = r / 15;
            if (srow > 7199) srow = 7199;
            float a = (float)(r % 15);
            float4 u = *(const float4*)(Utm + srow * 256 + ln * 4);
            float sv[4];
            sv[0] = fmaxf(u.x + a * wr.x + bb.x, 0.f);
            sv[1] = fmaxf(u.y + a * wr.y + bb.y, 0.f);
            sv[2] = fmaxf(u.z + a * wr.z + bb.z, 0.f);
            sv[3] = fmaxf(u.w + a * wr.w + bb.w, 0.f);
            split1_write(sv, actH + i * ASTR + ln * 4);
        }
        __syncthreads();
        layer_b1<9, true,  false, true >(P + 3 * PL, tmB1, nullptr, nullptr, nullptr, row0, actH, hred);
        layer_b1<9, true,  false, true >(P + 9 * PL, b45,  nullptr, nullptr, nullptr, row0, actH, hred);
        layer_b1<9, true,  true,  false>(P + 6 * PL, emB1, w5, b5, Vns3, row0, actH, hred);
    } else {
        if (idx >= 1688) return;
        const int row0 = idx * 64;
        short* actH = lds;
        short* actL = lds + 64 * ASTR;
        stage2wact<64, true>(Ucr, crW0 + 65536, crB0, row0, actH, actL);
        __syncthreads();
        f32x4 acc[4][4];
#pragma unroll
        for (int a = 0; a < 4; ++a)
#pragma unroll
            for (int b = 0; b < 4; ++b) acc[a][b] = f32x4{0.f,0.f,0.f,0.f};
        mm24<4>(P + 0*PL, P + 1*PL, actH, actL, acc);
        float hp[4] = {0.f, 0.f, 0.f, 0.f};
#pragma unroll
        for (int ct = 0; ct < 4; ++ct) {
            const int colb = wv * 64 + ct * 16 + lng * 4;
            const float4 b1 = *(const float4*)(crB1 + colb);
#pragma unroll
            for (int rt = 0; rt < 4; ++rt) {
                f32x4 v = acc[ct][rt];
                v[0] += b1.x; v[1] += b1.y; v[2] += b1.z; v[3] += b1.w;
#pragma unroll
                for (int j = 0; j < 4; ++j) v[j] = fmaxf(v[j], 0.f);
#pragma unroll
                for (int j = 0; j < 4; ++j) hp[rt] += v[j] * crW2[(colb + j) * 2];
            }
        }
#pragma unroll
        for (int rt = 0; rt < 4; ++rt) {
            hp[rt] += __shfl_xor(hp[rt], 16);
            hp[rt] += __shfl_xor(hp[rt], 32);
        }
        if (lng == 0) {
#pragma unroll
            for (int rt = 0; rt < 4; ++rt) hred[wv * 64 + rt * 16 + ln15] = hp[rt];
        }
        __syncthreads();
        if (tid < 64 && row0 + tid < 108000)
            cont2[row0 + tid] = hred[tid] + hred[64 + tid] + hred[128 + tid] + hred[192 + tid] + crB2[0];
    }
}

extern "C" void kernel_launch(void* const* d_in, const int* in_sizes, int n_in,
                              void* d_out, int out_size, void* d_ws, size_t ws_size,
                              hipStream_t stream)
{
    (void)in_sizes; (void)n_in; (void)out_size; (void)ws_size;
    const float* x    = (const float*)d_in[0];
    const float* emW0 = (const float*)d_in[1];
    const float* emB0 = (const float*)d_in[2];
    const float* emW1 = (const float*)d_in[3];
    const float* emB1 = (const float*)d_in[4];
    const float* emW2 = (const float*)d_in[5];
    const float* emB2 = (const float*)d_in[6];
    const float* vW   = (const float*)d_in[7];
    const float* vb   = (const float*)d_in[8];
    const float* crW0 = (const float*)d_in[9];
    const float* crB0 = (const float*)d_in[10];
    const float* crW1 = (const float*)d_in[11];
    const float* crB1 = (const float*)d_in[12];
    const float* crW2 = (const float*)d_in[13];
    const float* crB2 = (const float*)d_in[14];
    const float* tmW0 = (const float*)d_in[15];
    const float* tmB0 = (const float*)d_in[16];
    const float* tmW1 = (const float*)d_in[17];
    const float* tmB1 = (const float*)d_in[18];
    const float* tmW2 = (const float*)d_in[19];
    const float* tmB2 = (const float*)d_in[20];
    float* out = (float*)d_out;

    float* w     = (float*)d_ws;
    float* rews0 = w;                     // 480
    float* cont1 = rews0 + 480;           // 7200
    float* rews1 = cont1 + 7200;          // 7200
    float* cont2 = rews1 + 7200;          // 108000
    float* Vns3  = cont2 + 108000;        // 108000
    float* U1cr  = Vns3 + 108000;         // 32*256
    float* U1tm  = U1cr + 32 * 256;       // 32*256
    short* planes = (short*)(U1tm + 32 * 256);  // 18 * PL shorts = 2.25 MB
    float* U2cr  = (float*)(planes + 18 * PL);  // 480*256
    float* U2tm  = U2cr + 480 * 256;            // 480*256
    float* Ucr   = U2tm + 480 * 256;            // 7200*256
    float* Utm   = Ucr + 7200 * 256;            // 7200*256
    float* w5    = Utm + 7200 * 256;            // 256
    float* b5    = w5 + 256;                    // 1 (pad to 4)
    float* c2cr  = b5 + 4;                      // 256
    float* c2tm  = c2cr + 256;                  // 256
    float* b45   = c2tm + 256;                  // 256

    front_kernel<<<66, 256, 0, stream>>>(x,
        emW0, emB0, emW1, emB1, emW2, emB2, vW, vb,
        crW0, crW1, tmW0, tmW1, tmW2, tmB2,
        planes, w5, b5, c2cr, c2tm, b45,
        out + NB * NA, U1cr, U1tm);
    stage1m_kernel<<<30, 256, 0, stream>>>(U1cr, U1tm, planes,
        crW0, crB0, crB1, crW2, crB2, tmW0, tmB0, tmB1,
        c2cr, c2tm, rews0, U2cr, U2tm);
    stage2m_kernel<<<225, 256, 0, stream>>>(U2cr, U2tm, planes,
        crW0, crB0, crB1, crW2, crB2, tmW0, tmB0, tmB1,
        c2cr, c2tm, cont1, rews1, Ucr, Utm);
    k3ab_kernel<<<2500, 256, 0, stream>>>(Ucr, Utm, planes,
        crW0, crB0, crB1, crW2, crB2,
        tmW0, tmB0, tmB1, b45, emB1, w5, b5, cont2, Vns3);
    finalize_kernel<<<NB, 256, 0, stream>>>(Vns3, cont2, rews0, rews1, cont1, out);
}

// Round 23
// 204.284 us; speedup vs baseline: 1.7055x; 1.0590x over previous
//
#include <hip/hip_runtime.h>

#define NA 15
#define NB 32
#define DD 256
#define PL 65536  // shorts per weight plane (8 slices x 256 cols x 32 k)
#define ASTR 264  // act LDS row stride (shorts)

using bf16x8 = __attribute__((ext_vector_type(8))) short;
using f32x4  = __attribute__((ext_vector_type(4))) float;

__device__ __forceinline__ unsigned short f2bf(float f){
  unsigned int u = __float_as_uint(f);
  u = u + 0x7fffu + ((u >> 16) & 1u);
  return (unsigned short)(u >> 16);
}
__device__ __forceinline__ float bf2f(unsigned short h){
  return __uint_as_float(((unsigned int)h) << 16);
}
__device__ __forceinline__ unsigned int cvtpk_bf16(float lo, float hi){
    unsigned int r;
    asm("v_cvt_pk_bf16_f32 %0, %1, %2" : "=v"(r) : "v"(lo), "v"(hi));
    return r;
}
__device__ __forceinline__ void split1_write(const float v[4], short* pH){
    unsigned int h01 = cvtpk_bf16(v[0], v[1]);
    unsigned int h23 = cvtpk_bf16(v[2], v[3]);
    *(uint2*)pH = make_uint2(h01, h23);
}
__device__ __forceinline__ void split2_write(const float v[4], short* pH, short* pL){
    unsigned int h01 = cvtpk_bf16(v[0], v[1]);
    unsigned int h23 = cvtpk_bf16(v[2], v[3]);
    float r0 = v[0] - __uint_as_float(h01 << 16);
    float r1 = v[1] - __uint_as_float(h01 & 0xffff0000u);
    float r2 = v[2] - __uint_as_float(h23 << 16);
    float r3 = v[3] - __uint_as_float(h23 & 0xffff0000u);
    unsigned int l01 = cvtpk_bf16(r0, r1);
    unsigned int l23 = cvtpk_bf16(r2, r3);
    *(uint2*)pH = make_uint2(h01, h23);
    *(uint2*)pL = make_uint2(l01, l23);
}
__device__ __forceinline__ void split3_write(const float v[4], short* pH, short* pM, short* pL){
    unsigned int h01 = cvtpk_bf16(v[0], v[1]);
    unsigned int h23 = cvtpk_bf16(v[2], v[3]);
    float r0 = v[0] - __uint_as_float(h01 << 16);
    float r1 = v[1] - __uint_as_float(h01 & 0xffff0000u);
    float r2 = v[2] - __uint_as_float(h23 << 16);
    float r3 = v[3] - __uint_as_float(h23 & 0xffff0000u);
    unsigned int m01 = cvtpk_bf16(r0, r1);
    unsigned int m23 = cvtpk_bf16(r2, r3);
    float s0 = r0 - __uint_as_float(m01 << 16);
    float s1 = r1 - __uint_as_float(m01 & 0xffff0000u);
    float s2 = r2 - __uint_as_float(m23 << 16);
    float s3 = r3 - __uint_as_float(m23 & 0xffff0000u);
    unsigned int l01 = cvtpk_bf16(s0, s1);
    unsigned int l23 = cvtpk_bf16(s2, s3);
    *(uint2*)pH = make_uint2(h01, h23);
    *(uint2*)pM = make_uint2(m01, m23);
    *(uint2*)pL = make_uint2(l01, l23);
}

// ---------------------------------------------------------------------------
// fp32 VALU primitives (value_x branch of front kernel)
// ---------------------------------------------------------------------------
template<int TM, bool RELU>
__device__ __forceinline__ void layer256(
    const float* __restrict__ W, const float* __restrict__ bias,
    const float* act, int K, int lda, float* out, int ldo)
{
    constexpr int RPG = TM / 4;
    const int tid = threadIdx.x;
    const int tr = tid >> 6;
    const int tc = tid & 63;
    float acc[RPG][4];
#pragma unroll
    for (int i = 0; i < RPG; ++i) { acc[i][0]=0.f; acc[i][1]=0.f; acc[i][2]=0.f; acc[i][3]=0.f; }
    const float* wp = W + 4 * tc;
    int k = 0;
    for (; k + 4 <= K; k += 4) {
        float4 w0 = *reinterpret_cast<const float4*>(wp + (k + 0) * DD);
        float4 w1 = *reinterpret_cast<const float4*>(wp + (k + 1) * DD);
        float4 w2 = *reinterpret_cast<const float4*>(wp + (k + 2) * DD);
        float4 w3 = *reinterpret_cast<const float4*>(wp + (k + 3) * DD);
#pragma unroll
        for (int i = 0; i < RPG; ++i) {
            float4 a = *reinterpret_cast<const float4*>(act + (RPG * tr + i) * lda + k);
            acc[i][0] += a.x * w0.x + a.y * w1.x + a.z * w2.x + a.w * w3.x;
            acc[i][1] += a.x * w0.y + a.y * w1.y + a.z * w2.y + a.w * w3.y;
            acc[i][2] += a.x * w0.z + a.y * w1.z + a.z * w2.z + a.w * w3.z;
            acc[i][3] += a.x * w0.w + a.y * w1.w + a.z * w2.w + a.w * w3.w;
        }
    }
    for (; k < K; ++k) {
        float4 w0 = *reinterpret_cast<const float4*>(wp + k * DD);
#pragma unroll
        for (int i = 0; i < RPG; ++i) {
            float a = act[(RPG * tr + i) * lda + k];
            acc[i][0] += a * w0.x; acc[i][1] += a * w0.y;
            acc[i][2] += a * w0.z; acc[i][3] += a * w0.w;
        }
    }
    float4 bb = *reinterpret_cast<const float4*>(bias + 4 * tc);
#pragma unroll
    for (int i = 0; i < RPG; ++i) {
        float4 o;
        o.x = acc[i][0] + bb.x; o.y = acc[i][1] + bb.y;
        o.z = acc[i][2] + bb.z; o.w = acc[i][3] + bb.w;
        if (RELU) {
            o.x = fmaxf(o.x, 0.f); o.y = fmaxf(o.y, 0.f);
            o.z = fmaxf(o.z, 0.f); o.w = fmaxf(o.w, 0.f);
        }
        *reinterpret_cast<float4*>(out + (RPG * tr + i) * ldo + 4 * tc) = o;
    }
}

template<int TM>
__device__ __forceinline__ void head1c(
    const float* h, int ldh, const float* __restrict__ W, int wstr, int col, float bias,
    float* __restrict__ gout, int gbase)
{
    const int wv = threadIdx.x >> 6;
    const int lane = threadIdx.x & 63;
    for (int rr = wv; rr < TM; rr += 4) {
        float p = 0.f;
#pragma unroll
        for (int t = 0; t < 4; ++t) {
            int k = lane + 64 * t;
            p += h[rr * ldh + k] * W[k * wstr + col];
        }
#pragma unroll
        for (int m = 1; m < 64; m <<= 1) p += __shfl_xor(p, m);
        if (lane == 0) gout[gbase + rr] = p + bias;
    }
}

// ---------------------------------------------------------------------------
// front_kernel (unchanged)
// ---------------------------------------------------------------------------
__global__ __launch_bounds__(256) void front_kernel(
    const float* __restrict__ x,
    const float* __restrict__ emW0, const float* __restrict__ emB0,
    const float* __restrict__ emW1, const float* __restrict__ emB1,
    const float* __restrict__ emW2, const float* __restrict__ emB2,
    const float* __restrict__ vW, const float* __restrict__ vb,
    const float* __restrict__ crW0, const float* __restrict__ crW1,
    const float* __restrict__ tmW0, const float* __restrict__ tmW1,
    const float* __restrict__ tmW2, const float* __restrict__ tmB2,
    short* __restrict__ planes, float* __restrict__ w5, float* __restrict__ b5,
    float* __restrict__ c2cr, float* __restrict__ c2tm, float* __restrict__ b45,
    float* __restrict__ vout, float* __restrict__ U1cr, float* __restrict__ U1tm)
{
    __shared__ __align__(16) float smem[32 * DD];
    const int blk = blockIdx.x;
    const int tid = threadIdx.x;

    if (blk < 24) {
        const int mat = blk >> 3;
        const int kk  = blk & 7;
        const float* W = (mat == 0) ? crW1 : (mat == 1) ? tmW1 : emW1;
        const int col = tid;
        short bh[32], bm[32], bl[32];
#pragma unroll
        for (int j = 0; j < 32; ++j) {
            float w = W[(kk * 32 + j) * 256 + col];
            unsigned short h = f2bf(w); float fh = bf2f(h);
            float r1 = w - fh;
            unsigned short m = f2bf(r1); float fm = bf2f(m);
            bh[j] = (short)h; bm[j] = (short)m; bl[j] = (short)f2bf(r1 - fm);
        }
        short* pH = planes + (size_t)(mat * 3 + 0) * PL + kk * 8192 + col * 32;
        short* pM = planes + (size_t)(mat * 3 + 1) * PL + kk * 8192 + col * 32;
        short* pLp = planes + (size_t)(mat * 3 + 2) * PL + kk * 8192 + col * 32;
#pragma unroll
        for (int j = 0; j < 32; j += 4) {
            *(short4*)(pH + j) = make_short4(bh[j], bh[j+1], bh[j+2], bh[j+3]);
            *(short4*)(pM + j) = make_short4(bm[j], bm[j+1], bm[j+2], bm[j+3]);
            *(short4*)(pLp + j) = make_short4(bl[j], bl[j+1], bl[j+2], bl[j+3]);
        }
    } else if (blk == 24) {
        float acc = 0.f;
        for (int j = 0; j < 256; j += 4) {
            float4 wrow = *(const float4*)(emW2 + tid * 256 + j);
            float4 vv   = *(const float4*)(vW + j);
            acc += wrow.x * vv.x + wrow.y * vv.y + wrow.z * vv.z + wrow.w * vv.w;
        }
        w5[tid] = acc;
        if (tid == 0) {
            float b = 0.f;
            for (int j = 0; j < 256; ++j) b += emB2[j] * vW[j];
            b5[0] = b + vb[0];
        }
    } else if (blk < 33) {
        constexpr int TM = 4;
        float* bufA = smem;
        float* bufB = bufA + TM * DD;
        float* bufC = bufB + TM * DD;
        const int row0 = (blk - 25) * TM;
        for (int i = 0; i < TM; ++i) bufA[i * DD + tid] = x[(row0 + i) * DD + tid];
        __syncthreads();
        layer256<TM, true >(emW0, emB0, bufA, 256, DD, bufB, DD); __syncthreads();
        layer256<TM, true >(emW1, emB1, bufB, 256, DD, bufC, DD); __syncthreads();
        layer256<TM, false>(emW2, emB2, bufC, 256, DD, bufB, DD); __syncthreads();
        head1c<TM>(bufB, DD, vW, 1, 0, vb[0], vout, row0);
    } else if (blk < 41) {
        const int row0 = (blk - 33) * 4;
        float* xs = smem;   // [4][256]
        for (int i = 0; i < 4; ++i) xs[i * 256 + tid] = x[(row0 + i) * 256 + tid];
        __syncthreads();
        float acr[4] = {0.f,0.f,0.f,0.f}, atm[4] = {0.f,0.f,0.f,0.f};
        for (int k = 0; k < 256; ++k) {
            float wc = crW0[k * 256 + tid];
            float wt = tmW0[k * 256 + tid];
#pragma unroll
            for (int i = 0; i < 4; ++i) {
                acr[i] += xs[i * 256 + k] * wc;
                atm[i] += xs[i * 256 + k] * wt;
            }
        }
        for (int i = 0; i < 4; ++i) {
            U1cr[(row0 + i) * 256 + tid] = acr[i];
            U1tm[(row0 + i) * 256 + tid] = atm[i];
        }
    } else if (blk < 65) {
        const int pb = blk - 41;
        const int prod = pb >> 3;           // 0=W45, 1=W2cr, 2=W2tm
        const int r0 = (pb & 7) * 32;
        const float* B = (prod == 0) ? emW0 : (prod == 1) ? crW0 : tmW0;
        const int pbase = 9 + prod * 3;
        float* As = smem;   // [32][256]
        for (int i = tid; i < 32 * 256; i += 256)
            As[i] = tmW2[(r0 + (i >> 8)) * 256 + (i & 255)];
        __syncthreads();
        float acc[32];
#pragma unroll
        for (int j = 0; j < 32; ++j) acc[j] = 0.f;
        for (int m = 0; m < 256; ++m) {
            float b = B[m * 256 + tid];
#pragma unroll
            for (int j = 0; j < 32; ++j) acc[j] += As[j * 256 + m] * b;
        }
        short bh[32], bm[32], bl[32];
#pragma unroll
        for (int j = 0; j < 32; ++j) {
            float w = acc[j];
            unsigned short h = f2bf(w); float fh = bf2f(h);
            float r1 = w - fh;
            unsigned short mm = f2bf(r1); float fm = bf2f(mm);
            bh[j] = (short)h; bm[j] = (short)mm; bl[j] = (short)f2bf(r1 - fm);
        }
        const int kk = r0 >> 5;
        short* pH = planes + (size_t)(pbase + 0) * PL + kk * 8192 + tid * 32;
        short* pM = planes + (size_t)(pbase + 1) * PL + kk * 8192 + tid * 32;
        short* pLp = planes + (size_t)(pbase + 2) * PL + kk * 8192 + tid * 32;
#pragma unroll
        for (int j = 0; j < 32; j += 4) {
            *(short4*)(pH + j) = make_short4(bh[j], bh[j+1], bh[j+2], bh[j+3]);
            *(short4*)(pM + j) = make_short4(bm[j], bm[j+1], bm[j+2], bm[j+3]);
            *(short4*)(pLp + j) = make_short4(bl[j], bl[j+1], bl[j+2], bl[j+3]);
        }
    } else {
        const int j = tid;
        float a0 = 0.f, a1 = 0.f, a2 = 0.f;
        for (int k = 0; k < 256; ++k) {
            float t = tmB2[k];
            a0 += t * crW0[k * 256 + j];
            a1 += t * tmW0[k * 256 + j];
            a2 += t * emW0[k * 256 + j];
        }
        c2cr[j] = a0;
        c2tm[j] = a1;
        b45[j] = a2 + emB0[j];
    }
}

__global__ __launch_bounds__(256) void finalize_kernel(
    const float* __restrict__ Vns3, const float* __restrict__ cont2,
    const float* __restrict__ rews0, const float* __restrict__ rews1,
    const float* __restrict__ cont1, float* __restrict__ out)
{
    const int b = blockIdx.x;
    const int tid = threadIdx.x;
    __shared__ float vs2[NA][NA];
    __shared__ float vs3[NA];
    if (tid < NA * NA) {
        const int x = tid / NA, y = tid % NA;
        float vals[NA];
        float m = -INFINITY;
#pragma unroll
        for (int z = 0; z < NA; ++z) {
            int vidx = ((b * NA + y) * NA + z) * NA + x;
            int cidx = ((b * NA + x) * NA + y) * NA + z;
            float c1 = rews0[b * NA + z] * 0.99f;
            float c2 = (c1 + rews1[(b * NA + x) * NA + z]) * 0.99f;
            float v = Vns3[vidx] * 0.970299f + c2;
            if (cont2[cidx] > 0.f) v = 0.f;
            vals[z] = v;
            m = fmaxf(m, v);
        }
        float se = 0.f, sw = 0.f;
#pragma unroll
        for (int z = 0; z < NA; ++z) { float e = expf(vals[z] - m); se += e; sw += e * vals[z]; }
        vs2[x][y] = sw / se;
    }
    __syncthreads();
    if (tid < NA) {
        const int x = tid;
        float vals[NA];
        float m = -INFINITY;
#pragma unroll
        for (int y = 0; y < NA; ++y) {
            float v = vs2[x][y];
            if (cont1[(b * NA + x) * NA + y] > 0.f) v = 0.f;
            vals[y] = v;
            m = fmaxf(m, v);
        }
        float se = 0.f, sw = 0.f;
#pragma unroll
        for (int y = 0; y < NA; ++y) { float e = expf(vals[y] - m); se += e; sw += e * vals[y]; }
        vs3[x] = sw / se;
    }
    __syncthreads();
    if (tid == 0) {
        float m = -INFINITY;
#pragma unroll
        for (int x = 0; x < NA; ++x) m = fmaxf(m, vs3[x]);
        float se = 0.f;
#pragma unroll
        for (int x = 0; x < NA; ++x) se += expf(vs3[x] - m);
        float l = logf(se);
#pragma unroll
        for (int x = 0; x < NA; ++x) out[b * NA + x] = vs3[x] - m - l;
    }
}

// ---------------------------------------------------------------------------
// mm3: RT row-tiles x 4 col-tiles over K=256 with NP passes (3-way act planes).
// ---------------------------------------------------------------------------
template<int RT, int NP>
__device__ __forceinline__ void mm3(
    const short* __restrict__ plH, const short* __restrict__ plM, const short* __restrict__ plL,
    const short* actH, const short* actM, const short* actL,
    f32x4 (&acc)[4][RT])
{
    const int tid = threadIdx.x;
    const int ln15 = tid & 15, lng = (tid >> 4) & 3, wv = tid >> 6;
    const int wo = (wv * 64 + ln15) * 32 + lng * 8;
#pragma unroll
    for (int kk = 0; kk < 8; ++kk) {
        bf16x8 wH[4], wM[4], wL[4], xH[RT], xM[RT], xL[RT];
#pragma unroll
        for (int ct = 0; ct < 4; ++ct) {
            wH[ct] = *(const bf16x8*)(plH + wo + kk * 8192 + ct * 512);
            wM[ct] = *(const bf16x8*)(plM + wo + kk * 8192 + ct * 512);
            if (NP == 6) wL[ct] = *(const bf16x8*)(plL + wo + kk * 8192 + ct * 512);
        }
#pragma unroll
        for (int rt = 0; rt < RT; ++rt) {
            int off = (rt * 16 + ln15) * ASTR + kk * 32 + lng * 8;
            xH[rt] = *(const bf16x8*)(actH + off);
            xM[rt] = *(const bf16x8*)(actM + off);
            if (NP == 6) xL[rt] = *(const bf16x8*)(actL + off);
        }
        __builtin_amdgcn_s_setprio(1);
#pragma unroll
        for (int ct = 0; ct < 4; ++ct)
#pragma unroll
            for (int rt = 0; rt < RT; ++rt) {
                acc[ct][rt] = __builtin_amdgcn_mfma_f32_16x16x32_bf16(wH[ct], xH[rt], acc[ct][rt], 0, 0, 0);
                acc[ct][rt] = __builtin_amdgcn_mfma_f32_16x16x32_bf16(wH[ct], xM[rt], acc[ct][rt], 0, 0, 0);
                acc[ct][rt] = __builtin_amdgcn_mfma_f32_16x16x32_bf16(wM[ct], xH[rt], acc[ct][rt], 0, 0, 0);
                if (NP == 6) {
                    acc[ct][rt] = __builtin_amdgcn_mfma_f32_16x16x32_bf16(wM[ct], xM[rt], acc[ct][rt], 0, 0, 0);
                    acc[ct][rt] = __builtin_amdgcn_mfma_f32_16x16x32_bf16(wH[ct], xL[rt], acc[ct][rt], 0, 0, 0);
                    acc[ct][rt] = __builtin_amdgcn_mfma_f32_16x16x32_bf16(wL[ct], xH[rt], acc[ct][rt], 0, 0, 0);
                }
            }
        __builtin_amdgcn_s_setprio(0);
    }
}

// ---------------------------------------------------------------------------
// mm24: exact (wH+wM) x (xH+xL) product — 4 passes, 2-way weights x 2-way act.
// Error ~2^-18 relative: sufficient for mask logits (min |logit| >> 1e-5).
// ---------------------------------------------------------------------------
template<int RT>
__device__ __forceinline__ void mm24(
    const short* __restrict__ plH, const short* __restrict__ plM,
    const short* actH, const short* actL,
    f32x4 (&acc)[4][RT])
{
    const int tid = threadIdx.x;
    const int ln15 = tid & 15, lng = (tid >> 4) & 3, wv = tid >> 6;
    const int wo = (wv * 64 + ln15) * 32 + lng * 8;
#pragma unroll
    for (int kk = 0; kk < 8; ++kk) {
        bf16x8 wH[4], wM[4], xH[RT], xL[RT];
#pragma unroll
        for (int ct = 0; ct < 4; ++ct) {
            wH[ct] = *(const bf16x8*)(plH + wo + kk * 8192 + ct * 512);
            wM[ct] = *(const bf16x8*)(plM + wo + kk * 8192 + ct * 512);
        }
#pragma unroll
        for (int rt = 0; rt < RT; ++rt) {
            int off = (rt * 16 + ln15) * ASTR + kk * 32 + lng * 8;
            xH[rt] = *(const bf16x8*)(actH + off);
            xL[rt] = *(const bf16x8*)(actL + off);
        }
        __builtin_amdgcn_s_setprio(1);
#pragma unroll
        for (int ct = 0; ct < 4; ++ct)
#pragma unroll
            for (int rt = 0; rt < RT; ++rt) {
                acc[ct][rt] = __builtin_amdgcn_mfma_f32_16x16x32_bf16(wH[ct], xH[rt], acc[ct][rt], 0, 0, 0);
                acc[ct][rt] = __builtin_amdgcn_mfma_f32_16x16x32_bf16(wH[ct], xL[rt], acc[ct][rt], 0, 0, 0);
                acc[ct][rt] = __builtin_amdgcn_mfma_f32_16x16x32_bf16(wM[ct], xH[rt], acc[ct][rt], 0, 0, 0);
                acc[ct][rt] = __builtin_amdgcn_mfma_f32_16x16x32_bf16(wM[ct], xL[rt], acc[ct][rt], 0, 0, 0);
            }
        __builtin_amdgcn_s_setprio(0);
    }
}

// stage a 3-way-split activation row block from U + a*wrow + bias (relu)
template<int ROWS, bool CLAMP>
__device__ __forceinline__ void stage3w(
    const float* __restrict__ U, const float* __restrict__ wrow256,
    const float* __restrict__ bias, int row0,
    short* actH, short* actM, short* actL)
{
    const int tid = threadIdx.x;
    const int wv = tid >> 6, ln = tid & 63;
    constexpr int RPW = ROWS / 4;
    const float4 wr = *(const float4*)(wrow256 + ln * 4);
    const float4 bb = *(const float4*)(bias + ln * 4);
    for (int i = wv * RPW; i < wv * RPW + RPW; ++i) {
        int r = row0 + i;
        int srow = r / 15;
        if (CLAMP && srow > 7199) srow = 7199;
        float a = (float)(r % 15);
        float4 u = *(const float4*)(U + srow * 256 + ln * 4);
        float sv[4];
        sv[0] = fmaxf(u.x + a * wr.x + bb.x, 0.f);
        sv[1] = fmaxf(u.y + a * wr.y + bb.y, 0.f);
        sv[2] = fmaxf(u.z + a * wr.z + bb.z, 0.f);
        sv[3] = fmaxf(u.w + a * wr.w + bb.w, 0.f);
        split3_write(sv, actH + i * ASTR + ln * 4, actM + i * ASTR + ln * 4, actL + i * ASTR + ln * 4);
    }
}

// stage a 2-way-split activation row block (H + L covering ~2^-18)
template<int ROWS, bool CLAMP>
__device__ __forceinline__ void stage2wact(
    const float* __restrict__ U, const float* __restrict__ wrow256,
    const float* __restrict__ bias, int row0,
    short* actH, short* actL)
{
    const int tid = threadIdx.x;
    const int wv = tid >> 6, ln = tid & 63;
    constexpr int RPW = ROWS / 4;
    const float4 wr = *(const float4*)(wrow256 + ln * 4);
    const float4 bb = *(const float4*)(bias + ln * 4);
    for (int i = wv * RPW; i < wv * RPW + RPW; ++i) {
        int r = row0 + i;
        int srow = r / 15;
        if (CLAMP && srow > 7199) srow = 7199;
        float a = (float)(r % 15);
        float4 u = *(const float4*)(U + srow * 256 + ln * 4);
        float sv[4];
        sv[0] = fmaxf(u.x + a * wr.x + bb.x, 0.f);
        sv[1] = fmaxf(u.y + a * wr.y + bb.y, 0.f);
        sv[2] = fmaxf(u.z + a * wr.z + bb.z, 0.f);
        sv[3] = fmaxf(u.w + a * wr.w + bb.w, 0.f);
        split2_write(sv, actH + i * ASTR + ln * 4, actL + i * ASTR + ln * 4);
    }
}

// ---------------------------------------------------------------------------
// stage1m: 480 rows (b,a1), 30 blocks x 16 rows. rews0 + U2cr/U2tm.
// Phase A (rews0, continuous) uses 4-pass; phase B stays 6-pass (mask chain).
// ---------------------------------------------------------------------------
__global__ __launch_bounds__(256, 2) void stage1m_kernel(
    const float* __restrict__ U1cr, const float* __restrict__ U1tm,
    const short* __restrict__ planes,
    const float* __restrict__ crW0, const float* __restrict__ crB0,
    const float* __restrict__ crB1, const float* __restrict__ crW2, const float* __restrict__ crB2,
    const float* __restrict__ tmW0, const float* __restrict__ tmB0,
    const float* __restrict__ tmB1,
    const float* __restrict__ c2cr, const float* __restrict__ c2tm,
    float* __restrict__ rews0, float* __restrict__ U2cr, float* __restrict__ U2tm)
{
    __shared__ short actH[16 * ASTR];
    __shared__ short actM[16 * ASTR];
    __shared__ short actL[16 * ASTR];
    __shared__ float hred[64];
    const int tid = threadIdx.x;
    const int row0 = blockIdx.x * 16;
    const int ln15 = tid & 15, lng = (tid >> 4) & 3, wv = tid >> 6;

    stage2wact<16, false>(U1cr, crW0 + 65536, crB0, row0, actH, actL);
    __syncthreads();
    {
        f32x4 acc[4][1];
#pragma unroll
        for (int a = 0; a < 4; ++a) acc[a][0] = f32x4{0.f,0.f,0.f,0.f};
        mm24<1>(planes + 0*PL, planes + 1*PL, actH, actL, acc);
        float hp = 0.f;
#pragma unroll
        for (int ct = 0; ct < 4; ++ct) {
            const int colb = wv * 64 + ct * 16 + lng * 4;
            const float4 b1 = *(const float4*)(crB1 + colb);
            f32x4 v = acc[ct][0];
            v[0] += b1.x; v[1] += b1.y; v[2] += b1.z; v[3] += b1.w;
#pragma unroll
            for (int j = 0; j < 4; ++j) v[j] = fmaxf(v[j], 0.f);
#pragma unroll
            for (int j = 0; j < 4; ++j) hp += v[j] * crW2[(colb + j) * 2 + 1];
        }
        hp += __shfl_xor(hp, 16);
        hp += __shfl_xor(hp, 32);
        if (lng == 0) hred[wv * 16 + ln15] = hp;
        __syncthreads();
        if (tid < 16) rews0[row0 + tid] = hred[tid] + hred[16 + tid] + hred[32 + tid] + hred[48 + tid] + crB2[1];
        __syncthreads();
    }

    stage3w<16, false>(U1tm, tmW0 + 65536, tmB0, row0, actH, actM, actL);
    __syncthreads();
    {
        f32x4 acc[4][1];
#pragma unroll
        for (int a = 0; a < 4; ++a) acc[a][0] = f32x4{0.f,0.f,0.f,0.f};
        mm3<1, 6>(planes + 3*PL, planes + 4*PL, planes + 5*PL, actH, actM, actL, acc);
        __syncthreads();
#pragma unroll
        for (int ct = 0; ct < 4; ++ct) {
            const int colb = wv * 64 + ct * 16 + lng * 4;
            const float4 bb = *(const float4*)(tmB1 + colb);
            f32x4 v = acc[ct][0];
            v[0] += bb.x; v[1] += bb.y; v[2] += bb.z; v[3] += bb.w;
#pragma unroll
            for (int j = 0; j < 4; ++j) v[j] = fmaxf(v[j], 0.f);
            float sv[4] = {v[0], v[1], v[2], v[3]};
            const int ao = ln15 * ASTR + colb;
            split3_write(sv, actH + ao, actM + ao, actL + ao);
        }
        __syncthreads();
    }
    {
        f32x4 acc[4][1];
#pragma unroll
        for (int a = 0; a < 4; ++a) acc[a][0] = f32x4{0.f,0.f,0.f,0.f};
        mm3<1, 6>(planes + 12*PL, planes + 13*PL, planes + 14*PL, actH, actM, actL, acc);
#pragma unroll
        for (int ct = 0; ct < 4; ++ct) {
            const int colb = wv * 64 + ct * 16 + lng * 4;
            const float4 cc = *(const float4*)(c2cr + colb);
            float4 o; o.x = acc[ct][0][0] + cc.x; o.y = acc[ct][0][1] + cc.y;
            o.z = acc[ct][0][2] + cc.z; o.w = acc[ct][0][3] + cc.w;
            *(float4*)(U2cr + (row0 + ln15) * 256 + colb) = o;
        }
    }
    {
        f32x4 acc[4][1];
#pragma unroll
        for (int a = 0; a < 4; ++a) acc[a][0] = f32x4{0.f,0.f,0.f,0.f};
        mm3<1, 6>(planes + 15*PL, planes + 16*PL, planes + 17*PL, actH, actM, actL, acc);
#pragma unroll
        for (int ct = 0; ct < 4; ++ct) {
            const int colb = wv * 64 + ct * 16 + lng * 4;
            const float4 cc = *(const float4*)(c2tm + colb);
            float4 o; o.x = acc[ct][0][0] + cc.x; o.y = acc[ct][0][1] + cc.y;
            o.z = acc[ct][0][2] + cc.z; o.w = acc[ct][0][3] + cc.w;
            *(float4*)(U2tm + (row0 + ln15) * 256 + colb) = o;
        }
    }
}

// ---------------------------------------------------------------------------
// stage2m: 7200 rows, 225 blocks x 32 rows (RT=2). Phase A (cont1/rews1)
// 4-pass; phase B (feeds Ucr mask chain) stays 6-pass.
// ---------------------------------------------------------------------------
__global__ __launch_bounds__(256, 2) void stage2m_kernel(
    const float* __restrict__ U2cr, const float* __restrict__ U2tm,
    const short* __restrict__ planes,
    const float* __restrict__ crW0, const float* __restrict__ crB0,
    const float* __restrict__ crB1, const float* __restrict__ crW2, const float* __restrict__ crB2,
    const float* __restrict__ tmW0, const float* __restrict__ tmB0,
    const float* __restrict__ tmB1,
    const float* __restrict__ c2cr, const float* __restrict__ c2tm,
    float* __restrict__ cont1, float* __restrict__ rews1,
    float* __restrict__ Ucr, float* __restrict__ Utm)
{
    __shared__ short actH[32 * ASTR];
    __shared__ short actM[32 * ASTR];
    __shared__ short actL[32 * ASTR];
    __shared__ float hred[2][128];
    const int tid = threadIdx.x;
    const int row0 = blockIdx.x * 32;
    const int ln15 = tid & 15, lng = (tid >> 4) & 3, wv = tid >> 6;

    stage2wact<32, false>(U2cr, crW0 + 65536, crB0, row0, actH, actL);
    __syncthreads();
    {
        f32x4 acc[4][2];
#pragma unroll
        for (int a = 0; a < 4; ++a)
#pragma unroll
            for (int b = 0; b < 2; ++b) acc[a][b] = f32x4{0.f,0.f,0.f,0.f};
        mm24<2>(planes + 0*PL, planes + 1*PL, actH, actL, acc);
        float hp0[2] = {0.f, 0.f}, hp1[2] = {0.f, 0.f};
#pragma unroll
        for (int ct = 0; ct < 4; ++ct) {
            const int colb = wv * 64 + ct * 16 + lng * 4;
            const float4 b1 = *(const float4*)(crB1 + colb);
#pragma unroll
            for (int rt = 0; rt < 2; ++rt) {
                f32x4 v = acc[ct][rt];
                v[0] += b1.x; v[1] += b1.y; v[2] += b1.z; v[3] += b1.w;
#pragma unroll
                for (int j = 0; j < 4; ++j) v[j] = fmaxf(v[j], 0.f);
#pragma unroll
                for (int j = 0; j < 4; ++j) {
                    hp0[rt] += v[j] * crW2[(colb + j) * 2 + 0];
                    hp1[rt] += v[j] * crW2[(colb + j) * 2 + 1];
                }
            }
        }
#pragma unroll
        for (int rt = 0; rt < 2; ++rt) {
            hp0[rt] += __shfl_xor(hp0[rt], 16); hp0[rt] += __shfl_xor(hp0[rt], 32);
            hp1[rt] += __shfl_xor(hp1[rt], 16); hp1[rt] += __shfl_xor(hp1[rt], 32);
        }
        if (lng == 0) {
#pragma unroll
            for (int rt = 0; rt < 2; ++rt) {
                hred[0][wv * 32 + rt * 16 + ln15] = hp0[rt];
                hred[1][wv * 32 + rt * 16 + ln15] = hp1[rt];
            }
        }
        __syncthreads();
        if (tid < 32)
            cont1[row0 + tid] = hred[0][tid] + hred[0][32 + tid] + hred[0][64 + tid] + hred[0][96 + tid] + crB2[0];
        else if (tid >= 64 && tid < 96)
            rews1[row0 + tid - 64] = hred[1][tid - 64] + hred[1][32 + tid - 64] + hred[1][64 + tid - 64] + hred[1][96 + tid - 64] + crB2[1];
        __syncthreads();
    }

    stage3w<32, false>(U2tm, tmW0 + 65536, tmB0, row0, actH, actM, actL);
    __syncthreads();
    {
        f32x4 acc[4][2];
#pragma unroll
        for (int a = 0; a < 4; ++a)
#pragma unroll
            for (int b = 0; b < 2; ++b) acc[a][b] = f32x4{0.f,0.f,0.f,0.f};
        mm3<2, 6>(planes + 3*PL, planes + 4*PL, planes + 5*PL, actH, actM, actL, acc);
        __syncthreads();
#pragma unroll
        for (int ct = 0; ct < 4; ++ct) {
            const int colb = wv * 64 + ct * 16 + lng * 4;
            const float4 bb = *(const float4*)(tmB1 + colb);
#pragma unroll
            for (int rt = 0; rt < 2; ++rt) {
                f32x4 v = acc[ct][rt];
                v[0] += bb.x; v[1] += bb.y; v[2] += bb.z; v[3] += bb.w;
#pragma unroll
                for (int j = 0; j < 4; ++j) v[j] = fmaxf(v[j], 0.f);
                float sv[4] = {v[0], v[1], v[2], v[3]};
                const int ao = (rt * 16 + ln15) * ASTR + colb;
                split3_write(sv, actH + ao, actM + ao, actL + ao);
            }
        }
        __syncthreads();
    }
    int pr[2];
#pragma unroll
    for (int rt = 0; rt < 2; ++rt) {
        int r = row0 + rt * 16 + ln15;
        int b = r / 225, a1 = (r / 15) % 15, a2 = r % 15;
        pr[rt] = (b * 15 + a2) * 15 + a1;
    }
    {
        f32x4 acc[4][2];
#pragma unroll
        for (int a = 0; a < 4; ++a)
#pragma unroll
            for (int b = 0; b < 2; ++b) acc[a][b] = f32x4{0.f,0.f,0.f,0.f};
        mm3<2, 6>(planes + 12*PL, planes + 13*PL, planes + 14*PL, actH, actM, actL, acc);
#pragma unroll
        for (int ct = 0; ct < 4; ++ct) {
            const int colb = wv * 64 + ct * 16 + lng * 4;
            const float4 cc = *(const float4*)(c2cr + colb);
#pragma unroll
            for (int rt = 0; rt < 2; ++rt) {
                float4 o; o.x = acc[ct][rt][0] + cc.x; o.y = acc[ct][rt][1] + cc.y;
                o.z = acc[ct][rt][2] + cc.z; o.w = acc[ct][rt][3] + cc.w;
                *(float4*)(Ucr + pr[rt] * 256 + colb) = o;
            }
        }
    }
    {
        f32x4 acc[4][2];
#pragma unroll
        for (int a = 0; a < 4; ++a)
#pragma unroll
            for (int b = 0; b < 2; ++b) acc[a][b] = f32x4{0.f,0.f,0.f,0.f};
        mm3<2, 3>(planes + 15*PL, planes + 16*PL, planes + 17*PL, actH, actM, actL, acc);
#pragma unroll
        for (int ct = 0; ct < 4; ++ct) {
            const int colb = wv * 64 + ct * 16 + lng * 4;
            const float4 cc = *(const float4*)(c2tm + colb);
#pragma unroll
            for (int rt = 0; rt < 2; ++rt) {
                float4 o; o.x = acc[ct][rt][0] + cc.x; o.y = acc[ct][rt][1] + cc.y;
                o.z = acc[ct][rt][2] + cc.z; o.w = acc[ct][rt][3] + cc.w;
                *(float4*)(Utm + pr[rt] * 256 + colb) = o;
            }
        }
    }
}

// ---------------------------------------------------------------------------
// layer_b1: pure-bf16 1-pass 16x16x32 layer over RT*16-row act tile.
// ---------------------------------------------------------------------------
template<int RT, bool RELU, bool HEAD, bool WRITEACT>
__device__ __forceinline__ void layer_b1(
    const short* __restrict__ plH,
    const float* __restrict__ bias,
    const float* __restrict__ headW, const float* __restrict__ headB,
    float* __restrict__ headOut, int row0,
    short* actH, float* hred)
{
    const int tid = threadIdx.x;
    const int ln15 = tid & 15, lng = (tid >> 4) & 3, wv = tid >> 6;
    const int wo = (wv * 64 + ln15) * 32 + lng * 8;
    f32x4 acc[4][RT];
#pragma unroll
    for (int a = 0; a < 4; ++a)
#pragma unroll
        for (int b = 0; b < RT; ++b) acc[a][b] = f32x4{0.f, 0.f, 0.f, 0.f};

#pragma unroll
    for (int kk = 0; kk < 8; ++kk) {
        bf16x8 aH[4], bH[RT];
#pragma unroll
        for (int ct = 0; ct < 4; ++ct)
            aH[ct] = *(const bf16x8*)(plH + wo + kk * 8192 + ct * 512);
#pragma unroll
        for (int rt = 0; rt < RT; ++rt) {
            int off = (rt * 16 + ln15) * ASTR + kk * 32 + lng * 8;
            bH[rt] = *(const bf16x8*)(actH + off);
        }
        __builtin_amdgcn_s_setprio(1);
#pragma unroll
        for (int ct = 0; ct < 4; ++ct)
#pragma unroll
            for (int rt = 0; rt < RT; ++rt)
                acc[ct][rt] = __builtin_amdgcn_mfma_f32_16x16x32_bf16(aH[ct], bH[rt], acc[ct][rt], 0, 0, 0);
        __builtin_amdgcn_s_setprio(0);
    }
    __syncthreads();

    float hp[RT];
#pragma unroll
    for (int rt = 0; rt < RT; ++rt) hp[rt] = 0.f;
#pragma unroll
    for (int ct = 0; ct < 4; ++ct) {
        const int colb = wv * 64 + ct * 16 + lng * 4;
        const float4 bb = *(const float4*)(bias + colb);
#pragma unroll
        for (int rt = 0; rt < RT; ++rt) {
            f32x4 v = acc[ct][rt];
            v[0] += bb.x; v[1] += bb.y; v[2] += bb.z; v[3] += bb.w;
            if (RELU) {
#pragma unroll
                for (int j = 0; j < 4; ++j) v[j] = fmaxf(v[j], 0.f);
            }
            if (HEAD) {
                const float4 hw = *(const float4*)(headW + colb);
                hp[rt] += v[0] * hw.x + v[1] * hw.y + v[2] * hw.z + v[3] * hw.w;
            }
            if (WRITEACT) {
                float sv[4] = {v[0], v[1], v[2], v[3]};
                const int ao = (rt * 16 + ln15) * ASTR + colb;
                split1_write(sv, actH + ao);
            }
        }
    }
    if constexpr (HEAD) {
        constexpr int NR = RT * 16;
#pragma unroll
        for (int rt = 0; rt < RT; ++rt) {
            hp[rt] += __shfl_xor(hp[rt], 16);
            hp[rt] += __shfl_xor(hp[rt], 32);
        }
        if (lng == 0) {
#pragma unroll
            for (int rt = 0; rt < RT; ++rt) hred[wv * NR + rt * 16 + ln15] = hp[rt];
        }
        __syncthreads();
        if (tid < NR && row0 + tid < 108000) {
            float s = hred[tid] + hred[NR + tid] + hred[2 * NR + tid] + hred[3 * NR + tid] + headB[0];
            headOut[row0 + tid] = s;
        }
    }
    if constexpr (WRITEACT) __syncthreads();
}

// ---------------------------------------------------------------------------
// k3ab: fused stage-3, 3 blocks/CU (frontier re-test at the reduced workload:
// k3a now 2-plane/4-pass, k3b 1-pass — weight:compute ratio fell ~2-3x vs the
// R16 measurement that favored 2 blk/CU).
// k3b: 1125 x 96-row tiles (RT=6, 1 act plane). k3a: 2250 x 48-row (RT=3).
// Interleave 1:2 in groups of 3 (1125 groups = 3375 blocks, exact cover).
// LDS: max(96, 2*48)*ASTR*2 = 50688 B + hred 1536 B = 52224 <= 160K/3.
// ---------------------------------------------------------------------------
__global__ __launch_bounds__(256, 3) void k3ab_kernel(
    const float* __restrict__ Ucr, const float* __restrict__ Utm,
    const short* __restrict__ planes,
    const float* __restrict__ crW0, const float* __restrict__ crB0,
    const float* __restrict__ crB1, const float* __restrict__ crW2,
    const float* __restrict__ crB2,
    const float* __restrict__ tmW0, const float* __restrict__ tmB0,
    const float* __restrict__ tmB1,
    const float* __restrict__ b45, const float* __restrict__ emB1,
    const float* __restrict__ w5, const float* __restrict__ b5,
    float* __restrict__ cont2, float* __restrict__ Vns3)
{
    __shared__ short lds[2 * 48 * ASTR];   // 50688 B (== 96*ASTR for k3b)
    __shared__ float hred[384];
    const int tid = threadIdx.x;
    const int g = blockIdx.x / 3, rm = blockIdx.x % 3;
    const bool isB = rm == 0;
    const int idx = isB ? g : (g * 2 + (rm - 1));
    const int ln15 = tid & 15, lng = (tid >> 4) & 3, wv = tid >> 6;
    const short* P = planes;

    if (isB) {
        const int row0 = idx * 96;
        short* actH = lds;
        const int ln = tid & 63;
        const float4 wr = *(const float4*)(tmW0 + 65536 + ln * 4);
        const float4 bb = *(const float4*)(tmB0 + ln * 4);
        for (int i = wv * 24; i < wv * 24 + 24; ++i) {
            int r = row0 + i;
            int srow = r / 15;
            if (srow > 7199) srow = 7199;
            float a = (float)(r % 15);
            float4 u = *(const float4*)(Utm + srow * 256 + ln * 4);
            float sv[4];
            sv[0] = fmaxf(u.x + a * wr.x + bb.x, 0.f);
            sv[1] = fmaxf(u.y + a * wr.y + bb.y, 0.f);
            sv[2] = fmaxf(u.z + a * wr.z + bb.z, 0.f);
            sv[3] = fmaxf(u.w + a * wr.w + bb.w, 0.f);
            split1_write(sv, actH + i * ASTR + ln * 4);
        }
        __syncthreads();
        layer_b1<6, true,  false, true >(P + 3 * PL, tmB1, nullptr, nullptr, nullptr, row0, actH, hred);
        layer_b1<6, true,  false, true >(P + 9 * PL, b45,  nullptr, nullptr, nullptr, row0, actH, hred);
        layer_b1<6, true,  true,  false>(P + 6 * PL, emB1, w5, b5, Vns3, row0, actH, hred);
    } else {
        const int row0 = idx * 48;
        short* actH = lds;
        short* actL = lds + 48 * ASTR;
        stage2wact<48, true>(Ucr, crW0 + 65536, crB0, row0, actH, actL);
        __syncthreads();
        f32x4 acc[4][3];
#pragma unroll
        for (int a = 0; a < 4; ++a)
#pragma unroll
            for (int b = 0; b < 3; ++b) acc[a][b] = f32x4{0.f,0.f,0.f,0.f};
        mm24<3>(P + 0*PL, P + 1*PL, actH, actL, acc);
        float hp[3] = {0.f, 0.f, 0.f};
#pragma unroll
        for (int ct = 0; ct < 4; ++ct) {
            const int colb = wv * 64 + ct * 16 + lng * 4;
            const float4 b1 = *(const float4*)(crB1 + colb);
#pragma unroll
            for (int rt = 0; rt < 3; ++rt) {
                f32x4 v = acc[ct][rt];
                v[0] += b1.x; v[1] += b1.y; v[2] += b1.z; v[3] += b1.w;
#pragma unroll
                for (int j = 0; j < 4; ++j) v[j] = fmaxf(v[j], 0.f);
#pragma unroll
                for (int j = 0; j < 4; ++j) hp[rt] += v[j] * crW2[(colb + j) * 2];
            }
        }
#pragma unroll
        for (int rt = 0; rt < 3; ++rt) {
            hp[rt] += __shfl_xor(hp[rt], 16);
            hp[rt] += __shfl_xor(hp[rt], 32);
        }
        if (lng == 0) {
#pragma unroll
            for (int rt = 0; rt < 3; ++rt) hred[wv * 48 + rt * 16 + ln15] = hp[rt];
        }
        __syncthreads();
        if (tid < 48 && row0 + tid < 108000)
            cont2[row0 + tid] = hred[tid] + hred[48 + tid] + hred[96 + tid] + hred[144 + tid] + crB2[0];
    }
}

extern "C" void kernel_launch(void* const* d_in, const int* in_sizes, int n_in,
                              void* d_out, int out_size, void* d_ws, size_t ws_size,
                              hipStream_t stream)
{
    (void)in_sizes; (void)n_in; (void)out_size; (void)ws_size;
    const float* x    = (const float*)d_in[0];
    const float* emW0 = (const float*)d_in[1];
    const float* emB0 = (const float*)d_in[2];
    const float* emW1 = (const float*)d_in[3];
    const float* emB1 = (const float*)d_in[4];
    const float* emW2 = (const float*)d_in[5];
    const float* emB2 = (const float*)d_in[6];
    const float* vW   = (const float*)d_in[7];
    const float* vb   = (const float*)d_in[8];
    const float* crW0 = (const float*)d_in[9];
    const float* crB0 = (const float*)d_in[10];
    const float* crW1 = (const float*)d_in[11];
    const float* crB1 = (const float*)d_in[12];
    const float* crW2 = (const float*)d_in[13];
    const float* crB2 = (const float*)d_in[14];
    const float* tmW0 = (const float*)d_in[15];
    const float* tmB0 = (const float*)d_in[16];
    const float* tmW1 = (const float*)d_in[17];
    const float* tmB1 = (const float*)d_in[18];
    const float* tmW2 = (const float*)d_in[19];
    const float* tmB2 = (const float*)d_in[20];
    float* out = (float*)d_out;

    float* w     = (float*)d_ws;
    float* rews0 = w;                     // 480
    float* cont1 = rews0 + 480;           // 7200
    float* rews1 = cont1 + 7200;          // 7200
    float* cont2 = rews1 + 7200;          // 108000
    float* Vns3  = cont2 + 108000;        // 108000
    float* U1cr  = Vns3 + 108000;         // 32*256
    float* U1tm  = U1cr + 32 * 256;       // 32*256
    short* planes = (short*)(U1tm + 32 * 256);  // 18 * PL shorts = 2.25 MB
    float* U2cr  = (float*)(planes + 18 * PL);  // 480*256
    float* U2tm  = U2cr + 480 * 256;            // 480*256
    float* Ucr   = U2tm + 480 * 256;            // 7200*256
    float* Utm   = Ucr + 7200 * 256;            // 7200*256
    float* w5    = Utm + 7200 * 256;            // 256
    float* b5    = w5 + 256;                    // 1 (pad to 4)
    float* c2cr  = b5 + 4;                      // 256
    float* c2tm  = c2cr + 256;                  // 256
    float* b45   = c2tm + 256;                  // 256

    front_kernel<<<66, 256, 0, stream>>>(x,
        emW0, emB0, emW1, emB1, emW2, emB2, vW, vb,
        crW0, crW1, tmW0, tmW1, tmW2, tmB2,
        planes, w5, b5, c2cr, c2tm, b45,
        out + NB * NA, U1cr, U1tm);
    stage1m_kernel<<<30, 256, 0, stream>>>(U1cr, U1tm, planes,
        crW0, crB0, crB1, crW2, crB2, tmW0, tmB0, tmB1,
        c2cr, c2tm, rews0, U2cr, U2tm);
    stage2m_kernel<<<225, 256, 0, stream>>>(U2cr, U2tm, planes,
        crW0, crB0, crB1, crW2, crB2, tmW0, tmB0, tmB1,
        c2cr, c2tm, cont1, rews1, Ucr, Utm);
    k3ab_kernel<<<3375, 256, 0, stream>>>(Ucr, Utm, planes,
        crW0, crB0, crB1, crW2, crB2,
        tmW0, tmB0, tmB1, b45, emB1, w5, b5, cont2, Vns3);
    finalize_kernel<<<NB, 256, 0, stream>>>(Vns3, cont2, rews0, rews1, cont1, out);
}